// Round 7
// baseline (1012.541 us; speedup 1.0000x reference)
//
#include <hip/hip_runtime.h>
#include <math.h>

#define NN 50000
#define NE 800000
#define TDIM 100

typedef _Float16 half2v __attribute__((ext_vector_type(2)));
typedef _Float16 half4v __attribute__((ext_vector_type(4)));
typedef _Float16 half8v __attribute__((ext_vector_type(8)));
typedef __fp16 fp16x2 __attribute__((ext_vector_type(2)));
typedef float f32x4 __attribute__((ext_vector_type(4)));

union U16 { uint4 u; half8v h; };
union U4h { unsigned u; half2v h; };

// cos(x) matching np.cos(float32) to ~1e-6: Cody-Waite into revolutions +
// hardware v_cos_f32.
__device__ __forceinline__ float ref_cosf(float x) {
  const float C1 = 0.15915494f;
  const float C2 = 6.42063831e-9f;
  float p = x * C1;
  float r = __fmaf_rn(x, C1, -p);
  r = __fmaf_rn(x, C2, r);
  float n = rintf(p);
  float f = (p - n) + r;
  return __builtin_amdgcn_cosf(f);
}

__device__ __forceinline__ float fdot2f(unsigned a, unsigned b, float c) {
  U4h ua, ub; ua.u = a; ub.u = b;
#if __has_builtin(__builtin_amdgcn_fdot2)
  return __builtin_amdgcn_fdot2(ua.h, ub.h, c, false);
#else
  return c + (float)ua.h.x * (float)ub.h.x + (float)ua.h.y * (float)ub.h.y;
#endif
}

__device__ __forceinline__ unsigned pk16(float a, float b) {
  fp16x2 h = __builtin_amdgcn_cvt_pkrtz(a, b);
  unsigned u;
  __builtin_memcpy(&u, &h, 4);
  return u;
}

// ---------------- projection GEMM + fused Z ----------------
#define PBK 16
__global__ void k_proj(
    const float* __restrict__ x,
    const float* __restrict__ Wq, const float* __restrict__ bq,
    const float* __restrict__ Wk, const float* __restrict__ bk,
    const float* __restrict__ Wv, const float* __restrict__ bv,
    const float* __restrict__ Wskip, const float* __restrict__ bskip,
    const float* __restrict__ We,
    _Float16* __restrict__ Q16, _Float16* __restrict__ K16,
    _Float16* __restrict__ V16, _Float16* __restrict__ S16,
    _Float16* __restrict__ Z16)
{
  __shared__ float a_s[PBK][68];
  __shared__ float b_s[PBK][64];
  __shared__ unsigned qs2[64][32];     // q as f16x2 pairs [row][k-pair]
  __shared__ unsigned wes2[8][104];    // We slice f16x2 [k-pair][j]

  const int tid = threadIdx.x;
  const int cy = blockIdx.x;              // 0..7: 64-col slice of 512
  const int n0 = blockIdx.y * 64;

  const float* W    = (cy < 2) ? Wq : (cy < 4) ? Wk : (cy < 6) ? Wv : Wskip;
  const float* bias = (cy < 2) ? bq : (cy < 4) ? bk : (cy < 6) ? bv : bskip;
  _Float16* dst     = (cy < 2) ? Q16 : (cy < 4) ? K16 : (cy < 6) ? V16 : S16;
  const int cb = (cy & 1) * 64;

  const int ty = tid >> 4, tx = tid & 15;
  const int lrow = tid >> 2, lk4 = (tid & 3) << 2;
  const int lc = tid & 63, lk0 = tid >> 6;

  float acc[4][4];
#pragma unroll
  for (int r = 0; r < 4; ++r)
#pragma unroll
    for (int j = 0; j < 4; ++j) acc[r][j] = 0.f;

  for (int kt = 0; kt < 128; kt += PBK) {
    float4 av = make_float4(0.f, 0.f, 0.f, 0.f);
    if (n0 + lrow < NN)
      av = *(const float4*)&x[(size_t)(n0 + lrow) * 128 + kt + lk4];
    a_s[lk4 + 0][lrow] = av.x; a_s[lk4 + 1][lrow] = av.y;
    a_s[lk4 + 2][lrow] = av.z; a_s[lk4 + 3][lrow] = av.w;
#pragma unroll
    for (int i = 0; i < 4; ++i) {
      int k = lk0 + (i << 2);
      b_s[k][lc] = W[(kt + k) * 128 + cb + lc];
    }
    __syncthreads();
#pragma unroll
    for (int k = 0; k < PBK; ++k) {
      float4 a = *(const float4*)&a_s[k][ty << 2];
      float4 b = *(const float4*)&b_s[k][tx << 2];
      acc[0][0] = fmaf(a.x, b.x, acc[0][0]); acc[0][1] = fmaf(a.x, b.y, acc[0][1]);
      acc[0][2] = fmaf(a.x, b.z, acc[0][2]); acc[0][3] = fmaf(a.x, b.w, acc[0][3]);
      acc[1][0] = fmaf(a.y, b.x, acc[1][0]); acc[1][1] = fmaf(a.y, b.y, acc[1][1]);
      acc[1][2] = fmaf(a.y, b.z, acc[1][2]); acc[1][3] = fmaf(a.y, b.w, acc[1][3]);
      acc[2][0] = fmaf(a.z, b.x, acc[2][0]); acc[2][1] = fmaf(a.z, b.y, acc[2][1]);
      acc[2][2] = fmaf(a.z, b.z, acc[2][2]); acc[2][3] = fmaf(a.z, b.w, acc[2][3]);
      acc[3][0] = fmaf(a.w, b.x, acc[3][0]); acc[3][1] = fmaf(a.w, b.y, acc[3][1]);
      acc[3][2] = fmaf(a.w, b.z, acc[3][2]); acc[3][3] = fmaf(a.w, b.w, acc[3][3]);
    }
    __syncthreads();
  }

  float4 bb = *(const float4*)&bias[cb + (tx << 2)];
#pragma unroll
  for (int r = 0; r < 4; ++r) {
#pragma unroll
    for (int j = 0; j < 4; ++j) acc[r][j] += (&bb.x)[j];
    int row = n0 + (ty << 2) + r;
    if (row < NN) {
      half4v h;
      h.x = (_Float16)acc[r][0]; h.y = (_Float16)acc[r][1];
      h.z = (_Float16)acc[r][2]; h.w = (_Float16)acc[r][3];
      *(half4v*)&dst[(size_t)row * 128 + cb + (tx << 2)] = h;
    }
  }

  if (cy >= 2) return;

  // ---- fused Z for heads {2cy, 2cy+1} ----
#pragma unroll
  for (int r = 0; r < 4; ++r) {
    qs2[(ty << 2) + r][2 * tx]     = pk16(acc[r][0], acc[r][1]);
    qs2[(ty << 2) + r][2 * tx + 1] = pk16(acc[r][2], acc[r][3]);
  }

  const int tn = tid >> 4, tj = tid & 15;
#pragma unroll
  for (int h2 = 0; h2 < 2; ++h2) {
    float acc2[4][7];
#pragma unroll
    for (int r = 0; r < 4; ++r)
#pragma unroll
      for (int c = 0; c < 7; ++c) acc2[r][c] = 0.f;

    for (int kc = 0; kc < 2; ++kc) {
      __syncthreads();
      for (int idx = tid; idx < 832; idx += 256) {
        int kp = idx & 7, j = idx >> 3;
        unsigned val = 0u;
        if (j < 101) {
          float2 wv = *(const float2*)&We[j * 128 + cy * 64 + h2 * 32 + kc * 16 + kp * 2];
          val = pk16(wv.x, wv.y);
        }
        wes2[kp][j] = val;
      }
      __syncthreads();
#pragma unroll
      for (int kp = 0; kp < 8; ++kp) {
#pragma unroll
        for (int r = 0; r < 4; ++r) {
          unsigned q2 = qs2[tn * 4 + r][h2 * 16 + kc * 8 + kp];
#pragma unroll
          for (int c = 0; c < 7; ++c) {
            int j = tj + 16 * c;
            if (j < 104) acc2[r][c] = fdot2f(q2, wes2[kp][j], acc2[r][c]);
          }
        }
      }
    }
#pragma unroll
    for (int r = 0; r < 4; ++r) {
      int row = n0 + tn * 4 + r;
      if (row < NN) {
#pragma unroll
        for (int c = 0; c < 7; ++c) {
          int j = tj + 16 * c;
          if (j < 104)
            Z16[(size_t)row * 416 + (cy * 2 + h2) * 104 + j] =
                (j <= 100) ? (_Float16)acc2[r][c] : (_Float16)0.f;
        }
      }
    }
  }
}

// ---------------- We^T A-fragment precompute (32 KB) -----------------------
__global__ void k_wefrag(const float* __restrict__ We, uint4* __restrict__ frag) {
  int idx = blockIdx.x * 256 + threadIdx.x;
  if (idx >= 2048) return;
  int lane = idx & 63, fi = idx >> 6;
  int ks = fi >> 3, mt = fi & 7;
  int ch = mt * 16 + (lane & 15);
  int k0 = ks * 32 + ((lane >> 4) << 3);
  U16 cv;
#pragma unroll
  for (int jj = 0; jj < 8; ++jj) {
    int j = k0 + jj;
    cv.h[jj] = (j <= 100) ? (_Float16)We[j * 128 + ch] : (_Float16)0.f;
  }
  frag[idx] = cv.u;
}

// ---------------- CSR build ----------------
__global__ void k_deg(const int* __restrict__ ei, int* __restrict__ deg) {
  int e = blockIdx.x * 256 + threadIdx.x;
  if (e < NE) atomicAdd(&deg[ei[NE + e]], 1);
}

#define SCHUNK 49
__global__ __launch_bounds__(1024) void k_scan(const int* __restrict__ deg,
                                               int* __restrict__ off) {
  __shared__ int s[1024];
  const int t = threadIdx.x;
  const int base = t * SCHUNK;
  int sum = 0;
#pragma unroll 7
  for (int i = 0; i < SCHUNK; ++i) {
    int idx = base + i;
    sum += (idx < NN) ? deg[idx] : 0;
  }
  s[t] = sum;
  __syncthreads();
  for (int o = 1; o < 1024; o <<= 1) {
    int v = 0;
    if (t >= o) v = s[t - o];
    __syncthreads();
    if (t >= o) s[t] += v;
    __syncthreads();
  }
  int run = s[t] - sum;
  for (int i = 0; i < SCHUNK; ++i) {
    int idx = base + i;
    if (idx < NN) { off[idx] = run; run += deg[idx]; }
  }
  if (t == 1023) off[NN] = s[1023];
}

__global__ void k_fill(const int* __restrict__ ei, const int* __restrict__ off,
                       int* __restrict__ cur, int* __restrict__ elist) {
  int e = blockIdx.x * 256 + threadIdx.x;
  if (e < NE) {
    int d = ei[NE + e];
    int p = atomicAdd(&cur[d], 1);
    elist[off[d] + p] = e;
  }
}

// ---------------- fused attention: one wave per dst node --------------------
// alpha via z-trick; e via MFMA post-softmax. Software-pipelined: batch t+1's
// elist+metadata gathers issue during batch t's compute. q row staged in LDS
// (read transiently at qk) to cut persistent VGPR pressure.
// __launch_bounds__(256) with NO min-waves arg (R3/R5: forcing occupancy on
// the unified VGPR/AGPR file causes multi-GB scratch spill).
__global__ __launch_bounds__(256) void k_main(
    const _Float16* __restrict__ Q16, const _Float16* __restrict__ K16,
    const _Float16* __restrict__ V16, const _Float16* __restrict__ S16,
    const float* __restrict__ Wt, const float* __restrict__ bt,
    const uint4* __restrict__ wefrag, const unsigned* __restrict__ Z16u,
    const float* __restrict__ gamma, const float* __restrict__ beta,
    const float* __restrict__ msg, const int* __restrict__ last_update,
    const int* __restrict__ ei, const int* __restrict__ tt,
    const int* __restrict__ off, const int* __restrict__ elist,
    float* __restrict__ out)
{
  __shared__ uint4 wef_s[2048];        // 32 KB We^T A-fragments
  __shared__ float2 wtbt_s[104];
  __shared__ unsigned z_s[4][4][64];   // per-wave z f16-pairs [h][jp]
  __shared__ uint4 q_s[4][16];         // per-wave full q row (256 B)
  __shared__ float accs_s[4][128];

  for (int i = threadIdx.x; i < 2048; i += 256) wef_s[i] = wefrag[i];
  if (threadIdx.x < 104) {
    int j = threadIdx.x;
    wtbt_s[j] = make_float2(j < TDIM ? Wt[j] : 0.f, j < TDIM ? bt[j] : 0.f);
  }

  const int wid = threadIdx.x >> 6, lane = threadIdx.x & 63;
  const int node = blockIdx.x * 4 + wid;          // grid = NN/4 exact
  const int g = lane >> 4, ed = lane & 15;

  {
    const unsigned* zrow = Z16u + (size_t)node * 208;
#pragma unroll
    for (int it = 0; it < 4; ++it) {
      int i = lane + it * 64;
      int h = i >> 6, jp = i & 63;
      ((unsigned*)z_s[wid])[i] = (jp < 52) ? zrow[h * 52 + jp] : 0u;
    }
  }
  if (lane < 16)
    q_s[wid][lane] = ((const uint4*)(Q16 + (size_t)node * 128))[lane];
  __syncthreads();

  const int o0 = off[node];
  const int deg = off[node + 1] - o0;

  float mh[4] = {-INFINITY, -INFINITY, -INFINITY, -INFINITY};
  float lh[4] = {0.f, 0.f, 0.f, 0.f};
  float acc[8][4] = {};

  // prologue: prefetch batch-0 metadata
  float rel = 0.f, mg = 0.f; int srcl = 0;
  {
    int cnt0 = deg < 16 ? deg : 16;
    if (lane < cnt0) {
      int eid = elist[o0 + lane];
      srcl = ei[eid];
      mg = msg[eid];
      rel = (float)(last_update[srcl] - tt[eid]);
    }
  }

  for (int cbs = 0; cbs < deg; cbs += 16) {
    int cnt = deg - cbs; if (cnt > 16) cnt = 16;

    // broadcast current batch (prefetched last iteration)
    float rel_b = __shfl(rel, ed);
    float mg_b  = __shfl(mg, ed);
    int   src_b = __shfl(srcl, ed);
    const bool valid = (ed < cnt);

    // K gather issues immediately (src_b already known)
    uint4 ka[4];
    {
      const uint4* kp4 = (const uint4*)&K16[(size_t)src_b * 128 + g * 32];
#pragma unroll
      for (int i = 0; i < 4; ++i) ka[i] = kp4[i];
    }

    // issue next batch's elist load (hidden under cos/zdot)
    int nrem = deg - cbs - 16;
    int ncnt = nrem < 16 ? nrem : 16;
    int neid = 0;
    if (lane < ncnt) neid = elist[o0 + cbs + 16 + lane];

    // attr -> f16 B-fragments + z-dot (alpha e-term)
    unsigned bfu[4][4];
    float zd[4] = {0.f, 0.f, 0.f, 0.f};
#pragma unroll
    for (int ks = 0; ks < 4; ++ks) {
#pragma unroll
      for (int p = 0; p < 4; ++p) {
        int j0 = ks * 32 + g * 8 + 2 * p;
        float a0 = 0.f, a1 = 0.f;
        if (valid) {
          if (ks < 3) {   // j0,j0+1 <= 95: always cos
            float2 w0 = wtbt_s[j0], w1 = wtbt_s[j0 + 1];
            a0 = ref_cosf(__fmaf_rn(rel_b, w0.x, w0.y));
            a1 = ref_cosf(__fmaf_rn(rel_b, w1.x, w1.y));
          } else {
            if (j0 < 100) {
              float2 w0 = wtbt_s[j0];
              a0 = ref_cosf(__fmaf_rn(rel_b, w0.x, w0.y));
            } else if (j0 == 100) a0 = mg_b;
            if (j0 + 1 < 100) {
              float2 w1 = wtbt_s[j0 + 1];
              a1 = ref_cosf(__fmaf_rn(rel_b, w1.x, w1.y));
            } else if (j0 + 1 == 100) a1 = mg_b;
          }
        }
        bfu[ks][p] = pk16(a0, a1);
      }
#pragma unroll
      for (int h = 0; h < 4; ++h) {
        uint2 za = *(const uint2*)&z_s[wid][h][ks * 16 + g * 4];
        uint2 zb = *(const uint2*)&z_s[wid][h][ks * 16 + g * 4 + 2];
        zd[h] = fdot2f(bfu[ks][0], za.x, zd[h]);
        zd[h] = fdot2f(bfu[ks][1], za.y, zd[h]);
        zd[h] = fdot2f(bfu[ks][2], zb.x, zd[h]);
        zd[h] = fdot2f(bfu[ks][3], zb.y, zd[h]);
      }
    }

    // issue next batch's metadata gathers (hidden under qk/softmax/V phase)
    float nrel = 0.f, nmg = 0.f; int nsrc = 0;
    if (lane < ncnt) {
      nsrc = ei[neid];
      nmg = msg[neid];
      nrel = (float)(last_update[nsrc] - tt[neid]);
    }

    // q.k (head g within this lane); q read transiently from LDS
    float qk = 0.f;
#pragma unroll
    for (int i = 0; i < 4; ++i) {
      uint4 qa = q_s[wid][g * 4 + i];
      qk = fdot2f(qa.x, ka[i].x, qk);
      qk = fdot2f(qa.y, ka[i].y, qk);
      qk = fdot2f(qa.z, ka[i].z, qk);
      qk = fdot2f(qa.w, ka[i].w, qk);
    }

    // alpha per head
    float al[4];
#pragma unroll
    for (int h = 0; h < 4; ++h) {
      float p = zd[h] + ((h == g) ? qk : 0.f);
      p += __shfl_xor(p, 16); p += __shfl_xor(p, 32);
      al[h] = valid ? p * 0.17677669529663689f : -INFINITY;
    }

    // online softmax per head (reduce over ed lanes)
    float w_[4], sc_[4];
#pragma unroll
    for (int h = 0; h < 4; ++h) {
      float bm = al[h];
      bm = fmaxf(bm, __shfl_xor(bm, 1)); bm = fmaxf(bm, __shfl_xor(bm, 2));
      bm = fmaxf(bm, __shfl_xor(bm, 4)); bm = fmaxf(bm, __shfl_xor(bm, 8));
      float nm = fmaxf(mh[h], bm);
      sc_[h] = __expf(mh[h] - nm);
      w_[h] = __expf(al[h] - nm);
      float ls = w_[h];
      ls += __shfl_xor(ls, 1); ls += __shfl_xor(ls, 2);
      ls += __shfl_xor(ls, 4); ls += __shfl_xor(ls, 8);
      lh[h] = lh[h] * sc_[h] + ls;
      mh[h] = nm;
    }

    // V phase: e per mt-tile via MFMA, consumed immediately
#pragma unroll
    for (int mt = 0; mt < 8; ++mt) {
      uint2 vv = *(const uint2*)&V16[(size_t)src_b * 128 + mt * 16 + g * 4];
      f32x4 c4 = {0.f, 0.f, 0.f, 0.f};
#pragma unroll
      for (int ks = 0; ks < 4; ++ks) {
        U16 av2; av2.u = wef_s[(ks * 8 + mt) * 64 + lane];
        U16 bv2; bv2.u.x = bfu[ks][0]; bv2.u.y = bfu[ks][1];
        bv2.u.z = bfu[ks][2]; bv2.u.w = bfu[ks][3];
        c4 = __builtin_amdgcn_mfma_f32_16x16x32_f16(av2.h, bv2.h, c4, 0, 0, 0);
      }
      U4h v0, v1; v0.u = vv.x; v1.u = vv.y;
      int hh = mt >> 1;
      acc[mt][0] = fmaf(w_[hh], (float)v0.h.x + c4[0], acc[mt][0] * sc_[hh]);
      acc[mt][1] = fmaf(w_[hh], (float)v0.h.y + c4[1], acc[mt][1] * sc_[hh]);
      acc[mt][2] = fmaf(w_[hh], (float)v1.h.x + c4[2], acc[mt][2] * sc_[hh]);
      acc[mt][3] = fmaf(w_[hh], (float)v1.h.y + c4[3], acc[mt][3] * sc_[hh]);
    }

    // rotate prefetched metadata
    rel = nrel; mg = nmg; srcl = nsrc;
  }

  // reduce acc over ed lanes; stash in LDS for channel-major epilogue
#pragma unroll
  for (int mt = 0; mt < 8; ++mt)
#pragma unroll
    for (int r = 0; r < 4; ++r) {
      float v = acc[mt][r];
      v += __shfl_xor(v, 1); v += __shfl_xor(v, 2);
      v += __shfl_xor(v, 4); v += __shfl_xor(v, 8);
      acc[mt][r] = v;
    }
  if (ed == 0) {
#pragma unroll
    for (int mt = 0; mt < 8; ++mt)
#pragma unroll
      for (int r = 0; r < 4; ++r)
        accs_s[wid][mt * 16 + g * 4 + r] = acc[mt][r];
  }
  __asm__ volatile("s_waitcnt lgkmcnt(0)" ::: "memory");

  // epilogue: skip + relu + layernorm; lane owns channels 2L, 2L+1
  float iv = 1.f / (lh[g] + 1e-16f);
  float2 av2 = *(const float2*)&accs_s[wid][2 * lane];
  U4h s2; s2.u = *(const unsigned*)&S16[(size_t)node * 128 + 2 * lane];
  float r0 = fmaxf(fmaf(av2.x, iv, (float)s2.h.x), 0.f);
  float r1 = fmaxf(fmaf(av2.y, iv, (float)s2.h.y), 0.f);

  float sum = r0 + r1;
#pragma unroll
  for (int o = 1; o < 64; o <<= 1) sum += __shfl_xor(sum, o);
  float mu = sum * 0.0078125f;
  float d0 = r0 - mu, d1 = r1 - mu;
  float vs = d0 * d0 + d1 * d1;
#pragma unroll
  for (int o = 1; o < 64; o <<= 1) vs += __shfl_xor(vs, o);
  float rstd = rsqrtf(vs * 0.0078125f + 1e-5f);
  float2 gm = ((const float2*)gamma)[lane], bb = ((const float2*)beta)[lane];
  ((float2*)out)[node * 64 + lane] =
      make_float2(d0 * rstd * gm.x + bb.x, d1 * rstd * gm.y + bb.y);
}

// ---------------- launch ----------------
// ws (bytes): Q16 0 | S16 12.8M | K16 25.6M | V16 38.4M | Z16 51.2M (41.6M)
//   deg 92.8M | cur 93.0M | off 93.2M | elist 93,400,064 | wef 96,600,064
//   end 96,632,832  (< proven 106,200,064)
extern "C" void kernel_launch(void* const* d_in, const int* in_sizes, int n_in,
                              void* d_out, int out_size, void* d_ws, size_t ws_size,
                              hipStream_t stream)
{
  (void)in_sizes; (void)n_in; (void)out_size;
  if (ws_size < 96632832u) return;

  const float* x     = (const float*)d_in[0];
  const float* msg   = (const float*)d_in[1];
  const float* Wt    = (const float*)d_in[2];
  const float* bt    = (const float*)d_in[3];
  const float* Wq    = (const float*)d_in[4];
  const float* bq    = (const float*)d_in[5];
  const float* Wk    = (const float*)d_in[6];
  const float* bk    = (const float*)d_in[7];
  const float* Wv    = (const float*)d_in[8];
  const float* bv    = (const float*)d_in[9];
  const float* We    = (const float*)d_in[10];
  const float* Wskip = (const float*)d_in[11];
  const float* bskip = (const float*)d_in[12];
  const float* gamma = (const float*)d_in[13];
  const float* beta  = (const float*)d_in[14];
  const int* last_update = (const int*)d_in[15];
  const int* ei    = (const int*)d_in[16];
  const int* tt    = (const int*)d_in[17];

  char* ws = (char*)d_ws;
  _Float16* Q16 = (_Float16*)(ws);
  _Float16* S16 = (_Float16*)(ws + 12800000);
  _Float16* K16 = (_Float16*)(ws + 25600000);
  _Float16* V16 = (_Float16*)(ws + 38400000);
  _Float16* Z16 = (_Float16*)(ws + 51200000);
  int* deg   = (int*)(ws + 92800000);
  int* cur   = (int*)(ws + 93000000);
  int* off   = (int*)(ws + 93200000);
  int* elist = (int*)(ws + 93400064);
  uint4* wef = (uint4*)(ws + 96600064);

  (void)hipMemsetAsync(deg, 0, 400000, stream);        // deg + cur
  k_wefrag<<<8, 256, 0, stream>>>(We, wef);
  k_deg <<<(NE + 255) / 256, 256, 0, stream>>>(ei, deg);
  k_scan<<<1, 1024, 0, stream>>>(deg, off);
  k_fill<<<(NE + 255) / 256, 256, 0, stream>>>(ei, off, cur, elist);
  dim3 pg(8, (NN + 63) / 64);
  k_proj<<<pg, 256, 0, stream>>>(x, Wq, bq, Wk, bk, Wv, bv, Wskip, bskip, We,
                                 Q16, K16, V16, S16, Z16);
  k_main<<<NN / 4, 256, 0, stream>>>(Q16, K16, V16, S16, Wt, bt, wef,
                                     (const unsigned*)Z16, gamma, beta,
                                     msg, last_update, ei, tt, off, elist,
                                     (float*)d_out);
}

// Round 8
// 948.268 us; speedup vs baseline: 1.0678x; 1.0678x over previous
//
#include <hip/hip_runtime.h>
#include <math.h>

#define NN 50000
#define NE 800000
#define TDIM 100

typedef _Float16 half2v __attribute__((ext_vector_type(2)));
typedef _Float16 half4v __attribute__((ext_vector_type(4)));
typedef _Float16 half8v __attribute__((ext_vector_type(8)));
typedef __fp16 fp16x2 __attribute__((ext_vector_type(2)));
typedef float f32x4 __attribute__((ext_vector_type(4)));

union U16 { uint4 u; half8v h; };
union U4h { unsigned u; half2v h; };

// cos(x) matching np.cos(float32) to ~1e-6.
__device__ __forceinline__ float ref_cosf(float x) {
  const float C1 = 0.15915494f;
  const float C2 = 6.42063831e-9f;
  float p = x * C1;
  float r = __fmaf_rn(x, C1, -p);
  r = __fmaf_rn(x, C2, r);
  float n = rintf(p);
  float f = (p - n) + r;
  return __builtin_amdgcn_cosf(f);
}

__device__ __forceinline__ float fdot2f(unsigned a, unsigned b, float c) {
  U4h ua, ub; ua.u = a; ub.u = b;
#if __has_builtin(__builtin_amdgcn_fdot2)
  return __builtin_amdgcn_fdot2(ua.h, ub.h, c, false);
#else
  return c + (float)ua.h.x * (float)ub.h.x + (float)ua.h.y * (float)ub.h.y;
#endif
}

__device__ __forceinline__ unsigned pk16(float a, float b) {
  fp16x2 h = __builtin_amdgcn_cvt_pkrtz(a, b);
  unsigned u;
  __builtin_memcpy(&u, &h, 4);
  return u;
}

// monotone float<->uint encoding for atomicMax
__device__ __forceinline__ unsigned encf(float f) {
  unsigned i = __float_as_uint(f);
  return (i & 0x80000000u) ? ~i : (i | 0x80000000u);
}
__device__ __forceinline__ float decf(unsigned k) {
  unsigned i = (k & 0x80000000u) ? (k & 0x7FFFFFFFu) : ~k;
  return __uint_as_float(i);
}

// shared cos->bfu fragment builder: lane slice (g), j = ks*32+g*8+2p
__device__ __forceinline__ void build_bfu(float rel_b, float mg_b, int g,
                                          const float2* wtbt_s, unsigned bfu[4][4]) {
#pragma unroll
  for (int ks = 0; ks < 4; ++ks) {
#pragma unroll
    for (int p = 0; p < 4; ++p) {
      int j0 = ks * 32 + g * 8 + 2 * p;
      float a0 = 0.f, a1 = 0.f;
      if (ks < 3) {
        float2 w0 = wtbt_s[j0], w1 = wtbt_s[j0 + 1];
        a0 = ref_cosf(__fmaf_rn(rel_b, w0.x, w0.y));
        a1 = ref_cosf(__fmaf_rn(rel_b, w1.x, w1.y));
      } else {
        if (j0 < 100) {
          float2 w0 = wtbt_s[j0];
          a0 = ref_cosf(__fmaf_rn(rel_b, w0.x, w0.y));
        } else if (j0 == 100) a0 = mg_b;
        if (j0 + 1 < 100) {
          float2 w1 = wtbt_s[j0 + 1];
          a1 = ref_cosf(__fmaf_rn(rel_b, w1.x, w1.y));
        } else if (j0 + 1 == 100) a1 = mg_b;
      }
      bfu[ks][p] = pk16(a0, a1);
    }
  }
}

// ---------------- projection GEMM + fused Z ----------------
// V is stored PERMUTED: channel c -> pos ((c>>2)&3)*32 + (c>>4)*4 + (c&3)
// so k_aggr's lane (g) reads its 8 mt-fragments as one contiguous 64B.
#define PBK 16
__global__ void k_proj(
    const float* __restrict__ x,
    const float* __restrict__ Wq, const float* __restrict__ bq,
    const float* __restrict__ Wk, const float* __restrict__ bk,
    const float* __restrict__ Wv, const float* __restrict__ bv,
    const float* __restrict__ Wskip, const float* __restrict__ bskip,
    const float* __restrict__ We,
    _Float16* __restrict__ Q16, _Float16* __restrict__ K16,
    _Float16* __restrict__ V16, _Float16* __restrict__ S16,
    _Float16* __restrict__ Z16)
{
  __shared__ float a_s[PBK][68];
  __shared__ float b_s[PBK][64];
  __shared__ unsigned qs2[64][32];
  __shared__ unsigned wes2[8][104];

  const int tid = threadIdx.x;
  const int cy = blockIdx.x;
  const int n0 = blockIdx.y * 64;

  const float* W    = (cy < 2) ? Wq : (cy < 4) ? Wk : (cy < 6) ? Wv : Wskip;
  const float* bias = (cy < 2) ? bq : (cy < 4) ? bk : (cy < 6) ? bv : bskip;
  _Float16* dst     = (cy < 2) ? Q16 : (cy < 4) ? K16 : (cy < 6) ? V16 : S16;
  const int cb = (cy & 1) * 64;

  const int ty = tid >> 4, tx = tid & 15;
  const int lrow = tid >> 2, lk4 = (tid & 3) << 2;
  const int lc = tid & 63, lk0 = tid >> 6;

  float acc[4][4];
#pragma unroll
  for (int r = 0; r < 4; ++r)
#pragma unroll
    for (int j = 0; j < 4; ++j) acc[r][j] = 0.f;

  for (int kt = 0; kt < 128; kt += PBK) {
    float4 av = make_float4(0.f, 0.f, 0.f, 0.f);
    if (n0 + lrow < NN)
      av = *(const float4*)&x[(size_t)(n0 + lrow) * 128 + kt + lk4];
    a_s[lk4 + 0][lrow] = av.x; a_s[lk4 + 1][lrow] = av.y;
    a_s[lk4 + 2][lrow] = av.z; a_s[lk4 + 3][lrow] = av.w;
#pragma unroll
    for (int i = 0; i < 4; ++i) {
      int k = lk0 + (i << 2);
      b_s[k][lc] = W[(kt + k) * 128 + cb + lc];
    }
    __syncthreads();
#pragma unroll
    for (int k = 0; k < PBK; ++k) {
      float4 a = *(const float4*)&a_s[k][ty << 2];
      float4 b = *(const float4*)&b_s[k][tx << 2];
      acc[0][0] = fmaf(a.x, b.x, acc[0][0]); acc[0][1] = fmaf(a.x, b.y, acc[0][1]);
      acc[0][2] = fmaf(a.x, b.z, acc[0][2]); acc[0][3] = fmaf(a.x, b.w, acc[0][3]);
      acc[1][0] = fmaf(a.y, b.x, acc[1][0]); acc[1][1] = fmaf(a.y, b.y, acc[1][1]);
      acc[1][2] = fmaf(a.y, b.z, acc[1][2]); acc[1][3] = fmaf(a.y, b.w, acc[1][3]);
      acc[2][0] = fmaf(a.z, b.x, acc[2][0]); acc[2][1] = fmaf(a.z, b.y, acc[2][1]);
      acc[2][2] = fmaf(a.z, b.z, acc[2][2]); acc[2][3] = fmaf(a.z, b.w, acc[2][3]);
      acc[3][0] = fmaf(a.w, b.x, acc[3][0]); acc[3][1] = fmaf(a.w, b.y, acc[3][1]);
      acc[3][2] = fmaf(a.w, b.z, acc[3][2]); acc[3][3] = fmaf(a.w, b.w, acc[3][3]);
    }
    __syncthreads();
  }

  float4 bb = *(const float4*)&bias[cb + (tx << 2)];
  {
    int c = cb + (tx << 2);
    int pidx = (cy == 4 || cy == 5)
                 ? ((((c >> 2) & 3) << 5) | ((c >> 4) << 2))   // V permute
                 : c;
#pragma unroll
    for (int r = 0; r < 4; ++r) {
#pragma unroll
      for (int j = 0; j < 4; ++j) acc[r][j] += (&bb.x)[j];
      int row = n0 + (ty << 2) + r;
      if (row < NN) {
        half4v h;
        h.x = (_Float16)acc[r][0]; h.y = (_Float16)acc[r][1];
        h.z = (_Float16)acc[r][2]; h.w = (_Float16)acc[r][3];
        *(half4v*)&dst[(size_t)row * 128 + pidx] = h;
      }
    }
  }

  if (cy >= 2) return;

  // ---- fused Z for heads {2cy, 2cy+1} ----
#pragma unroll
  for (int r = 0; r < 4; ++r) {
    qs2[(ty << 2) + r][2 * tx]     = pk16(acc[r][0], acc[r][1]);
    qs2[(ty << 2) + r][2 * tx + 1] = pk16(acc[r][2], acc[r][3]);
  }

  const int tn = tid >> 4, tj = tid & 15;
#pragma unroll
  for (int h2 = 0; h2 < 2; ++h2) {
    float acc2[4][7];
#pragma unroll
    for (int r = 0; r < 4; ++r)
#pragma unroll
      for (int c = 0; c < 7; ++c) acc2[r][c] = 0.f;

    for (int kc = 0; kc < 2; ++kc) {
      __syncthreads();
      for (int idx = tid; idx < 832; idx += 256) {
        int kp = idx & 7, j = idx >> 3;
        unsigned val = 0u;
        if (j < 101) {
          float2 wv = *(const float2*)&We[j * 128 + cy * 64 + h2 * 32 + kc * 16 + kp * 2];
          val = pk16(wv.x, wv.y);
        }
        wes2[kp][j] = val;
      }
      __syncthreads();
#pragma unroll
      for (int kp = 0; kp < 8; ++kp) {
#pragma unroll
        for (int r = 0; r < 4; ++r) {
          unsigned q2 = qs2[tn * 4 + r][h2 * 16 + kc * 8 + kp];
#pragma unroll
          for (int c = 0; c < 7; ++c) {
            int j = tj + 16 * c;
            if (j < 104) acc2[r][c] = fdot2f(q2, wes2[kp][j], acc2[r][c]);
          }
        }
      }
    }
#pragma unroll
    for (int r = 0; r < 4; ++r) {
      int row = n0 + tn * 4 + r;
      if (row < NN) {
#pragma unroll
        for (int c = 0; c < 7; ++c) {
          int j = tj + 16 * c;
          if (j < 104)
            Z16[(size_t)row * 416 + (cy * 2 + h2) * 104 + j] =
                (j <= 100) ? (_Float16)acc2[r][c] : (_Float16)0.f;
        }
      }
    }
  }
}

// ---------------- We^T A-fragment precompute (32 KB) -----------------------
__global__ void k_wefrag(const float* __restrict__ We, uint4* __restrict__ frag) {
  int idx = blockIdx.x * 256 + threadIdx.x;
  if (idx >= 2048) return;
  int lane = idx & 63, fi = idx >> 6;
  int ks = fi >> 3, mt = fi & 7;
  int ch = mt * 16 + (lane & 15);
  int k0 = ks * 32 + ((lane >> 4) << 3);
  U16 cv;
#pragma unroll
  for (int jj = 0; jj < 8; ++jj) {
    int j = k0 + jj;
    cv.h[jj] = (j <= 100) ? (_Float16)We[j * 128 + ch] : (_Float16)0.f;
  }
  frag[idx] = cv.u;
}

// ---------------- CSR build ----------------
__global__ void k_deg(const int* __restrict__ ei, int* __restrict__ deg,
                      unsigned* __restrict__ maxb) {
  int e = blockIdx.x * 256 + threadIdx.x;
  if (e < 4 * NN) maxb[e] = 0x007FFFFFu;   // enc(-inf)
  if (e < NE) atomicAdd(&deg[ei[NE + e]], 1);
}

#define SCHUNK 49
__global__ __launch_bounds__(1024) void k_scan(const int* __restrict__ deg,
                                               int* __restrict__ off) {
  __shared__ int s[1024];
  const int t = threadIdx.x;
  const int base = t * SCHUNK;
  int sum = 0;
#pragma unroll 7
  for (int i = 0; i < SCHUNK; ++i) {
    int idx = base + i;
    sum += (idx < NN) ? deg[idx] : 0;
  }
  s[t] = sum;
  __syncthreads();
  for (int o = 1; o < 1024; o <<= 1) {
    int v = 0;
    if (t >= o) v = s[t - o];
    __syncthreads();
    if (t >= o) s[t] += v;
    __syncthreads();
  }
  int run = s[t] - sum;
  for (int i = 0; i < SCHUNK; ++i) {
    int idx = base + i;
    if (idx < NN) { off[idx] = run; run += deg[idx]; }
  }
  if (t == 1023) off[NN] = s[1023];
}

__global__ void k_fill(const int* __restrict__ ei, const int* __restrict__ off,
                       int* __restrict__ cur, int* __restrict__ elist) {
  int e = blockIdx.x * 256 + threadIdx.x;
  if (e < NE) {
    int d = ei[NE + e];
    int p = atomicAdd(&cur[d], 1);
    elist[off[d] + p] = e;
  }
}

// ---------------- k_alpha: edge-parallel alpha + per-(dst,head) max ---------
// 16 edges/wave (lane = (g,ed)); natural edge order (coalesced ei/msg/tt).
// alpha[e] = f16x4; maxb via encoded atomicMax (order-independent).
__global__ __launch_bounds__(256) void k_alpha(
    const _Float16* __restrict__ Q16, const _Float16* __restrict__ K16,
    const unsigned* __restrict__ Z16u,
    const float* __restrict__ Wt, const float* __restrict__ bt,
    const float* __restrict__ msg, const int* __restrict__ last_update,
    const int* __restrict__ ei, const int* __restrict__ tt,
    uint2* __restrict__ alpha16, unsigned* __restrict__ maxb)
{
  __shared__ float2 wtbt_s[104];
  if (threadIdx.x < 104) {
    int j = threadIdx.x;
    wtbt_s[j] = make_float2(j < TDIM ? Wt[j] : 0.f, j < TDIM ? bt[j] : 0.f);
  }
  __syncthreads();

  const int wid = threadIdx.x >> 6, lane = threadIdx.x & 63;
  const int g = lane >> 4, ed = lane & 15;
  const int e = (blockIdx.x * 4 + wid) * 16 + ed;   // NE = 12500*64 exact

  int src = ei[e];
  int dst = ei[NE + e];
  float mg = msg[e];
  float rel = (float)(last_update[src] - tt[e]);

  unsigned bfu[4][4];
  build_bfu(rel, mg, g, wtbt_s, bfu);

  // z-dot: z[dst][h][pair ks*16+g*4 .. +4]
  float zd[4] = {0.f, 0.f, 0.f, 0.f};
  const unsigned* zr = Z16u + (size_t)dst * 208;
#pragma unroll
  for (int ks = 0; ks < 3; ++ks) {
#pragma unroll
    for (int h = 0; h < 4; ++h) {
      uint4 z4 = *(const uint4*)&zr[h * 52 + ks * 16 + g * 4];
      zd[h] = fdot2f(bfu[ks][0], z4.x, zd[h]);
      zd[h] = fdot2f(bfu[ks][1], z4.y, zd[h]);
      zd[h] = fdot2f(bfu[ks][2], z4.z, zd[h]);
      zd[h] = fdot2f(bfu[ks][3], z4.w, zd[h]);
    }
  }
  if (g == 0) {   // ks=3 slice only exists for g==0 (j<=100)
#pragma unroll
    for (int h = 0; h < 4; ++h) {
      uint4 z4 = *(const uint4*)&zr[h * 52 + 48];
      zd[h] = fdot2f(bfu[3][0], z4.x, zd[h]);
      zd[h] = fdot2f(bfu[3][1], z4.y, zd[h]);
      zd[h] = fdot2f(bfu[3][2], z4.z, zd[h]);
      zd[h] = fdot2f(bfu[3][3], z4.w, zd[h]);
    }
  }

  // q.k for head g (channels g*32..g*32+31)
  float qk = 0.f;
  {
    const uint4* qp = (const uint4*)&Q16[(size_t)dst * 128 + g * 32];
    const uint4* kp = (const uint4*)&K16[(size_t)src * 128 + g * 32];
#pragma unroll
    for (int i = 0; i < 4; ++i) {
      uint4 qa = qp[i], ka = kp[i];
      qk = fdot2f(qa.x, ka.x, qk);
      qk = fdot2f(qa.y, ka.y, qk);
      qk = fdot2f(qa.z, ka.z, qk);
      qk = fdot2f(qa.w, ka.w, qk);
    }
  }

  float al[4];
#pragma unroll
  for (int h = 0; h < 4; ++h) {
    float p = zd[h] + ((h == g) ? qk : 0.f);
    p += __shfl_xor(p, 16); p += __shfl_xor(p, 32);
    al[h] = p * 0.17677669529663689f;
  }

  if (lane < 16) {
    half2v lo2, hi2;
    lo2.x = (_Float16)al[0]; lo2.y = (_Float16)al[1];
    hi2.x = (_Float16)al[2]; hi2.y = (_Float16)al[3];
    unsigned lou, hiu;
    __builtin_memcpy(&lou, &lo2, 4);
    __builtin_memcpy(&hiu, &hi2, 4);
    alpha16[e] = make_uint2(lou, hiu);
    U4h ul, uh; ul.u = lou; uh.u = hiu;
    atomicMax(&maxb[dst * 4 + 0], encf((float)ul.h.x));
    atomicMax(&maxb[dst * 4 + 1], encf((float)ul.h.y));
    atomicMax(&maxb[dst * 4 + 2], encf((float)uh.h.x));
    atomicMax(&maxb[dst * 4 + 3], encf((float)uh.h.y));
  }
}

// ---------------- k_aggr: node-parallel aggregation (max-known softmax) -----
__global__ __launch_bounds__(256) void k_aggr(
    const _Float16* __restrict__ V16, const _Float16* __restrict__ S16,
    const float* __restrict__ Wt, const float* __restrict__ bt,
    const uint4* __restrict__ wefrag,
    const float* __restrict__ gamma, const float* __restrict__ beta,
    const float* __restrict__ msg, const int* __restrict__ last_update,
    const int* __restrict__ ei, const int* __restrict__ tt,
    const int* __restrict__ off, const int* __restrict__ elist,
    const uint2* __restrict__ alpha16, const unsigned* __restrict__ maxb,
    float* __restrict__ out)
{
  __shared__ uint4 wef_s[2048];
  __shared__ float2 wtbt_s[104];
  __shared__ float accs_s[4][128];

  for (int i = threadIdx.x; i < 2048; i += 256) wef_s[i] = wefrag[i];
  if (threadIdx.x < 104) {
    int j = threadIdx.x;
    wtbt_s[j] = make_float2(j < TDIM ? Wt[j] : 0.f, j < TDIM ? bt[j] : 0.f);
  }
  __syncthreads();

  const int wid = threadIdx.x >> 6, lane = threadIdx.x & 63;
  const int node = blockIdx.x * 4 + wid;
  const int g = lane >> 4, ed = lane & 15;

  const int o0 = off[node];
  const int deg = off[node + 1] - o0;

  float maxf[4];
  {
    uint4 mb = *(const uint4*)&maxb[node * 4];
    maxf[0] = decf(mb.x); maxf[1] = decf(mb.y);
    maxf[2] = decf(mb.z); maxf[3] = decf(mb.w);
  }

  float lh[4] = {0.f, 0.f, 0.f, 0.f};
  float acc[8][4] = {};

  // prologue: prefetch batch-0 metadata + alpha
  float rel = 0.f, mg = 0.f; int srcl = 0; uint2 aw = make_uint2(0u, 0u);
  {
    int c0 = deg < 16 ? deg : 16;
    if (lane < c0) {
      int eid = elist[o0 + lane];
      srcl = ei[eid];
      mg = msg[eid];
      rel = (float)(last_update[srcl] - tt[eid]);
      aw = alpha16[eid];
    }
  }

  for (int cbs = 0; cbs < deg; cbs += 16) {
    int cnt = deg - cbs; if (cnt > 16) cnt = 16;

    float rel_b = __shfl(rel, ed);
    float mg_b  = __shfl(mg, ed);
    int   src_b = __shfl(srcl, ed);
    unsigned awx = (unsigned)__shfl((int)aw.x, ed);
    unsigned awy = (unsigned)__shfl((int)aw.y, ed);
    const bool valid = (ed < cnt);

    // V gather: permuted layout -> 64B contiguous per lane
    uint4 v4[4];
    {
      const uint4* vp = (const uint4*)&V16[(size_t)src_b * 128 + g * 32];
#pragma unroll
      for (int i = 0; i < 4; ++i) v4[i] = vp[i];
    }

    // prefetch next batch
    int nrem = deg - cbs - 16;
    int ncnt = nrem < 16 ? nrem : 16;
    float nrel = 0.f, nmg = 0.f; int nsrc = 0; uint2 naw = make_uint2(0u, 0u);
    if (lane < ncnt) {
      int neid = elist[o0 + cbs + 16 + lane];
      nsrc = ei[neid];
      nmg = msg[neid];
      nrel = (float)(last_update[nsrc] - tt[neid]);
      naw = alpha16[neid];
    }

    // softmax weights from precomputed alpha/max
    float w_[4];
    {
      U4h alo, ahi; alo.u = awx; ahi.u = awy;
      w_[0] = valid ? __expf((float)alo.h.x - maxf[0]) : 0.f;
      w_[1] = valid ? __expf((float)alo.h.y - maxf[1]) : 0.f;
      w_[2] = valid ? __expf((float)ahi.h.x - maxf[2]) : 0.f;
      w_[3] = valid ? __expf((float)ahi.h.y - maxf[3]) : 0.f;
      lh[0] += w_[0]; lh[1] += w_[1]; lh[2] += w_[2]; lh[3] += w_[3];
    }

    // attr fragments for e-MFMA
    unsigned bfu[4][4];
    build_bfu(rel_b, mg_b, g, wtbt_s, bfu);

    // V phase: e per mt-tile via MFMA, accumulate w*(v+e)
#pragma unroll
    for (int mt = 0; mt < 8; ++mt) {
      f32x4 c4 = {0.f, 0.f, 0.f, 0.f};
#pragma unroll
      for (int ks = 0; ks < 4; ++ks) {
        U16 av2; av2.u = wef_s[(ks * 8 + mt) * 64 + lane];
        U16 bv2; bv2.u.x = bfu[ks][0]; bv2.u.y = bfu[ks][1];
        bv2.u.z = bfu[ks][2]; bv2.u.w = bfu[ks][3];
        c4 = __builtin_amdgcn_mfma_f32_16x16x32_f16(av2.h, bv2.h, c4, 0, 0, 0);
      }
      uint4 t = v4[mt >> 1];
      unsigned vlo = (mt & 1) ? t.z : t.x;
      unsigned vhi = (mt & 1) ? t.w : t.y;
      U4h v0, v1; v0.u = vlo; v1.u = vhi;
      int hh = mt >> 1;
      acc[mt][0] = fmaf(w_[hh], (float)v0.h.x + c4[0], acc[mt][0]);
      acc[mt][1] = fmaf(w_[hh], (float)v0.h.y + c4[1], acc[mt][1]);
      acc[mt][2] = fmaf(w_[hh], (float)v1.h.x + c4[2], acc[mt][2]);
      acc[mt][3] = fmaf(w_[hh], (float)v1.h.y + c4[3], acc[mt][3]);
    }

    rel = nrel; mg = nmg; srcl = nsrc; aw = naw;
  }

  // reduce den + acc over the 16 edge-lanes
#pragma unroll
  for (int h = 0; h < 4; ++h) {
    float v = lh[h];
    v += __shfl_xor(v, 1); v += __shfl_xor(v, 2);
    v += __shfl_xor(v, 4); v += __shfl_xor(v, 8);
    lh[h] = v;
  }
#pragma unroll
  for (int mt = 0; mt < 8; ++mt)
#pragma unroll
    for (int r = 0; r < 4; ++r) {
      float v = acc[mt][r];
      v += __shfl_xor(v, 1); v += __shfl_xor(v, 2);
      v += __shfl_xor(v, 4); v += __shfl_xor(v, 8);
      acc[mt][r] = v;
    }
  if (ed == 0) {
#pragma unroll
    for (int mt = 0; mt < 8; ++mt)
#pragma unroll
      for (int r = 0; r < 4; ++r)
        accs_s[wid][mt * 16 + g * 4 + r] = acc[mt][r];
  }
  __asm__ volatile("s_waitcnt lgkmcnt(0)" ::: "memory");

  // epilogue: skip + relu + layernorm; lane owns channels 2L, 2L+1
  float iv = 1.f / (lh[g] + 1e-16f);
  float2 av2 = *(const float2*)&accs_s[wid][2 * lane];
  U4h s2; s2.u = *(const unsigned*)&S16[(size_t)node * 128 + 2 * lane];
  float r0 = fmaxf(fmaf(av2.x, iv, (float)s2.h.x), 0.f);
  float r1 = fmaxf(fmaf(av2.y, iv, (float)s2.h.y), 0.f);

  float sum = r0 + r1;
#pragma unroll
  for (int o = 1; o < 64; o <<= 1) sum += __shfl_xor(sum, o);
  float mu = sum * 0.0078125f;
  float d0 = r0 - mu, d1 = r1 - mu;
  float vs = d0 * d0 + d1 * d1;
#pragma unroll
  for (int o = 1; o < 64; o <<= 1) vs += __shfl_xor(vs, o);
  float rstd = rsqrtf(vs * 0.0078125f + 1e-5f);
  float2 gm = ((const float2*)gamma)[lane], bb = ((const float2*)beta)[lane];
  ((float2*)out)[node * 64 + lane] =
      make_float2(d0 * rstd * gm.x + bb.x, d1 * rstd * gm.y + bb.y);
}

// ---------------- launch ----------------
// ws (bytes): Q16 0 | S16 12.8M | K16 25.6M | V16 38.4M | Z16 51.2M (41.6M)
//   deg 92.8M | cur 93.0M | off 93.2M | elist 93,400,064 | wef 96,600,064
//   alpha16 96,632,832 (6.4M) | maxb 103,032,832 (0.8M) | end 103,832,832
extern "C" void kernel_launch(void* const* d_in, const int* in_sizes, int n_in,
                              void* d_out, int out_size, void* d_ws, size_t ws_size,
                              hipStream_t stream)
{
  (void)in_sizes; (void)n_in; (void)out_size;
  if (ws_size < 103832832u) return;

  const float* x     = (const float*)d_in[0];
  const float* msg   = (const float*)d_in[1];
  const float* Wt    = (const float*)d_in[2];
  const float* bt    = (const float*)d_in[3];
  const float* Wq    = (const float*)d_in[4];
  const float* bq    = (const float*)d_in[5];
  const float* Wk    = (const float*)d_in[6];
  const float* bk    = (const float*)d_in[7];
  const float* Wv    = (const float*)d_in[8];
  const float* bv    = (const float*)d_in[9];
  const float* We    = (const float*)d_in[10];
  const float* Wskip = (const float*)d_in[11];
  const float* bskip = (const float*)d_in[12];
  const float* gamma = (const float*)d_in[13];
  const float* beta  = (const float*)d_in[14];
  const int* last_update = (const int*)d_in[15];
  const int* ei    = (const int*)d_in[16];
  const int* tt    = (const int*)d_in[17];

  char* ws = (char*)d_ws;
  _Float16* Q16 = (_Float16*)(ws);
  _Float16* S16 = (_Float16*)(ws + 12800000);
  _Float16* K16 = (_Float16*)(ws + 25600000);
  _Float16* V16 = (_Float16*)(ws + 38400000);
  _Float16* Z16 = (_Float16*)(ws + 51200000);
  int* deg   = (int*)(ws + 92800000);
  int* cur   = (int*)(ws + 93000000);
  int* off   = (int*)(ws + 93200000);
  int* elist = (int*)(ws + 93400064);
  uint4* wef = (uint4*)(ws + 96600064);
  uint2* alpha16 = (uint2*)(ws + 96632832);
  unsigned* maxb = (unsigned*)(ws + 103032832);

  (void)hipMemsetAsync(deg, 0, 400000, stream);        // deg + cur
  k_wefrag<<<8, 256, 0, stream>>>(We, wef);
  k_deg <<<(NE + 255) / 256, 256, 0, stream>>>(ei, deg, maxb);
  k_scan<<<1, 1024, 0, stream>>>(deg, off);
  k_fill<<<(NE + 255) / 256, 256, 0, stream>>>(ei, off, cur, elist);
  dim3 pg(8, (NN + 63) / 64);
  k_proj<<<pg, 256, 0, stream>>>(x, Wq, bq, Wk, bk, Wv, bv, Wskip, bskip, We,
                                 Q16, K16, V16, S16, Z16);
  k_alpha<<<NE / 64, 256, 0, stream>>>(Q16, K16, (const unsigned*)Z16, Wt, bt,
                                       msg, last_update, ei, tt, alpha16, maxb);
  k_aggr<<<NN / 4, 256, 0, stream>>>(V16, S16, Wt, bt, wef, gamma, beta,
                                     msg, last_update, ei, tt, off, elist,
                                     alpha16, maxb, (float*)d_out);
}

// Round 10
// 579.590 us; speedup vs baseline: 1.7470x; 1.6361x over previous
//
#include <hip/hip_runtime.h>
#include <math.h>

#define NN 50000
#define NE 800000
#define TDIM 100
#define MAXCH 100000   // upper bound on total chunks: sum ceil(deg/16) <= NN + NE/16

typedef _Float16 half2v __attribute__((ext_vector_type(2)));
typedef _Float16 half4v __attribute__((ext_vector_type(4)));
typedef _Float16 half8v __attribute__((ext_vector_type(8)));
typedef __fp16 fp16x2 __attribute__((ext_vector_type(2)));
typedef float f32x4 __attribute__((ext_vector_type(4)));

union U16 { uint4 u; half8v h; };
union U4h { unsigned u; half2v h; };

// cos(x) matching np.cos(float32) to ~1e-6.
__device__ __forceinline__ float ref_cosf(float x) {
  const float C1 = 0.15915494f;
  const float C2 = 6.42063831e-9f;
  float p = x * C1;
  float r = __fmaf_rn(x, C1, -p);
  r = __fmaf_rn(x, C2, r);
  float n = rintf(p);
  float f = (p - n) + r;
  return __builtin_amdgcn_cosf(f);
}

__device__ __forceinline__ unsigned pk16(float a, float b) {
  fp16x2 h = __builtin_amdgcn_cvt_pkrtz(a, b);
  unsigned u;
  __builtin_memcpy(&u, &h, 4);
  return u;
}

// attr fragments: lane slice g, j = ks*32 + g*8 + 2p (+1); j>100 -> 0
__device__ __forceinline__ void build_bfu(float rel_b, float mg_b, int g,
                                          const float2* wtbt_s, unsigned bfu[4][4]) {
#pragma unroll
  for (int ks = 0; ks < 4; ++ks) {
#pragma unroll
    for (int p = 0; p < 4; ++p) {
      int j0 = ks * 32 + g * 8 + 2 * p;
      float a0 = 0.f, a1 = 0.f;
      if (ks < 3) {
        float2 w0 = wtbt_s[j0], w1 = wtbt_s[j0 + 1];
        a0 = ref_cosf(__fmaf_rn(rel_b, w0.x, w0.y));
        a1 = ref_cosf(__fmaf_rn(rel_b, w1.x, w1.y));
      } else {
        if (j0 < 100) {
          float2 w0 = wtbt_s[j0];
          a0 = ref_cosf(__fmaf_rn(rel_b, w0.x, w0.y));
        } else if (j0 == 100) a0 = mg_b;
        if (j0 + 1 < 100) {
          float2 w1 = wtbt_s[j0 + 1];
          a1 = ref_cosf(__fmaf_rn(rel_b, w1.x, w1.y));
        } else if (j0 + 1 == 100) a1 = mg_b;
      }
      bfu[ks][p] = pk16(a0, a1);
    }
  }
}

// ---------------- projection GEMM ----------------
// Q,K,V stored PERMUTED: channel c -> ((c>>2)&3)*32 + (c>>4)*4 + (c&3), so a
// lane's 32 channels {mt*16+g*4+r} are one contiguous 64B block at g*32.
// In this layout, block i of the 4 uint4s covers mt=2i,2i+1 == HEAD i.
// S stored natural. All f16.
#define PBK 16
__global__ void k_proj(
    const float* __restrict__ x,
    const float* __restrict__ Wq, const float* __restrict__ bq,
    const float* __restrict__ Wk, const float* __restrict__ bk,
    const float* __restrict__ Wv, const float* __restrict__ bv,
    const float* __restrict__ Wskip, const float* __restrict__ bskip,
    _Float16* __restrict__ Q16, _Float16* __restrict__ K16,
    _Float16* __restrict__ V16, _Float16* __restrict__ S16)
{
  __shared__ float a_s[PBK][68];
  __shared__ float b_s[PBK][64];

  const int tid = threadIdx.x;
  const int cy = blockIdx.x;
  const int n0 = blockIdx.y * 64;

  const float* W    = (cy < 2) ? Wq : (cy < 4) ? Wk : (cy < 6) ? Wv : Wskip;
  const float* bias = (cy < 2) ? bq : (cy < 4) ? bk : (cy < 6) ? bv : bskip;
  _Float16* dst     = (cy < 2) ? Q16 : (cy < 4) ? K16 : (cy < 6) ? V16 : S16;
  const int cb = (cy & 1) * 64;

  const int ty = tid >> 4, tx = tid & 15;
  const int lrow = tid >> 2, lk4 = (tid & 3) << 2;
  const int lc = tid & 63, lk0 = tid >> 6;

  float acc[4][4];
#pragma unroll
  for (int r = 0; r < 4; ++r)
#pragma unroll
    for (int j = 0; j < 4; ++j) acc[r][j] = 0.f;

  for (int kt = 0; kt < 128; kt += PBK) {
    float4 av = make_float4(0.f, 0.f, 0.f, 0.f);
    if (n0 + lrow < NN)
      av = *(const float4*)&x[(size_t)(n0 + lrow) * 128 + kt + lk4];
    a_s[lk4 + 0][lrow] = av.x; a_s[lk4 + 1][lrow] = av.y;
    a_s[lk4 + 2][lrow] = av.z; a_s[lk4 + 3][lrow] = av.w;
#pragma unroll
    for (int i = 0; i < 4; ++i) {
      int k = lk0 + (i << 2);
      b_s[k][lc] = W[(kt + k) * 128 + cb + lc];
    }
    __syncthreads();
#pragma unroll
    for (int k = 0; k < PBK; ++k) {
      float4 a = *(const float4*)&a_s[k][ty << 2];
      float4 b = *(const float4*)&b_s[k][tx << 2];
      acc[0][0] = fmaf(a.x, b.x, acc[0][0]); acc[0][1] = fmaf(a.x, b.y, acc[0][1]);
      acc[0][2] = fmaf(a.x, b.z, acc[0][2]); acc[0][3] = fmaf(a.x, b.w, acc[0][3]);
      acc[1][0] = fmaf(a.y, b.x, acc[1][0]); acc[1][1] = fmaf(a.y, b.y, acc[1][1]);
      acc[1][2] = fmaf(a.y, b.z, acc[1][2]); acc[1][3] = fmaf(a.y, b.w, acc[1][3]);
      acc[2][0] = fmaf(a.z, b.x, acc[2][0]); acc[2][1] = fmaf(a.z, b.y, acc[2][1]);
      acc[2][2] = fmaf(a.z, b.z, acc[2][2]); acc[2][3] = fmaf(a.z, b.w, acc[2][3]);
      acc[3][0] = fmaf(a.w, b.x, acc[3][0]); acc[3][1] = fmaf(a.w, b.y, acc[3][1]);
      acc[3][2] = fmaf(a.w, b.z, acc[3][2]); acc[3][3] = fmaf(a.w, b.w, acc[3][3]);
    }
    __syncthreads();
  }

  float4 bb = *(const float4*)&bias[cb + (tx << 2)];
  int c = cb + (tx << 2);
  int pidx = (cy < 6) ? ((((c >> 2) & 3) << 5) | ((c >> 4) << 2)) : c;
#pragma unroll
  for (int r = 0; r < 4; ++r) {
#pragma unroll
    for (int j = 0; j < 4; ++j) acc[r][j] += (&bb.x)[j];
    int row = n0 + (ty << 2) + r;
    if (row < NN) {
      half4v h;
      h.x = (_Float16)acc[r][0]; h.y = (_Float16)acc[r][1];
      h.z = (_Float16)acc[r][2]; h.w = (_Float16)acc[r][3];
      *(half4v*)&dst[(size_t)row * 128 + pidx] = h;
    }
  }
}

// ---------------- We^T A-fragment precompute (32 KB) -----------------------
__global__ void k_wefrag(const float* __restrict__ We, uint4* __restrict__ frag) {
  int idx = blockIdx.x * 256 + threadIdx.x;
  if (idx >= 2048) return;
  int lane = idx & 63, fi = idx >> 6;
  int ks = fi >> 3, mt = fi & 7;
  int ch = mt * 16 + (lane & 15);
  int k0 = ks * 32 + ((lane >> 4) << 3);
  U16 cv;
#pragma unroll
  for (int jj = 0; jj < 8; ++jj) {
    int j = k0 + jj;
    cv.h[jj] = (j <= 100) ? (_Float16)We[j * 128 + ch] : (_Float16)0.f;
  }
  frag[idx] = cv.u;
}

// ---------------- CSR + chunk-table build ----------------
__global__ void k_deg(const int* __restrict__ ei, int* __restrict__ deg) {
  int e = blockIdx.x * 256 + threadIdx.x;
  if (e < NE) atomicAdd(&deg[ei[NE + e]], 1);
}

#define SCHUNK 49
__global__ __launch_bounds__(1024) void k_scan(const int* __restrict__ deg,
                                               int* __restrict__ off,
                                               int* __restrict__ choff) {
  __shared__ int s[1024];
  const int t = threadIdx.x;
  const int base = t * SCHUNK;
  int sum = 0;
  for (int i = 0; i < SCHUNK; ++i) {
    int idx = base + i;
    sum += (idx < NN) ? deg[idx] : 0;
  }
  s[t] = sum;
  __syncthreads();
  for (int o = 1; o < 1024; o <<= 1) {
    int v = 0;
    if (t >= o) v = s[t - o];
    __syncthreads();
    if (t >= o) s[t] += v;
    __syncthreads();
  }
  int run = s[t] - sum;
  for (int i = 0; i < SCHUNK; ++i) {
    int idx = base + i;
    if (idx < NN) { off[idx] = run; run += deg[idx]; }
  }
  if (t == 1023) off[NN] = s[1023];
  __syncthreads();
  int sum2 = 0;
  for (int i = 0; i < SCHUNK; ++i) {
    int idx = base + i;
    sum2 += (idx < NN) ? ((deg[idx] + 15) >> 4) : 0;
  }
  s[t] = sum2;
  __syncthreads();
  for (int o = 1; o < 1024; o <<= 1) {
    int v = 0;
    if (t >= o) v = s[t - o];
    __syncthreads();
    if (t >= o) s[t] += v;
    __syncthreads();
  }
  int run2 = s[t] - sum2;
  for (int i = 0; i < SCHUNK; ++i) {
    int idx = base + i;
    if (idx < NN) { choff[idx] = run2; run2 += (deg[idx] + 15) >> 4; }
  }
  if (t == 1023) choff[NN] = s[1023];
}

__global__ void k_fill(const int* __restrict__ ei, const int* __restrict__ off,
                       int* __restrict__ cur, int* __restrict__ elist) {
  int e = blockIdx.x * 256 + threadIdx.x;
  if (e < NE) {
    int d = ei[NE + e];
    int p = atomicAdd(&cur[d], 1);
    elist[off[d] + p] = e;
  }
}

__global__ void k_chunkfill(const int* __restrict__ deg, const int* __restrict__ off,
                            const int* __restrict__ choff, uint2* __restrict__ chunks) {
  int n = blockIdx.x * 256 + threadIdx.x;
  if (n >= NN) return;
  int d = deg[n], o = off[n], c = choff[n];
  int nch = (d + 15) >> 4;
  for (int j = 0; j < nch; ++j) {
    int cnt = d - 16 * j; if (cnt > 16) cnt = 16;
    chunks[c + j] = make_uint2((unsigned)(o + 16 * j),
                               ((unsigned)n << 5) | (unsigned)cnt);
  }
}

// ---------------- k_edge: one straight-line wave per 16-edge chunk ----------
// gathers -> cos -> MFMA e -> PER-HEAD alpha (head i = uint4 block i in the
// permuted layout) -> per-head chunk softmax -> partial num -> 256B write.
__global__ __launch_bounds__(256) void k_edge(
    const _Float16* __restrict__ Q16, const _Float16* __restrict__ K16,
    const _Float16* __restrict__ V16,
    const float* __restrict__ Wt, const float* __restrict__ bt,
    const uint4* __restrict__ wefrag,
    const float* __restrict__ msg, const int* __restrict__ last_update,
    const int* __restrict__ ei, const int* __restrict__ tt,
    const int* __restrict__ elist, const uint2* __restrict__ chunks,
    const int* __restrict__ choff,
    unsigned* __restrict__ numbuf, float4* __restrict__ mdm,
    float4* __restrict__ mdd)
{
  __shared__ uint4 wef_s[2048];
  __shared__ float2 wtbt_s[104];
  __shared__ float accs_s[4][128];

  for (int i = threadIdx.x; i < 2048; i += 256) wef_s[i] = wefrag[i];
  if (threadIdx.x < 104) {
    int j = threadIdx.x;
    wtbt_s[j] = make_float2(j < TDIM ? Wt[j] : 0.f, j < TDIM ? bt[j] : 0.f);
  }
  __syncthreads();

  const int wid = threadIdx.x >> 6, lane = threadIdx.x & 63;
  const int chunk = blockIdx.x * 4 + wid;
  if (chunk >= choff[NN]) return;

  uint2 ce = chunks[chunk];
  const int estart = (int)ce.x;
  const int node = (int)(ce.y >> 5);
  const int cnt = (int)(ce.y & 31u);
  const int g = lane >> 4, ed = lane & 15;

  float rel = 0.f, mg = 0.f; int srcl = 0;
  if (lane < cnt) {
    int eid = elist[estart + lane];
    srcl = ei[eid];
    mg = msg[eid];
    rel = (float)(last_update[srcl] - tt[eid]);
  }
  float rel_b = __shfl(rel, ed);
  float mg_b  = __shfl(mg, ed);
  int   src_b = __shfl(srcl, ed);
  const bool valid = (ed < cnt);

  unsigned bfu[4][4];
  build_bfu(rel_b, mg_b, g, wtbt_s, bfu);

  // e via MFMA: ec[mt][r] = e[ed][mt*16+g*4+r]
  f32x4 ec[8];
#pragma unroll
  for (int mt = 0; mt < 8; ++mt) {
    f32x4 c4 = {0.f, 0.f, 0.f, 0.f};
#pragma unroll
    for (int ks = 0; ks < 4; ++ks) {
      U16 av2; av2.u = wef_s[(ks * 8 + mt) * 64 + lane];
      U16 bv2; bv2.u.x = bfu[ks][0]; bv2.u.y = bfu[ks][1];
      bv2.u.z = bfu[ks][2]; bv2.u.w = bfu[ks][3];
      c4 = __builtin_amdgcn_mfma_f32_16x16x32_f16(av2.h, bv2.h, c4, 0, 0, 0);
    }
    ec[mt] = c4;
  }

  // per-head partial alpha: uint4 block i covers mt=2i,2i+1 == head i
  float pal[4];
  {
    const uint4* qp = (const uint4*)&Q16[(size_t)node * 128 + g * 32];
    const uint4* kp = (const uint4*)&K16[(size_t)src_b * 128 + g * 32];
#pragma unroll
    for (int i = 0; i < 4; ++i) {
      uint4 qa = qp[i], ka = kp[i];
      U4h q0, q1, q2, q3, k0, k1, k2, k3;
      q0.u = qa.x; q1.u = qa.y; q2.u = qa.z; q3.u = qa.w;
      k0.u = ka.x; k1.u = ka.y; k2.u = ka.z; k3.u = ka.w;
      int mA = 2 * i, mB = 2 * i + 1;
      float p = 0.f;
      p = fmaf((float)q0.h.x, (float)k0.h.x + ec[mA][0], p);
      p = fmaf((float)q0.h.y, (float)k0.h.y + ec[mA][1], p);
      p = fmaf((float)q1.h.x, (float)k1.h.x + ec[mA][2], p);
      p = fmaf((float)q1.h.y, (float)k1.h.y + ec[mA][3], p);
      p = fmaf((float)q2.h.x, (float)k2.h.x + ec[mB][0], p);
      p = fmaf((float)q2.h.y, (float)k2.h.y + ec[mB][1], p);
      p = fmaf((float)q3.h.x, (float)k3.h.x + ec[mB][2], p);
      p = fmaf((float)q3.h.y, (float)k3.h.y + ec[mB][3], p);
      pal[i] = p;
    }
  }

  // per-head: complete dot across g-lanes, chunk softmax over ed-lanes
  float m_[4], w_[4], d_[4];
#pragma unroll
  for (int h = 0; h < 4; ++h) {
    float p = pal[h];
    p += __shfl_xor(p, 16); p += __shfl_xor(p, 32);
    float al = valid ? p * 0.17677669529663689f : -INFINITY;
    float mm = al;
    mm = fmaxf(mm, __shfl_xor(mm, 1)); mm = fmaxf(mm, __shfl_xor(mm, 2));
    mm = fmaxf(mm, __shfl_xor(mm, 4)); mm = fmaxf(mm, __shfl_xor(mm, 8));
    m_[h] = mm;
    w_[h] = __expf(al - mm);       // invalid -> 0
    float s = w_[h];
    s += __shfl_xor(s, 1); s += __shfl_xor(s, 2);
    s += __shfl_xor(s, 4); s += __shfl_xor(s, 8);
    d_[h] = s;
  }

  // partial num: overwrite ec in place; weight w_[head] = w_[i]
  {
    const uint4* vp = (const uint4*)&V16[(size_t)src_b * 128 + g * 32];
#pragma unroll
    for (int i = 0; i < 4; ++i) {
      uint4 va = vp[i];
      U4h v0, v1, v2, v3;
      v0.u = va.x; v1.u = va.y; v2.u = va.z; v3.u = va.w;
      int mA = 2 * i, mB = 2 * i + 1;
      float wi = w_[i];
      ec[mA][0] = wi * ((float)v0.h.x + ec[mA][0]);
      ec[mA][1] = wi * ((float)v0.h.y + ec[mA][1]);
      ec[mA][2] = wi * ((float)v1.h.x + ec[mA][2]);
      ec[mA][3] = wi * ((float)v1.h.y + ec[mA][3]);
      ec[mB][0] = wi * ((float)v2.h.x + ec[mB][0]);
      ec[mB][1] = wi * ((float)v2.h.y + ec[mB][1]);
      ec[mB][2] = wi * ((float)v3.h.x + ec[mB][2]);
      ec[mB][3] = wi * ((float)v3.h.y + ec[mB][3]);
    }
  }

  // reduce over the 16 edge-lanes
#pragma unroll
  for (int mt = 0; mt < 8; ++mt)
#pragma unroll
    for (int r = 0; r < 4; ++r) {
      float v = ec[mt][r];
      v += __shfl_xor(v, 1); v += __shfl_xor(v, 2);
      v += __shfl_xor(v, 4); v += __shfl_xor(v, 8);
      ec[mt][r] = v;
    }
  if (ed == 0) {
#pragma unroll
    for (int mt = 0; mt < 8; ++mt)
#pragma unroll
      for (int r = 0; r < 4; ++r)
        accs_s[wid][mt * 16 + g * 4 + r] = ec[mt][r];
  }
  __asm__ volatile("s_waitcnt lgkmcnt(0)" ::: "memory");

  float2 nv = *(const float2*)&accs_s[wid][2 * lane];
  numbuf[(size_t)chunk * 64 + lane] = pk16(nv.x, nv.y);
  if (lane == 0) {
    mdm[chunk] = make_float4(m_[0], m_[1], m_[2], m_[3]);
    mdd[chunk] = make_float4(d_[0], d_[1], d_[2], d_[3]);
  }
}

// ---------------- k_comb: per-head flash combine + skip/relu/layernorm ------
__global__ __launch_bounds__(256) void k_comb(
    const unsigned* __restrict__ numbuf, const float* __restrict__ mdmf,
    const float* __restrict__ mddf, const _Float16* __restrict__ S16,
    const float* __restrict__ gamma, const float* __restrict__ beta,
    const int* __restrict__ choff, float* __restrict__ out)
{
  const int wid = threadIdx.x >> 6, lane = threadIdx.x & 63;
  const int node = blockIdx.x * 4 + wid;
  const int g = lane >> 4;          // head of channels 2*lane, 2*lane+1
  const int c0 = choff[node], c1 = choff[node + 1];

  float M = -INFINITY;
  for (int c = c0; c < c1; ++c) M = fmaxf(M, mdmf[c * 4 + g]);

  float den = 0.f, n0 = 0.f, n1 = 0.f;
  for (int c = c0; c < c1; ++c) {
    float sc = __expf(mdmf[c * 4 + g] - M);
    den = fmaf(mddf[c * 4 + g], sc, den);
    U4h u; u.u = numbuf[(size_t)c * 64 + lane];
    n0 = fmaf((float)u.h.x, sc, n0);
    n1 = fmaf((float)u.h.y, sc, n1);
  }

  float iv = 1.f / (den + 1e-16f);
  U4h s2; s2.u = *(const unsigned*)&S16[(size_t)node * 128 + 2 * lane];
  float r0 = fmaxf(fmaf(n0, iv, (float)s2.h.x), 0.f);
  float r1 = fmaxf(fmaf(n1, iv, (float)s2.h.y), 0.f);

  float sum = r0 + r1;
#pragma unroll
  for (int o = 1; o < 64; o <<= 1) sum += __shfl_xor(sum, o);
  float mu = sum * 0.0078125f;
  float d0 = r0 - mu, d1 = r1 - mu;
  float vs = d0 * d0 + d1 * d1;
#pragma unroll
  for (int o = 1; o < 64; o <<= 1) vs += __shfl_xor(vs, o);
  float rstd = rsqrtf(vs * 0.0078125f + 1e-5f);
  float2 gm = ((const float2*)gamma)[lane], bb = ((const float2*)beta)[lane];
  ((float2*)out)[node * 64 + lane] =
      make_float2(d0 * rstd * gm.x + bb.x, d1 * rstd * gm.y + bb.y);
}

// ---------------- launch ----------------
// ws (bytes): Q16 0 | S16 12.8M | K16 25.6M | V16 38.4M | numbuf 51.2M (25.6M)
//   deg 76.8M | cur 77.0M | off 77.2M | choff 77,400,064 | elist 77,600,128
//   wef 80,800,128 | chunks 80,832,896 | mdm 81,632,896 | mdd 83,232,896
//   end 84,832,896
extern "C" void kernel_launch(void* const* d_in, const int* in_sizes, int n_in,
                              void* d_out, int out_size, void* d_ws, size_t ws_size,
                              hipStream_t stream)
{
  (void)in_sizes; (void)n_in; (void)out_size;
  if (ws_size < 84832896u) return;

  const float* x     = (const float*)d_in[0];
  const float* msg   = (const float*)d_in[1];
  const float* Wt    = (const float*)d_in[2];
  const float* bt    = (const float*)d_in[3];
  const float* Wq    = (const float*)d_in[4];
  const float* bq    = (const float*)d_in[5];
  const float* Wk    = (const float*)d_in[6];
  const float* bk    = (const float*)d_in[7];
  const float* Wv    = (const float*)d_in[8];
  const float* bv    = (const float*)d_in[9];
  const float* We    = (const float*)d_in[10];
  const float* Wskip = (const float*)d_in[11];
  const float* bskip = (const float*)d_in[12];
  const float* gamma = (const float*)d_in[13];
  const float* beta  = (const float*)d_in[14];
  const int* last_update = (const int*)d_in[15];
  const int* ei    = (const int*)d_in[16];
  const int* tt    = (const int*)d_in[17];

  char* ws = (char*)d_ws;
  _Float16* Q16 = (_Float16*)(ws);
  _Float16* S16 = (_Float16*)(ws + 12800000);
  _Float16* K16 = (_Float16*)(ws + 25600000);
  _Float16* V16 = (_Float16*)(ws + 38400000);
  unsigned* numbuf = (unsigned*)(ws + 51200000);
  int* deg   = (int*)(ws + 76800000);
  int* cur   = (int*)(ws + 77000000);
  int* off   = (int*)(ws + 77200000);
  int* choff = (int*)(ws + 77400064);
  int* elist = (int*)(ws + 77600128);
  uint4* wef = (uint4*)(ws + 80800128);
  uint2* chunks = (uint2*)(ws + 80832896);
  float4* mdm = (float4*)(ws + 81632896);
  float4* mdd = (float4*)(ws + 83232896);

  (void)hipMemsetAsync(deg, 0, 400000, stream);        // deg + cur
  k_wefrag<<<8, 256, 0, stream>>>(We, wef);
  k_deg <<<(NE + 255) / 256, 256, 0, stream>>>(ei, deg);
  k_scan<<<1, 1024, 0, stream>>>(deg, off, choff);
  k_fill<<<(NE + 255) / 256, 256, 0, stream>>>(ei, off, cur, elist);
  k_chunkfill<<<(NN + 255) / 256, 256, 0, stream>>>(deg, off, choff, chunks);
  dim3 pg(8, (NN + 63) / 64);
  k_proj<<<pg, 256, 0, stream>>>(x, Wq, bq, Wk, bk, Wv, bv, Wskip, bskip,
                                 Q16, K16, V16, S16);
  k_edge<<<MAXCH / 4, 256, 0, stream>>>(Q16, K16, V16, Wt, bt, wef,
                                        msg, last_update, ei, tt, elist,
                                        chunks, choff, numbuf, mdm, mdd);
  k_comb<<<NN / 4, 256, 0, stream>>>(numbuf, (const float*)mdm, (const float*)mdd,
                                     S16, gamma, beta, choff, (float*)d_out);
}

// Round 11
// 506.854 us; speedup vs baseline: 1.9977x; 1.1435x over previous
//
#include <hip/hip_runtime.h>
#include <math.h>

#define NN 50000
#define NE 800000
#define TDIM 100
#define MAXCH 100000   // upper bound on total chunks: sum ceil(deg/16) <= NN + NE/16

typedef _Float16 half2v __attribute__((ext_vector_type(2)));
typedef _Float16 half4v __attribute__((ext_vector_type(4)));
typedef _Float16 half8v __attribute__((ext_vector_type(8)));
typedef __fp16 fp16x2 __attribute__((ext_vector_type(2)));
typedef float f32x4 __attribute__((ext_vector_type(4)));

union U16 { uint4 u; half8v h; };
union U4h { unsigned u; half2v h; };

// cos(x) matching np.cos(float32) to ~1e-6.
__device__ __forceinline__ float ref_cosf(float x) {
  const float C1 = 0.15915494f;
  const float C2 = 6.42063831e-9f;
  float p = x * C1;
  float r = __fmaf_rn(x, C1, -p);
  r = __fmaf_rn(x, C2, r);
  float n = rintf(p);
  float f = (p - n) + r;
  return __builtin_amdgcn_cosf(f);
}

__device__ __forceinline__ unsigned pk16(float a, float b) {
  fp16x2 h = __builtin_amdgcn_cvt_pkrtz(a, b);
  unsigned u;
  __builtin_memcpy(&u, &h, 4);
  return u;
}

// attr fragments: lane slice g, j = ks*32 + g*8 + 2p (+1); j>100 -> 0
__device__ __forceinline__ void build_bfu(float rel_b, float mg_b, int g,
                                          const float2* wtbt_s, unsigned bfu[4][4]) {
#pragma unroll
  for (int ks = 0; ks < 4; ++ks) {
#pragma unroll
    for (int p = 0; p < 4; ++p) {
      int j0 = ks * 32 + g * 8 + 2 * p;
      float a0 = 0.f, a1 = 0.f;
      if (ks < 3) {
        float2 w0 = wtbt_s[j0], w1 = wtbt_s[j0 + 1];
        a0 = ref_cosf(__fmaf_rn(rel_b, w0.x, w0.y));
        a1 = ref_cosf(__fmaf_rn(rel_b, w1.x, w1.y));
      } else {
        if (j0 < 100) {
          float2 w0 = wtbt_s[j0];
          a0 = ref_cosf(__fmaf_rn(rel_b, w0.x, w0.y));
        } else if (j0 == 100) a0 = mg_b;
        if (j0 + 1 < 100) {
          float2 w1 = wtbt_s[j0 + 1];
          a1 = ref_cosf(__fmaf_rn(rel_b, w1.x, w1.y));
        } else if (j0 + 1 == 100) a1 = mg_b;
      }
      bfu[ks][p] = pk16(a0, a1);
    }
  }
}

// ---------------- fragment precompute: We (32KB) + projection W (128KB) -----
// wef: lane holds We[j = ks*32+(lane>>4)*8+jj][mt*16+(lane&15)], j>100 -> 0
// wpf: lane holds Wcy[k = ks*32+(lane>>4)*8+jj][nt*16+(lane&15)], cy=Q,K,V,S
__global__ void k_frag(const float* __restrict__ We,
                       const float* __restrict__ Wq, const float* __restrict__ Wk,
                       const float* __restrict__ Wv, const float* __restrict__ Wskip,
                       uint4* __restrict__ wef, uint4* __restrict__ wpf) {
  int idx = blockIdx.x * 256 + threadIdx.x;
  if (idx < 2048) {
    int lane = idx & 63, fi = idx >> 6;
    int ks = fi >> 3, mt = fi & 7;
    int ch = mt * 16 + (lane & 15);
    int k0 = ks * 32 + ((lane >> 4) << 3);
    U16 cv;
#pragma unroll
    for (int jj = 0; jj < 8; ++jj) {
      int j = k0 + jj;
      cv.h[jj] = (j <= 100) ? (_Float16)We[j * 128 + ch] : (_Float16)0.f;
    }
    wef[idx] = cv.u;
  } else if (idx < 2048 + 8192) {
    int i2 = idx - 2048;
    int lane = i2 & 63, fi = i2 >> 6;     // fi = (cy*4+ks)*8+nt
    int nt = fi & 7, ks = (fi >> 3) & 3, cy = fi >> 5;
    const float* W = (cy == 0) ? Wq : (cy == 1) ? Wk : (cy == 2) ? Wv : Wskip;
    int n = nt * 16 + (lane & 15);
    int k0 = ks * 32 + ((lane >> 4) << 3);
    U16 cv;
#pragma unroll
    for (int jj = 0; jj < 8; ++jj)
      cv.h[jj] = (_Float16)W[(k0 + jj) * 128 + n];
    wpf[i2] = cv.u;
  }
}

// ---------------- MFMA projection: 32 rows x 128 cols per block -------------
// Q,K,V stored PERMUTED: channel c -> ((c>>2)&3)*32 + (c>>4)*4 + (c&3).
// S natural. cy = blockIdx.x: 0=Q 1=K 2=V 3=S.
__global__ __launch_bounds__(256) void k_proj2(
    const float* __restrict__ x,
    const float* __restrict__ bq, const float* __restrict__ bk,
    const float* __restrict__ bv, const float* __restrict__ bskip,
    const uint4* __restrict__ wpf,
    _Float16* __restrict__ Q16, _Float16* __restrict__ K16,
    _Float16* __restrict__ V16, _Float16* __restrict__ S16)
{
  __shared__ unsigned xs[32][68];     // x rows as f16 pairs (272B pitch)
  __shared__ _Float16 os[32][136];    // output bounce (272B pitch)

  const int cy = blockIdx.x;
  const int n0 = blockIdx.y * 32;
  const int tid = threadIdx.x;
  const float* bias = (cy == 0) ? bq : (cy == 1) ? bk : (cy == 2) ? bv : bskip;
  _Float16* dst     = (cy == 0) ? Q16 : (cy == 1) ? K16 : (cy == 2) ? V16 : S16;

  {
    int r = tid >> 3, c16 = (tid & 7) * 16;
    int row = n0 + r;
    float4 v0 = {0,0,0,0}, v1 = {0,0,0,0}, v2 = {0,0,0,0}, v3 = {0,0,0,0};
    if (row < NN) {
      const float4* xp = (const float4*)&x[(size_t)row * 128 + c16];
      v0 = xp[0]; v1 = xp[1]; v2 = xp[2]; v3 = xp[3];
    }
    unsigned* xr = &xs[r][c16 >> 1];
    xr[0] = pk16(v0.x, v0.y); xr[1] = pk16(v0.z, v0.w);
    xr[2] = pk16(v1.x, v1.y); xr[3] = pk16(v1.z, v1.w);
    xr[4] = pk16(v2.x, v2.y); xr[5] = pk16(v2.z, v2.w);
    xr[6] = pk16(v3.x, v3.y); xr[7] = pk16(v3.z, v3.w);
  }
  __syncthreads();

  const int w = tid >> 6, lane = tid & 63;
  const int mrow = (w & 1) << 4;        // wave's 16-row tile
  const int nh = w >> 1;                // n-tiles nh*4 .. nh*4+3

  f32x4 acc[4] = {{0,0,0,0},{0,0,0,0},{0,0,0,0},{0,0,0,0}};
#pragma unroll
  for (int ks = 0; ks < 4; ++ks) {
    U16 a_; a_.u = *(const uint4*)&xs[mrow + (lane & 15)][ks * 16 + ((lane >> 4) << 2)];
#pragma unroll
    for (int nt = 0; nt < 4; ++nt) {
      U16 b_; b_.u = wpf[((cy * 4 + ks) * 8 + nh * 4 + nt) * 64 + lane];
      acc[nt] = __builtin_amdgcn_mfma_f32_16x16x32_f16(a_.h, b_.h, acc[nt], 0, 0, 0);
    }
  }

  // bias + stash to LDS (D: col=lane&15, row=(lane>>4)*4+reg)
#pragma unroll
  for (int nt = 0; nt < 4; ++nt) {
    int col = (nh * 4 + nt) * 16 + (lane & 15);
    float bb = bias[col];
    int rbase = mrow + ((lane >> 4) << 2);
#pragma unroll
    for (int reg = 0; reg < 4; ++reg)
      os[rbase + reg][col] = (_Float16)(acc[nt][reg] + bb);
  }
  __syncthreads();

  {
    int r = tid >> 3, c16 = (tid & 7) * 16;
    int row = n0 + r;
    if (row < NN) {
      const _Float16* op = &os[r][c16];
      if (cy < 3) {
#pragma unroll
        for (int q = 0; q < 4; ++q) {
          int j4 = (c16 >> 2) + q;
          int po = ((j4 & 3) << 5) | ((j4 >> 2) << 2);
          *(half4v*)&dst[(size_t)row * 128 + po] = *(const half4v*)&op[q * 4];
        }
      } else {
        *(uint4*)&dst[(size_t)row * 128 + c16]     = ((const uint4*)op)[0];
        *(uint4*)&dst[(size_t)row * 128 + c16 + 8] = ((const uint4*)op)[1];
      }
    }
  }
}

// ---------------- CSR + chunk-table build ----------------
__global__ void k_deg(const int* __restrict__ ei, int* __restrict__ deg) {
  int e = blockIdx.x * 256 + threadIdx.x;
  if (e < NE) atomicAdd(&deg[ei[NE + e]], 1);
}

#define SCHUNK 49
__global__ __launch_bounds__(1024) void k_scan(const int* __restrict__ deg,
                                               int* __restrict__ off,
                                               int* __restrict__ choff) {
  __shared__ int s[1024];
  const int t = threadIdx.x;
  const int base = t * SCHUNK;
  int sum = 0;
  for (int i = 0; i < SCHUNK; ++i) {
    int idx = base + i;
    sum += (idx < NN) ? deg[idx] : 0;
  }
  s[t] = sum;
  __syncthreads();
  for (int o = 1; o < 1024; o <<= 1) {
    int v = 0;
    if (t >= o) v = s[t - o];
    __syncthreads();
    if (t >= o) s[t] += v;
    __syncthreads();
  }
  int run = s[t] - sum;
  for (int i = 0; i < SCHUNK; ++i) {
    int idx = base + i;
    if (idx < NN) { off[idx] = run; run += deg[idx]; }
  }
  if (t == 1023) off[NN] = s[1023];
  __syncthreads();
  int sum2 = 0;
  for (int i = 0; i < SCHUNK; ++i) {
    int idx = base + i;
    sum2 += (idx < NN) ? ((deg[idx] + 15) >> 4) : 0;
  }
  s[t] = sum2;
  __syncthreads();
  for (int o = 1; o < 1024; o <<= 1) {
    int v = 0;
    if (t >= o) v = s[t - o];
    __syncthreads();
    if (t >= o) s[t] += v;
    __syncthreads();
  }
  int run2 = s[t] - sum2;
  for (int i = 0; i < SCHUNK; ++i) {
    int idx = base + i;
    if (idx < NN) { choff[idx] = run2; run2 += (deg[idx] + 15) >> 4; }
  }
  if (t == 1023) choff[NN] = s[1023];
}

// fused: blocks [0,3125) fill elist; blocks [3125,3321) build chunk table
__global__ void k_fillch(const int* __restrict__ ei, const int* __restrict__ deg,
                         const int* __restrict__ off, const int* __restrict__ choff,
                         int* __restrict__ cur, int* __restrict__ elist,
                         uint2* __restrict__ chunks) {
  int b = blockIdx.x;
  if (b < 3125) {
    int e = b * 256 + threadIdx.x;
    if (e < NE) {
      int d = ei[NE + e];
      int p = atomicAdd(&cur[d], 1);
      elist[off[d] + p] = e;
    }
  } else {
    int n = (b - 3125) * 256 + threadIdx.x;
    if (n < NN) {
      int d = deg[n], o = off[n], c = choff[n];
      int nch = (d + 15) >> 4;
      for (int j = 0; j < nch; ++j) {
        int cnt = d - 16 * j; if (cnt > 16) cnt = 16;
        chunks[c + j] = make_uint2((unsigned)(o + 16 * j),
                                   ((unsigned)n << 5) | (unsigned)cnt);
      }
    }
  }
}

// ---------------- k_edge: one straight-line wave per 16-edge chunk ----------
__global__ __launch_bounds__(256) void k_edge(
    const _Float16* __restrict__ Q16, const _Float16* __restrict__ K16,
    const _Float16* __restrict__ V16,
    const float* __restrict__ Wt, const float* __restrict__ bt,
    const uint4* __restrict__ wefrag,
    const float* __restrict__ msg, const int* __restrict__ last_update,
    const int* __restrict__ ei, const int* __restrict__ tt,
    const int* __restrict__ elist, const uint2* __restrict__ chunks,
    const int* __restrict__ choff,
    unsigned* __restrict__ numbuf, float4* __restrict__ mdm,
    float4* __restrict__ mdd)
{
  __shared__ uint4 wef_s[2048];
  __shared__ float2 wtbt_s[104];
  __shared__ float accs_s[4][128];

  for (int i = threadIdx.x; i < 2048; i += 256) wef_s[i] = wefrag[i];
  if (threadIdx.x < 104) {
    int j = threadIdx.x;
    wtbt_s[j] = make_float2(j < TDIM ? Wt[j] : 0.f, j < TDIM ? bt[j] : 0.f);
  }
  __syncthreads();

  const int wid = threadIdx.x >> 6, lane = threadIdx.x & 63;
  const int chunk = blockIdx.x * 4 + wid;
  if (chunk >= choff[NN]) return;

  uint2 ce = chunks[chunk];
  const int estart = (int)ce.x;
  const int node = (int)(ce.y >> 5);
  const int cnt = (int)(ce.y & 31u);
  const int g = lane >> 4, ed = lane & 15;

  float rel = 0.f, mg = 0.f; int srcl = 0;
  if (lane < cnt) {
    int eid = elist[estart + lane];
    srcl = ei[eid];
    mg = msg[eid];
    rel = (float)(last_update[srcl] - tt[eid]);
  }
  float rel_b = __shfl(rel, ed);
  float mg_b  = __shfl(mg, ed);
  int   src_b = __shfl(srcl, ed);
  const bool valid = (ed < cnt);

  unsigned bfu[4][4];
  build_bfu(rel_b, mg_b, g, wtbt_s, bfu);

  // e via MFMA: ec[mt][r] = e[ed][mt*16+g*4+r]
  f32x4 ec[8];
#pragma unroll
  for (int mt = 0; mt < 8; ++mt) {
    f32x4 c4 = {0.f, 0.f, 0.f, 0.f};
#pragma unroll
    for (int ks = 0; ks < 4; ++ks) {
      U16 av2; av2.u = wef_s[(ks * 8 + mt) * 64 + lane];
      U16 bv2; bv2.u.x = bfu[ks][0]; bv2.u.y = bfu[ks][1];
      bv2.u.z = bfu[ks][2]; bv2.u.w = bfu[ks][3];
      c4 = __builtin_amdgcn_mfma_f32_16x16x32_f16(av2.h, bv2.h, c4, 0, 0, 0);
    }
    ec[mt] = c4;
  }

  // per-head partial alpha: uint4 block i covers mt=2i,2i+1 == head i
  float pal[4];
  {
    const uint4* qp = (const uint4*)&Q16[(size_t)node * 128 + g * 32];
    const uint4* kp = (const uint4*)&K16[(size_t)src_b * 128 + g * 32];
#pragma unroll
    for (int i = 0; i < 4; ++i) {
      uint4 qa = qp[i], ka = kp[i];
      U4h q0, q1, q2, q3, k0, k1, k2, k3;
      q0.u = qa.x; q1.u = qa.y; q2.u = qa.z; q3.u = qa.w;
      k0.u = ka.x; k1.u = ka.y; k2.u = ka.z; k3.u = ka.w;
      int mA = 2 * i, mB = 2 * i + 1;
      float p = 0.f;
      p = fmaf((float)q0.h.x, (float)k0.h.x + ec[mA][0], p);
      p = fmaf((float)q0.h.y, (float)k0.h.y + ec[mA][1], p);
      p = fmaf((float)q1.h.x, (float)k1.h.x + ec[mA][2], p);
      p = fmaf((float)q1.h.y, (float)k1.h.y + ec[mA][3], p);
      p = fmaf((float)q2.h.x, (float)k2.h.x + ec[mB][0], p);
      p = fmaf((float)q2.h.y, (float)k2.h.y + ec[mB][1], p);
      p = fmaf((float)q3.h.x, (float)k3.h.x + ec[mB][2], p);
      p = fmaf((float)q3.h.y, (float)k3.h.y + ec[mB][3], p);
      pal[i] = p;
    }
  }

  // per-head: complete dot across g-lanes, chunk softmax over ed-lanes
  float m_[4], w_[4], d_[4];
#pragma unroll
  for (int h = 0; h < 4; ++h) {
    float p = pal[h];
    p += __shfl_xor(p, 16); p += __shfl_xor(p, 32);
    float al = valid ? p * 0.17677669529663689f : -INFINITY;
    float mm = al;
    mm = fmaxf(mm, __shfl_xor(mm, 1)); mm = fmaxf(mm, __shfl_xor(mm, 2));
    mm = fmaxf(mm, __shfl_xor(mm, 4)); mm = fmaxf(mm, __shfl_xor(mm, 8));
    m_[h] = mm;
    w_[h] = __expf(al - mm);       // invalid -> 0
    float s = w_[h];
    s += __shfl_xor(s, 1); s += __shfl_xor(s, 2);
    s += __shfl_xor(s, 4); s += __shfl_xor(s, 8);
    d_[h] = s;
  }

  // partial num: overwrite ec in place; weight w_[head]
  {
    const uint4* vp = (const uint4*)&V16[(size_t)src_b * 128 + g * 32];
#pragma unroll
    for (int i = 0; i < 4; ++i) {
      uint4 va = vp[i];
      U4h v0, v1, v2, v3;
      v0.u = va.x; v1.u = va.y; v2.u = va.z; v3.u = va.w;
      int mA = 2 * i, mB = 2 * i + 1;
      float wi = w_[i];
      ec[mA][0] = wi * ((float)v0.h.x + ec[mA][0]);
      ec[mA][1] = wi * ((float)v0.h.y + ec[mA][1]);
      ec[mA][2] = wi * ((float)v1.h.x + ec[mA][2]);
      ec[mA][3] = wi * ((float)v1.h.y + ec[mA][3]);
      ec[mB][0] = wi * ((float)v2.h.x + ec[mB][0]);
      ec[mB][1] = wi * ((float)v2.h.y + ec[mB][1]);
      ec[mB][2] = wi * ((float)v3.h.x + ec[mB][2]);
      ec[mB][3] = wi * ((float)v3.h.y + ec[mB][3]);
    }
  }

  // reduce over the 16 edge-lanes
#pragma unroll
  for (int mt = 0; mt < 8; ++mt)
#pragma unroll
    for (int r = 0; r < 4; ++r) {
      float v = ec[mt][r];
      v += __shfl_xor(v, 1); v += __shfl_xor(v, 2);
      v += __shfl_xor(v, 4); v += __shfl_xor(v, 8);
      ec[mt][r] = v;
    }
  if (ed == 0) {
#pragma unroll
    for (int mt = 0; mt < 8; ++mt)
#pragma unroll
      for (int r = 0; r < 4; ++r)
        accs_s[wid][mt * 16 + g * 4 + r] = ec[mt][r];
  }
  __asm__ volatile("s_waitcnt lgkmcnt(0)" ::: "memory");

  float2 nv = *(const float2*)&accs_s[wid][2 * lane];
  numbuf[(size_t)chunk * 64 + lane] = pk16(nv.x, nv.y);
  if (lane == 0) {
    mdm[chunk] = make_float4(m_[0], m_[1], m_[2], m_[3]);
    mdd[chunk] = make_float4(d_[0], d_[1], d_[2], d_[3]);
  }
}

// ---------------- k_comb: per-head flash combine + skip/relu/layernorm ------
__global__ __launch_bounds__(256) void k_comb(
    const unsigned* __restrict__ numbuf, const float* __restrict__ mdmf,
    const float* __restrict__ mddf, const _Float16* __restrict__ S16,
    const float* __restrict__ gamma, const float* __restrict__ beta,
    const int* __restrict__ choff, float* __restrict__ out)
{
  const int wid = threadIdx.x >> 6, lane = threadIdx.x & 63;
  const int node = blockIdx.x * 4 + wid;
  const int g = lane >> 4;          // head of channels 2*lane, 2*lane+1
  const int c0 = choff[node], c1 = choff[node + 1];

  float M = -INFINITY;
  for (int c = c0; c < c1; ++c) M = fmaxf(M, mdmf[c * 4 + g]);

  float den = 0.f, n0 = 0.f, n1 = 0.f;
  for (int c = c0; c < c1; ++c) {
    float sc = __expf(mdmf[c * 4 + g] - M);
    den = fmaf(mddf[c * 4 + g], sc, den);
    U4h u; u.u = numbuf[(size_t)c * 64 + lane];
    n0 = fmaf((float)u.h.x, sc, n0);
    n1 = fmaf((float)u.h.y, sc, n1);
  }

  float iv = 1.f / (den + 1e-16f);
  U4h s2; s2.u = *(const unsigned*)&S16[(size_t)node * 128 + 2 * lane];
  float r0 = fmaxf(fmaf(n0, iv, (float)s2.h.x), 0.f);
  float r1 = fmaxf(fmaf(n1, iv, (float)s2.h.y), 0.f);

  float sum = r0 + r1;
#pragma unroll
  for (int o = 1; o < 64; o <<= 1) sum += __shfl_xor(sum, o);
  float mu = sum * 0.0078125f;
  float d0 = r0 - mu, d1 = r1 - mu;
  float vs = d0 * d0 + d1 * d1;
#pragma unroll
  for (int o = 1; o < 64; o <<= 1) vs += __shfl_xor(vs, o);
  float rstd = rsqrtf(vs * 0.0078125f + 1e-5f);
  float2 gm = ((const float2*)gamma)[lane], bb = ((const float2*)beta)[lane];
  ((float2*)out)[node * 64 + lane] =
      make_float2(d0 * rstd * gm.x + bb.x, d1 * rstd * gm.y + bb.y);
}

// ---------------- launch ----------------
// ws (bytes): Q16 0 | S16 12.8M | K16 25.6M | V16 38.4M | numbuf 51.2M (25.6M)
//   deg 76.8M | cur 77.0M | off 77.2M | choff 77,400,064 | elist 77,600,128
//   wef 80,800,128 | chunks 80,832,896 | mdm 81,632,896 | mdd 83,232,896
//   wpf 84,832,896 (128KB) | end 84,963,968
extern "C" void kernel_launch(void* const* d_in, const int* in_sizes, int n_in,
                              void* d_out, int out_size, void* d_ws, size_t ws_size,
                              hipStream_t stream)
{
  (void)in_sizes; (void)n_in; (void)out_size;
  if (ws_size < 84963968u) return;

  const float* x     = (const float*)d_in[0];
  const float* msg   = (const float*)d_in[1];
  const float* Wt    = (const float*)d_in[2];
  const float* bt    = (const float*)d_in[3];
  const float* Wq    = (const float*)d_in[4];
  const float* bq    = (const float*)d_in[5];
  const float* Wk    = (const float*)d_in[6];
  const float* bk    = (const float*)d_in[7];
  const float* Wv    = (const float*)d_in[8];
  const float* bv    = (const float*)d_in[9];
  const float* We    = (const float*)d_in[10];
  const float* Wskip = (const float*)d_in[11];
  const float* bskip = (const float*)d_in[12];
  const float* gamma = (const float*)d_in[13];
  const float* beta  = (const float*)d_in[14];
  const int* last_update = (const int*)d_in[15];
  const int* ei    = (const int*)d_in[16];
  const int* tt    = (const int*)d_in[17];

  char* ws = (char*)d_ws;
  _Float16* Q16 = (_Float16*)(ws);
  _Float16* S16 = (_Float16*)(ws + 12800000);
  _Float16* K16 = (_Float16*)(ws + 25600000);
  _Float16* V16 = (_Float16*)(ws + 38400000);
  unsigned* numbuf = (unsigned*)(ws + 51200000);
  int* deg   = (int*)(ws + 76800000);
  int* cur   = (int*)(ws + 77000000);
  int* off   = (int*)(ws + 77200000);
  int* choff = (int*)(ws + 77400064);
  int* elist = (int*)(ws + 77600128);
  uint4* wef = (uint4*)(ws + 80800128);
  uint2* chunks = (uint2*)(ws + 80832896);
  float4* mdm = (float4*)(ws + 81632896);
  float4* mdd = (float4*)(ws + 83232896);
  uint4* wpf = (uint4*)(ws + 84832896);

  (void)hipMemsetAsync(deg, 0, 400000, stream);        // deg + cur
  k_frag<<<40, 256, 0, stream>>>(We, Wq, Wk, Wv, Wskip, wef, wpf);
  k_deg <<<(NE + 255) / 256, 256, 0, stream>>>(ei, deg);
  k_scan<<<1, 1024, 0, stream>>>(deg, off, choff);
  k_fillch<<<3125 + (NN + 255) / 256, 256, 0, stream>>>(ei, deg, off, choff,
                                                        cur, elist, chunks);
  dim3 pg(4, (NN + 31) / 32);
  k_proj2<<<pg, 256, 0, stream>>>(x, bq, bk, bv, bskip, wpf,
                                  Q16, K16, V16, S16);
  k_edge<<<MAXCH / 4, 256, 0, stream>>>(Q16, K16, V16, Wt, bt, wef,
                                        msg, last_update, ei, tt, elist,
                                        chunks, choff, numbuf, mdm, mdd);
  k_comb<<<NN / 4, 256, 0, stream>>>(numbuf, (const float*)mdm, (const float*)mdd,
                                     S16, gamma, beta, choff, (float*)d_out);
}

// Round 12
// 333.168 us; speedup vs baseline: 3.0391x; 1.5213x over previous
//
#include <hip/hip_runtime.h>
#include <math.h>

#define NN 50000
#define NE 800000
#define TDIM 100
#define MAXCH 100000   // sum ceil(deg/16) <= 50000 + 800000/16 = 100000
#define NBLK 196       // ceil(NN/256)

typedef _Float16 half2v __attribute__((ext_vector_type(2)));
typedef _Float16 half4v __attribute__((ext_vector_type(4)));
typedef _Float16 half8v __attribute__((ext_vector_type(8)));
typedef __fp16 fp16x2 __attribute__((ext_vector_type(2)));
typedef float f32x4 __attribute__((ext_vector_type(4)));

union U16 { uint4 u; half8v h; };
union U4h { unsigned u; half2v h; };

// cos(x) matching np.cos(float32) to ~1e-6.
__device__ __forceinline__ float ref_cosf(float x) {
  const float C1 = 0.15915494f;
  const float C2 = 6.42063831e-9f;
  float p = x * C1;
  float r = __fmaf_rn(x, C1, -p);
  r = __fmaf_rn(x, C2, r);
  float n = rintf(p);
  float f = (p - n) + r;
  return __builtin_amdgcn_cosf(f);
}

__device__ __forceinline__ unsigned pk16(float a, float b) {
  fp16x2 h = __builtin_amdgcn_cvt_pkrtz(a, b);
  unsigned u;
  __builtin_memcpy(&u, &h, 4);
  return u;
}

// attr fragments: lane slice g, j = ks*32 + g*8 + 2p (+1); j>100 -> 0
__device__ __forceinline__ void build_bfu(float rel_b, float mg_b, int g,
                                          const float2* wtbt_s, unsigned bfu[4][4]) {
#pragma unroll
  for (int ks = 0; ks < 4; ++ks) {
#pragma unroll
    for (int p = 0; p < 4; ++p) {
      int j0 = ks * 32 + g * 8 + 2 * p;
      float a0 = 0.f, a1 = 0.f;
      if (ks < 3) {
        float2 w0 = wtbt_s[j0], w1 = wtbt_s[j0 + 1];
        a0 = ref_cosf(__fmaf_rn(rel_b, w0.x, w0.y));
        a1 = ref_cosf(__fmaf_rn(rel_b, w1.x, w1.y));
      } else {
        if (j0 < 100) {
          float2 w0 = wtbt_s[j0];
          a0 = ref_cosf(__fmaf_rn(rel_b, w0.x, w0.y));
        } else if (j0 == 100) a0 = mg_b;
        if (j0 + 1 < 100) {
          float2 w1 = wtbt_s[j0 + 1];
          a1 = ref_cosf(__fmaf_rn(rel_b, w1.x, w1.y));
        } else if (j0 + 1 == 100) a1 = mg_b;
      }
      bfu[ks][p] = pk16(a0, a1);
    }
  }
}

// ---------------- k_init: W fragments + degree count (fused) ---------------
// wef: lane holds We[j = ks*32+(lane>>4)*8+jj][mt*16+(lane&15)], j>100 -> 0
// wpf: lane holds Wcy[k][nt*16+(lane&15)], cy=Q,K,V,S
__global__ void k_init(const float* __restrict__ We,
                       const float* __restrict__ Wq, const float* __restrict__ Wk,
                       const float* __restrict__ Wv, const float* __restrict__ Wskip,
                       uint4* __restrict__ wef, uint4* __restrict__ wpf,
                       const int* __restrict__ ei, int* __restrict__ deg) {
  int idx = blockIdx.x * 256 + threadIdx.x;
  if (idx < 2048) {
    int lane = idx & 63, fi = idx >> 6;
    int ks = fi >> 3, mt = fi & 7;
    int ch = mt * 16 + (lane & 15);
    int k0 = ks * 32 + ((lane >> 4) << 3);
    U16 cv;
#pragma unroll
    for (int jj = 0; jj < 8; ++jj) {
      int j = k0 + jj;
      cv.h[jj] = (j <= 100) ? (_Float16)We[j * 128 + ch] : (_Float16)0.f;
    }
    wef[idx] = cv.u;
  } else if (idx < 2048 + 8192) {
    int i2 = idx - 2048;
    int lane = i2 & 63, fi = i2 >> 6;     // fi = (cy*4+ks)*8+nt
    int nt = fi & 7, ks = (fi >> 3) & 3, cy = fi >> 5;
    const float* W = (cy == 0) ? Wq : (cy == 1) ? Wk : (cy == 2) ? Wv : Wskip;
    int n = nt * 16 + (lane & 15);
    int k0 = ks * 32 + ((lane >> 4) << 3);
    U16 cv;
#pragma unroll
    for (int jj = 0; jj < 8; ++jj)
      cv.h[jj] = (_Float16)W[(k0 + jj) * 128 + n];
    wpf[i2] = cv.u;
  }
  if (idx < NE) atomicAdd(&deg[ei[NE + idx]], 1);
}

// ---------------- MFMA projection: 32 rows x 128 cols per block -------------
// Q,K,V stored PERMUTED: channel c -> ((c>>2)&3)*32 + (c>>4)*4 + (c&3).
// S natural. cy = blockIdx.x: 0=Q 1=K 2=V 3=S.
__global__ __launch_bounds__(256) void k_proj2(
    const float* __restrict__ x,
    const float* __restrict__ bq, const float* __restrict__ bk,
    const float* __restrict__ bv, const float* __restrict__ bskip,
    const uint4* __restrict__ wpf,
    _Float16* __restrict__ Q16, _Float16* __restrict__ K16,
    _Float16* __restrict__ V16, _Float16* __restrict__ S16)
{
  __shared__ unsigned xs[32][68];     // x rows as f16 pairs (272B pitch)
  __shared__ _Float16 os[32][136];    // output bounce (272B pitch)

  const int cy = blockIdx.x;
  const int n0 = blockIdx.y * 32;
  const int tid = threadIdx.x;
  const float* bias = (cy == 0) ? bq : (cy == 1) ? bk : (cy == 2) ? bv : bskip;
  _Float16* dst     = (cy == 0) ? Q16 : (cy == 1) ? K16 : (cy == 2) ? V16 : S16;

  {
    int r = tid >> 3, c16 = (tid & 7) * 16;
    int row = n0 + r;
    float4 v0 = {0,0,0,0}, v1 = {0,0,0,0}, v2 = {0,0,0,0}, v3 = {0,0,0,0};
    if (row < NN) {
      const float4* xp = (const float4*)&x[(size_t)row * 128 + c16];
      v0 = xp[0]; v1 = xp[1]; v2 = xp[2]; v3 = xp[3];
    }
    unsigned* xr = &xs[r][c16 >> 1];
    xr[0] = pk16(v0.x, v0.y); xr[1] = pk16(v0.z, v0.w);
    xr[2] = pk16(v1.x, v1.y); xr[3] = pk16(v1.z, v1.w);
    xr[4] = pk16(v2.x, v2.y); xr[5] = pk16(v2.z, v2.w);
    xr[6] = pk16(v3.x, v3.y); xr[7] = pk16(v3.z, v3.w);
  }
  __syncthreads();

  const int w = tid >> 6, lane = tid & 63;
  const int mrow = (w & 1) << 4;        // wave's 16-row tile
  const int nh = w >> 1;                // n-tiles nh*4 .. nh*4+3

  f32x4 acc[4] = {{0,0,0,0},{0,0,0,0},{0,0,0,0},{0,0,0,0}};
#pragma unroll
  for (int ks = 0; ks < 4; ++ks) {
    U16 a_; a_.u = *(const uint4*)&xs[mrow + (lane & 15)][ks * 16 + ((lane >> 4) << 2)];
#pragma unroll
    for (int nt = 0; nt < 4; ++nt) {
      U16 b_; b_.u = wpf[((cy * 4 + ks) * 8 + nh * 4 + nt) * 64 + lane];
      acc[nt] = __builtin_amdgcn_mfma_f32_16x16x32_f16(a_.h, b_.h, acc[nt], 0, 0, 0);
    }
  }

  // bias + stash to LDS (D: col=lane&15, row=(lane>>4)*4+reg)
#pragma unroll
  for (int nt = 0; nt < 4; ++nt) {
    int col = (nh * 4 + nt) * 16 + (lane & 15);
    float bb = bias[col];
    int rbase = mrow + ((lane >> 4) << 2);
#pragma unroll
    for (int reg = 0; reg < 4; ++reg)
      os[rbase + reg][col] = (_Float16)(acc[nt][reg] + bb);
  }
  __syncthreads();

  {
    int r = tid >> 3, c16 = (tid & 7) * 16;
    int row = n0 + r;
    if (row < NN) {
      const _Float16* op = &os[r][c16];
      if (cy < 3) {
#pragma unroll
        for (int q = 0; q < 4; ++q) {
          int j4 = (c16 >> 2) + q;
          int po = ((j4 & 3) << 5) | ((j4 >> 2) << 2);
          *(half4v*)&dst[(size_t)row * 128 + po] = *(const half4v*)&op[q * 4];
        }
      } else {
        *(uint4*)&dst[(size_t)row * 128 + c16]     = ((const uint4*)op)[0];
        *(uint4*)&dst[(size_t)row * 128 + c16 + 8] = ((const uint4*)op)[1];
      }
    }
  }
}

// ---------------- parallel CSR scan (3 small kernels) ----------------------
__global__ __launch_bounds__(256) void k_scan1(const int* __restrict__ deg,
                                               int* __restrict__ off,
                                               int* __restrict__ choff,
                                               int* __restrict__ bsum,
                                               int* __restrict__ bsumc) {
  __shared__ int s[256], sc[256];
  const int b = blockIdx.x, t = threadIdx.x;
  const int n = b * 256 + t;
  int d = (n < NN) ? deg[n] : 0;
  int c = (d + 15) >> 4;
  s[t] = d; sc[t] = c;
  __syncthreads();
  for (int o = 1; o < 256; o <<= 1) {
    int v1 = 0, v2 = 0;
    if (t >= o) { v1 = s[t - o]; v2 = sc[t - o]; }
    __syncthreads();
    if (t >= o) { s[t] += v1; sc[t] += v2; }
    __syncthreads();
  }
  if (n < NN) { off[n] = s[t] - d; choff[n] = sc[t] - c; }
  if (t == 255) { bsum[b] = s[255]; bsumc[b] = sc[255]; }
}

__global__ __launch_bounds__(256) void k_scan2(int* __restrict__ bsum,
                                               int* __restrict__ bsumc,
                                               int* __restrict__ off,
                                               int* __restrict__ choff) {
  __shared__ int s[256], sc[256];
  const int t = threadIdx.x;
  int v = (t < NBLK) ? bsum[t] : 0;
  int vc = (t < NBLK) ? bsumc[t] : 0;
  s[t] = v; sc[t] = vc;
  __syncthreads();
  for (int o = 1; o < 256; o <<= 1) {
    int v1 = 0, v2 = 0;
    if (t >= o) { v1 = s[t - o]; v2 = sc[t - o]; }
    __syncthreads();
    if (t >= o) { s[t] += v1; sc[t] += v2; }
    __syncthreads();
  }
  if (t < NBLK) { bsum[t] = s[t] - v; bsumc[t] = sc[t] - vc; }  // exclusive
  if (t == 255) { off[NN] = s[255]; choff[NN] = sc[255]; }
}

__global__ void k_scan3(int* __restrict__ off, int* __restrict__ choff,
                        const int* __restrict__ bsum, const int* __restrict__ bsumc) {
  int b = blockIdx.x, n = b * 256 + threadIdx.x;
  if (n < NN) { off[n] += bsum[b]; choff[n] += bsumc[b]; }
}

// fused: blocks [0,3125) fill elist; blocks [3125,3321) build chunk table
__global__ void k_fillch(const int* __restrict__ ei, const int* __restrict__ deg,
                         const int* __restrict__ off, const int* __restrict__ choff,
                         int* __restrict__ cur, int* __restrict__ elist,
                         uint2* __restrict__ chunks) {
  int b = blockIdx.x;
  if (b < 3125) {
    int e = b * 256 + threadIdx.x;
    if (e < NE) {
      int d = ei[NE + e];
      int p = atomicAdd(&cur[d], 1);
      elist[off[d] + p] = e;
    }
  } else {
    int n = (b - 3125) * 256 + threadIdx.x;
    if (n < NN) {
      int d = deg[n], o = off[n], c = choff[n];
      int nch = (d + 15) >> 4;
      for (int j = 0; j < nch; ++j) {
        int cnt = d - 16 * j; if (cnt > 16) cnt = 16;
        chunks[c + j] = make_uint2((unsigned)(o + 16 * j),
                                   ((unsigned)n << 5) | (unsigned)cnt);
      }
    }
  }
}

// ---------------- k_edge: one straight-line wave per 16-edge chunk ----------
// 512-thread blocks: 8 waves share one 32KB wef_s copy -> LDS/block 37.7KB,
// 4 blocks/CU = 32 waves/CU (was 16 at 256-thread blocks -> occupancy 2x).
__global__ __launch_bounds__(512) void k_edge(
    const _Float16* __restrict__ Q16, const _Float16* __restrict__ K16,
    const _Float16* __restrict__ V16,
    const float* __restrict__ Wt, const float* __restrict__ bt,
    const uint4* __restrict__ wefrag,
    const float* __restrict__ msg, const int* __restrict__ last_update,
    const int* __restrict__ ei, const int* __restrict__ tt,
    const int* __restrict__ elist, const uint2* __restrict__ chunks,
    const int* __restrict__ choff,
    unsigned* __restrict__ numbuf, float4* __restrict__ mdm,
    float4* __restrict__ mdd)
{
  __shared__ uint4 wef_s[2048];
  __shared__ float2 wtbt_s[104];
  __shared__ float accs_s[8][128];

  for (int i = threadIdx.x; i < 2048; i += 512) wef_s[i] = wefrag[i];
  if (threadIdx.x < 104) {
    int j = threadIdx.x;
    wtbt_s[j] = make_float2(j < TDIM ? Wt[j] : 0.f, j < TDIM ? bt[j] : 0.f);
  }
  __syncthreads();

  const int wid = threadIdx.x >> 6, lane = threadIdx.x & 63;
  const int chunk = blockIdx.x * 8 + wid;
  if (chunk >= choff[NN]) return;

  uint2 ce = chunks[chunk];
  const int estart = (int)ce.x;
  const int node = (int)(ce.y >> 5);
  const int cnt = (int)(ce.y & 31u);
  const int g = lane >> 4, ed = lane & 15;

  float rel = 0.f, mg = 0.f; int srcl = 0;
  if (lane < cnt) {
    int eid = elist[estart + lane];
    srcl = ei[eid];
    mg = msg[eid];
    rel = (float)(last_update[srcl] - tt[eid]);
  }
  float rel_b = __shfl(rel, ed);
  float mg_b  = __shfl(mg, ed);
  int   src_b = __shfl(srcl, ed);
  const bool valid = (ed < cnt);

  unsigned bfu[4][4];
  build_bfu(rel_b, mg_b, g, wtbt_s, bfu);

  // e via MFMA: ec[mt][r] = e[ed][mt*16+g*4+r]
  f32x4 ec[8];
#pragma unroll
  for (int mt = 0; mt < 8; ++mt) {
    f32x4 c4 = {0.f, 0.f, 0.f, 0.f};
#pragma unroll
    for (int ks = 0; ks < 4; ++ks) {
      U16 av2; av2.u = wef_s[(ks * 8 + mt) * 64 + lane];
      U16 bv2; bv2.u.x = bfu[ks][0]; bv2.u.y = bfu[ks][1];
      bv2.u.z = bfu[ks][2]; bv2.u.w = bfu[ks][3];
      c4 = __builtin_amdgcn_mfma_f32_16x16x32_f16(av2.h, bv2.h, c4, 0, 0, 0);
    }
    ec[mt] = c4;
  }

  // per-head partial alpha: uint4 block i covers mt=2i,2i+1 == head i
  float pal[4];
  {
    const uint4* qp = (const uint4*)&Q16[(size_t)node * 128 + g * 32];
    const uint4* kp = (const uint4*)&K16[(size_t)src_b * 128 + g * 32];
#pragma unroll
    for (int i = 0; i < 4; ++i) {
      uint4 qa = qp[i], ka = kp[i];
      U4h q0, q1, q2, q3, k0, k1, k2, k3;
      q0.u = qa.x; q1.u = qa.y; q2.u = qa.z; q3.u = qa.w;
      k0.u = ka.x; k1.u = ka.y; k2.u = ka.z; k3.u = ka.w;
      int mA = 2 * i, mB = 2 * i + 1;
      float p = 0.f;
      p = fmaf((float)q0.h.x, (float)k0.h.x + ec[mA][0], p);
      p = fmaf((float)q0.h.y, (float)k0.h.y + ec[mA][1], p);
      p = fmaf((float)q1.h.x, (float)k1.h.x + ec[mA][2], p);
      p = fmaf((float)q1.h.y, (float)k1.h.y + ec[mA][3], p);
      p = fmaf((float)q2.h.x, (float)k2.h.x + ec[mB][0], p);
      p = fmaf((float)q2.h.y, (float)k2.h.y + ec[mB][1], p);
      p = fmaf((float)q3.h.x, (float)k3.h.x + ec[mB][2], p);
      p = fmaf((float)q3.h.y, (float)k3.h.y + ec[mB][3], p);
      pal[i] = p;
    }
  }

  // per-head: complete dot across g-lanes, chunk softmax over ed-lanes
  float m_[4], w_[4], d_[4];
#pragma unroll
  for (int h = 0; h < 4; ++h) {
    float p = pal[h];
    p += __shfl_xor(p, 16); p += __shfl_xor(p, 32);
    float al = valid ? p * 0.17677669529663689f : -INFINITY;
    float mm = al;
    mm = fmaxf(mm, __shfl_xor(mm, 1)); mm = fmaxf(mm, __shfl_xor(mm, 2));
    mm = fmaxf(mm, __shfl_xor(mm, 4)); mm = fmaxf(mm, __shfl_xor(mm, 8));
    m_[h] = mm;
    w_[h] = __expf(al - mm);       // invalid -> 0
    float s = w_[h];
    s += __shfl_xor(s, 1); s += __shfl_xor(s, 2);
    s += __shfl_xor(s, 4); s += __shfl_xor(s, 8);
    d_[h] = s;
  }

  // partial num: overwrite ec in place; weight w_[head]
  {
    const uint4* vp = (const uint4*)&V16[(size_t)src_b * 128 + g * 32];
#pragma unroll
    for (int i = 0; i < 4; ++i) {
      uint4 va = vp[i];
      U4h v0, v1, v2, v3;
      v0.u = va.x; v1.u = va.y; v2.u = va.z; v3.u = va.w;
      int mA = 2 * i, mB = 2 * i + 1;
      float wi = w_[i];
      ec[mA][0] = wi * ((float)v0.h.x + ec[mA][0]);
      ec[mA][1] = wi * ((float)v0.h.y + ec[mA][1]);
      ec[mA][2] = wi * ((float)v1.h.x + ec[mA][2]);
      ec[mA][3] = wi * ((float)v1.h.y + ec[mA][3]);
      ec[mB][0] = wi * ((float)v2.h.x + ec[mB][0]);
      ec[mB][1] = wi * ((float)v2.h.y + ec[mB][1]);
      ec[mB][2] = wi * ((float)v3.h.x + ec[mB][2]);
      ec[mB][3] = wi * ((float)v3.h.y + ec[mB][3]);
    }
  }

  // reduce over the 16 edge-lanes
#pragma unroll
  for (int mt = 0; mt < 8; ++mt)
#pragma unroll
    for (int r = 0; r < 4; ++r) {
      float v = ec[mt][r];
      v += __shfl_xor(v, 1); v += __shfl_xor(v, 2);
      v += __shfl_xor(v, 4); v += __shfl_xor(v, 8);
      ec[mt][r] = v;
    }
  if (ed == 0) {
#pragma unroll
    for (int mt = 0; mt < 8; ++mt)
#pragma unroll
      for (int r = 0; r < 4; ++r)
        accs_s[wid][mt * 16 + g * 4 + r] = ec[mt][r];
  }
  __asm__ volatile("s_waitcnt lgkmcnt(0)" ::: "memory");

  float2 nv = *(const float2*)&accs_s[wid][2 * lane];
  numbuf[(size_t)chunk * 64 + lane] = pk16(nv.x, nv.y);
  if (lane == 0) {
    mdm[chunk] = make_float4(m_[0], m_[1], m_[2], m_[3]);
    mdd[chunk] = make_float4(d_[0], d_[1], d_[2], d_[3]);
  }
}

// ---------------- k_comb: per-head flash combine + skip/relu/layernorm ------
__global__ __launch_bounds__(256) void k_comb(
    const unsigned* __restrict__ numbuf, const float* __restrict__ mdmf,
    const float* __restrict__ mddf, const _Float16* __restrict__ S16,
    const float* __restrict__ gamma, const float* __restrict__ beta,
    const int* __restrict__ choff, float* __restrict__ out)
{
  const int wid = threadIdx.x >> 6, lane = threadIdx.x & 63;
  const int node = blockIdx.x * 4 + wid;
  const int g = lane >> 4;          // head of channels 2*lane, 2*lane+1
  const int c0 = choff[node], c1 = choff[node + 1];

  float M = -INFINITY;
  for (int c = c0; c < c1; ++c) M = fmaxf(M, mdmf[c * 4 + g]);

  float den = 0.f, n0 = 0.f, n1 = 0.f;
  for (int c = c0; c < c1; ++c) {
    float sc = __expf(mdmf[c * 4 + g] - M);
    den = fmaf(mddf[c * 4 + g], sc, den);
    U4h u; u.u = numbuf[(size_t)c * 64 + lane];
    n0 = fmaf((float)u.h.x, sc, n0);
    n1 = fmaf((float)u.h.y, sc, n1);
  }

  float iv = 1.f / (den + 1e-16f);
  U4h s2; s2.u = *(const unsigned*)&S16[(size_t)node * 128 + 2 * lane];
  float r0 = fmaxf(fmaf(n0, iv, (float)s2.h.x), 0.f);
  float r1 = fmaxf(fmaf(n1, iv, (float)s2.h.y), 0.f);

  float sum = r0 + r1;
#pragma unroll
  for (int o = 1; o < 64; o <<= 1) sum += __shfl_xor(sum, o);
  float mu = sum * 0.0078125f;
  float d0 = r0 - mu, d1 = r1 - mu;
  float vs = d0 * d0 + d1 * d1;
#pragma unroll
  for (int o = 1; o < 64; o <<= 1) vs += __shfl_xor(vs, o);
  float rstd = rsqrtf(vs * 0.0078125f + 1e-5f);
  float2 gm = ((const float2*)gamma)[lane], bb = ((const float2*)beta)[lane];
  ((float2*)out)[node * 64 + lane] =
      make_float2(d0 * rstd * gm.x + bb.x, d1 * rstd * gm.y + bb.y);
}

// ---------------- launch ----------------
// ws (bytes): Q16 0 | S16 12.8M | K16 25.6M | V16 38.4M | numbuf 51.2M (25.6M)
//   deg 76.8M | cur 77.0M | off 77.2M | choff 77,400,064 | elist 77,600,128
//   wef 80,800,128 | chunks 80,832,896 | mdm 81,632,896 | mdd 83,232,896
//   wpf 84,832,896 (128KB) | bsum 84,963,968 | bsumc 84,964,968 | end 84,965,968
extern "C" void kernel_launch(void* const* d_in, const int* in_sizes, int n_in,
                              void* d_out, int out_size, void* d_ws, size_t ws_size,
                              hipStream_t stream)
{
  (void)in_sizes; (void)n_in; (void)out_size;
  if (ws_size < 84965968u) return;

  const float* x     = (const float*)d_in[0];
  const float* msg   = (const float*)d_in[1];
  const float* Wt    = (const float*)d_in[2];
  const float* bt    = (const float*)d_in[3];
  const float* Wq    = (const float*)d_in[4];
  const float* bq    = (const float*)d_in[5];
  const float* Wk    = (const float*)d_in[6];
  const float* bk    = (const float*)d_in[7];
  const float* Wv    = (const float*)d_in[8];
  const float* bv    = (const float*)d_in[9];
  const float* We    = (const float*)d_in[10];
  const float* Wskip = (const float*)d_in[11];
  const float* bskip = (const float*)d_in[12];
  const float* gamma = (const float*)d_in[13];
  const float* beta  = (const float*)d_in[14];
  const int* last_update = (const int*)d_in[15];
  const int* ei    = (const int*)d_in[16];
  const int* tt    = (const int*)d_in[17];

  char* ws = (char*)d_ws;
  _Float16* Q16 = (_Float16*)(ws);
  _Float16* S16 = (_Float16*)(ws + 12800000);
  _Float16* K16 = (_Float16*)(ws + 25600000);
  _Float16* V16 = (_Float16*)(ws + 38400000);
  unsigned* numbuf = (unsigned*)(ws + 51200000);
  int* deg   = (int*)(ws + 76800000);
  int* cur   = (int*)(ws + 77000000);
  int* off   = (int*)(ws + 77200000);
  int* choff = (int*)(ws + 77400064);
  int* elist = (int*)(ws + 77600128);
  uint4* wef = (uint4*)(ws + 80800128);
  uint2* chunks = (uint2*)(ws + 80832896);
  float4* mdm = (float4*)(ws + 81632896);
  float4* mdd = (float4*)(ws + 83232896);
  uint4* wpf = (uint4*)(ws + 84832896);
  int* bsum  = (int*)(ws + 84963968);
  int* bsumc = (int*)(ws + 84964968);

  (void)hipMemsetAsync(deg, 0, 400000, stream);        // deg + cur
  k_init<<<(NE + 255) / 256, 256, 0, stream>>>(We, Wq, Wk, Wv, Wskip, wef, wpf,
                                               ei, deg);
  k_scan1<<<NBLK, 256, 0, stream>>>(deg, off, choff, bsum, bsumc);
  k_scan2<<<1, 256, 0, stream>>>(bsum, bsumc, off, choff);
  k_scan3<<<NBLK, 256, 0, stream>>>(off, choff, bsum, bsumc);
  k_fillch<<<3125 + (NN + 255) / 256, 256, 0, stream>>>(ei, deg, off, choff,
                                                        cur, elist, chunks);
  dim3 pg(4, (NN + 31) / 32);
  k_proj2<<<pg, 256, 0, stream>>>(x, bq, bk, bv, bskip, wpf,
                                  Q16, K16, V16, S16);
  k_edge<<<MAXCH / 8, 512, 0, stream>>>(Q16, K16, V16, Wt, bt, wef,
                                        msg, last_update, ei, tt, elist,
                                        chunks, choff, numbuf, mdm, mdd);
  k_comb<<<NN / 4, 256, 0, stream>>>(numbuf, (const float*)mdm, (const float*)mdd,
                                     S16, gamma, beta, choff, (float*)d_out);
}

// Round 13
// 290.250 us; speedup vs baseline: 3.4885x; 1.1479x over previous
//
#include <hip/hip_runtime.h>
#include <math.h>

#define NN 50000
#define NE 800000
#define TDIM 100
#define MAXCH 100000   // sum ceil(deg/16) <= 50000 + 800000/16 = 100000
#define NBLK 196       // ceil(NN/256)

typedef _Float16 half2v __attribute__((ext_vector_type(2)));
typedef _Float16 half4v __attribute__((ext_vector_type(4)));
typedef _Float16 half8v __attribute__((ext_vector_type(8)));
typedef __fp16 fp16x2 __attribute__((ext_vector_type(2)));
typedef float f32x4 __attribute__((ext_vector_type(4)));

union U16 { uint4 u; half8v h; };
union U4h { unsigned u; half2v h; };

// cos(x) matching np.cos(float32) to ~1e-6.
__device__ __forceinline__ float ref_cosf(float x) {
  const float C1 = 0.15915494f;
  const float C2 = 6.42063831e-9f;
  float p = x * C1;
  float r = __fmaf_rn(x, C1, -p);
  r = __fmaf_rn(x, C2, r);
  float n = rintf(p);
  float f = (p - n) + r;
  return __builtin_amdgcn_cosf(f);
}

__device__ __forceinline__ unsigned pk16(float a, float b) {
  fp16x2 h = __builtin_amdgcn_cvt_pkrtz(a, b);
  unsigned u;
  __builtin_memcpy(&u, &h, 4);
  return u;
}

// ---- DPP 16-lane butterfly (VALU, not LDS pipe): masks {1,2,7,15} ----------
// quad_perm[1,0,3,2]=0xB1 (xor1), quad_perm[2,3,0,1]=0x4E (xor2),
// row_half_mirror=0x141 (xor7), row_mirror=0x140 (xor15). Generates the full
// 16-lane group; every lane ends with the total.
template<int CTRL>
__device__ __forceinline__ float dpp_addf(float x) {
  int y = __builtin_amdgcn_update_dpp(0, __float_as_int(x), CTRL, 0xf, 0xf, true);
  return x + __int_as_float(y);
}
template<int CTRL>
__device__ __forceinline__ float dpp_maxf(float x) {
  int y = __builtin_amdgcn_update_dpp(0, __float_as_int(x), CTRL, 0xf, 0xf, true);
  return fmaxf(x, __int_as_float(y));
}
__device__ __forceinline__ float red16_add(float x) {
  x = dpp_addf<0xB1>(x); x = dpp_addf<0x4E>(x);
  x = dpp_addf<0x141>(x); x = dpp_addf<0x140>(x);
  return x;
}
__device__ __forceinline__ float red16_max(float x) {
  x = dpp_maxf<0xB1>(x); x = dpp_maxf<0x4E>(x);
  x = dpp_maxf<0x141>(x); x = dpp_maxf<0x140>(x);
  return x;
}

// attr fragments: lane slice g, j = ks*32 + g*8 + 2p (+1); j>100 -> 0
__device__ __forceinline__ void build_bfu(float rel_b, float mg_b, int g,
                                          const float2* wtbt_s, unsigned bfu[4][4]) {
#pragma unroll
  for (int ks = 0; ks < 4; ++ks) {
#pragma unroll
    for (int p = 0; p < 4; ++p) {
      int j0 = ks * 32 + g * 8 + 2 * p;
      float a0 = 0.f, a1 = 0.f;
      if (ks < 3) {
        float2 w0 = wtbt_s[j0], w1 = wtbt_s[j0 + 1];
        a0 = ref_cosf(__fmaf_rn(rel_b, w0.x, w0.y));
        a1 = ref_cosf(__fmaf_rn(rel_b, w1.x, w1.y));
      } else {
        if (j0 < 100) {
          float2 w0 = wtbt_s[j0];
          a0 = ref_cosf(__fmaf_rn(rel_b, w0.x, w0.y));
        } else if (j0 == 100) a0 = mg_b;
        if (j0 + 1 < 100) {
          float2 w1 = wtbt_s[j0 + 1];
          a1 = ref_cosf(__fmaf_rn(rel_b, w1.x, w1.y));
        } else if (j0 + 1 == 100) a1 = mg_b;
      }
      bfu[ks][p] = pk16(a0, a1);
    }
  }
}

// ---------------- k_init: W fragments + degree count (fused) ---------------
__global__ void k_init(const float* __restrict__ We,
                       const float* __restrict__ Wq, const float* __restrict__ Wk,
                       const float* __restrict__ Wv, const float* __restrict__ Wskip,
                       uint4* __restrict__ wef, uint4* __restrict__ wpf,
                       const int* __restrict__ ei, int* __restrict__ deg) {
  int idx = blockIdx.x * 256 + threadIdx.x;
  if (idx < 2048) {
    int lane = idx & 63, fi = idx >> 6;
    int ks = fi >> 3, mt = fi & 7;
    int ch = mt * 16 + (lane & 15);
    int k0 = ks * 32 + ((lane >> 4) << 3);
    U16 cv;
#pragma unroll
    for (int jj = 0; jj < 8; ++jj) {
      int j = k0 + jj;
      cv.h[jj] = (j <= 100) ? (_Float16)We[j * 128 + ch] : (_Float16)0.f;
    }
    wef[idx] = cv.u;
  } else if (idx < 2048 + 8192) {
    int i2 = idx - 2048;
    int lane = i2 & 63, fi = i2 >> 6;     // fi = (cy*4+ks)*8+nt
    int nt = fi & 7, ks = (fi >> 3) & 3, cy = fi >> 5;
    const float* W = (cy == 0) ? Wq : (cy == 1) ? Wk : (cy == 2) ? Wv : Wskip;
    int n = nt * 16 + (lane & 15);
    int k0 = ks * 32 + ((lane >> 4) << 3);
    U16 cv;
#pragma unroll
    for (int jj = 0; jj < 8; ++jj)
      cv.h[jj] = (_Float16)W[(k0 + jj) * 128 + n];
    wpf[i2] = cv.u;
  }
  if (idx < NE) atomicAdd(&deg[ei[NE + idx]], 1);
}

// ---------------- MFMA projection: 32 rows x 128 cols per block -------------
// Q,K,V stored PERMUTED: channel c -> ((c>>2)&3)*32 + (c>>4)*4 + (c&3).
// S natural. cy = blockIdx.x: 0=Q 1=K 2=V 3=S.
__global__ __launch_bounds__(256) void k_proj2(
    const float* __restrict__ x,
    const float* __restrict__ bq, const float* __restrict__ bk,
    const float* __restrict__ bv, const float* __restrict__ bskip,
    const uint4* __restrict__ wpf,
    _Float16* __restrict__ Q16, _Float16* __restrict__ K16,
    _Float16* __restrict__ V16, _Float16* __restrict__ S16)
{
  __shared__ unsigned xs[32][68];     // x rows as f16 pairs (272B pitch)
  __shared__ _Float16 os[32][136];    // output bounce (272B pitch)

  const int cy = blockIdx.x;
  const int n0 = blockIdx.y * 32;
  const int tid = threadIdx.x;
  const float* bias = (cy == 0) ? bq : (cy == 1) ? bk : (cy == 2) ? bv : bskip;
  _Float16* dst     = (cy == 0) ? Q16 : (cy == 1) ? K16 : (cy == 2) ? V16 : S16;

  {
    int r = tid >> 3, c16 = (tid & 7) * 16;
    int row = n0 + r;
    float4 v0 = {0,0,0,0}, v1 = {0,0,0,0}, v2 = {0,0,0,0}, v3 = {0,0,0,0};
    if (row < NN) {
      const float4* xp = (const float4*)&x[(size_t)row * 128 + c16];
      v0 = xp[0]; v1 = xp[1]; v2 = xp[2]; v3 = xp[3];
    }
    unsigned* xr = &xs[r][c16 >> 1];
    xr[0] = pk16(v0.x, v0.y); xr[1] = pk16(v0.z, v0.w);
    xr[2] = pk16(v1.x, v1.y); xr[3] = pk16(v1.z, v1.w);
    xr[4] = pk16(v2.x, v2.y); xr[5] = pk16(v2.z, v2.w);
    xr[6] = pk16(v3.x, v3.y); xr[7] = pk16(v3.z, v3.w);
  }
  __syncthreads();

  const int w = tid >> 6, lane = tid & 63;
  const int mrow = (w & 1) << 4;        // wave's 16-row tile
  const int nh = w >> 1;                // n-tiles nh*4 .. nh*4+3

  f32x4 acc[4] = {{0,0,0,0},{0,0,0,0},{0,0,0,0},{0,0,0,0}};
#pragma unroll
  for (int ks = 0; ks < 4; ++ks) {
    U16 a_; a_.u = *(const uint4*)&xs[mrow + (lane & 15)][ks * 16 + ((lane >> 4) << 2)];
#pragma unroll
    for (int nt = 0; nt < 4; ++nt) {
      U16 b_; b_.u = wpf[((cy * 4 + ks) * 8 + nh * 4 + nt) * 64 + lane];
      acc[nt] = __builtin_amdgcn_mfma_f32_16x16x32_f16(a_.h, b_.h, acc[nt], 0, 0, 0);
    }
  }

  // bias + stash to LDS (D: col=lane&15, row=(lane>>4)*4+reg)
#pragma unroll
  for (int nt = 0; nt < 4; ++nt) {
    int col = (nh * 4 + nt) * 16 + (lane & 15);
    float bb = bias[col];
    int rbase = mrow + ((lane >> 4) << 2);
#pragma unroll
    for (int reg = 0; reg < 4; ++reg)
      os[rbase + reg][col] = (_Float16)(acc[nt][reg] + bb);
  }
  __syncthreads();

  {
    int r = tid >> 3, c16 = (tid & 7) * 16;
    int row = n0 + r;
    if (row < NN) {
      const _Float16* op = &os[r][c16];
      if (cy < 3) {
#pragma unroll
        for (int q = 0; q < 4; ++q) {
          int j4 = (c16 >> 2) + q;
          int po = ((j4 & 3) << 5) | ((j4 >> 2) << 2);
          *(half4v*)&dst[(size_t)row * 128 + po] = *(const half4v*)&op[q * 4];
        }
      } else {
        *(uint4*)&dst[(size_t)row * 128 + c16]     = ((const uint4*)op)[0];
        *(uint4*)&dst[(size_t)row * 128 + c16 + 8] = ((const uint4*)op)[1];
      }
    }
  }
}

// ---------------- parallel CSR scan (3 small kernels) ----------------------
__global__ __launch_bounds__(256) void k_scan1(const int* __restrict__ deg,
                                               int* __restrict__ off,
                                               int* __restrict__ choff,
                                               int* __restrict__ bsum,
                                               int* __restrict__ bsumc) {
  __shared__ int s[256], sc[256];
  const int b = blockIdx.x, t = threadIdx.x;
  const int n = b * 256 + t;
  int d = (n < NN) ? deg[n] : 0;
  int c = (d + 15) >> 4;
  s[t] = d; sc[t] = c;
  __syncthreads();
  for (int o = 1; o < 256; o <<= 1) {
    int v1 = 0, v2 = 0;
    if (t >= o) { v1 = s[t - o]; v2 = sc[t - o]; }
    __syncthreads();
    if (t >= o) { s[t] += v1; sc[t] += v2; }
    __syncthreads();
  }
  if (n < NN) { off[n] = s[t] - d; choff[n] = sc[t] - c; }
  if (t == 255) { bsum[b] = s[255]; bsumc[b] = sc[255]; }
}

__global__ __launch_bounds__(256) void k_scan2(int* __restrict__ bsum,
                                               int* __restrict__ bsumc,
                                               int* __restrict__ off,
                                               int* __restrict__ choff) {
  __shared__ int s[256], sc[256];
  const int t = threadIdx.x;
  int v = (t < NBLK) ? bsum[t] : 0;
  int vc = (t < NBLK) ? bsumc[t] : 0;
  s[t] = v; sc[t] = vc;
  __syncthreads();
  for (int o = 1; o < 256; o <<= 1) {
    int v1 = 0, v2 = 0;
    if (t >= o) { v1 = s[t - o]; v2 = sc[t - o]; }
    __syncthreads();
    if (t >= o) { s[t] += v1; sc[t] += v2; }
    __syncthreads();
  }
  if (t < NBLK) { bsum[t] = s[t] - v; bsumc[t] = sc[t] - vc; }  // exclusive
  if (t == 255) { off[NN] = s[255]; choff[NN] = sc[255]; }
}

__global__ void k_scan3(int* __restrict__ off, int* __restrict__ choff,
                        const int* __restrict__ bsum, const int* __restrict__ bsumc) {
  int b = blockIdx.x, n = b * 256 + threadIdx.x;
  if (n < NN) { off[n] += bsum[b]; choff[n] += bsumc[b]; }
}

// fused: blocks [0,3125) fill elist; blocks [3125,3321) build chunk table
__global__ void k_fillch(const int* __restrict__ ei, const int* __restrict__ deg,
                         const int* __restrict__ off, const int* __restrict__ choff,
                         int* __restrict__ cur, int* __restrict__ elist,
                         uint2* __restrict__ chunks) {
  int b = blockIdx.x;
  if (b < 3125) {
    int e = b * 256 + threadIdx.x;
    if (e < NE) {
      int d = ei[NE + e];
      int p = atomicAdd(&cur[d], 1);
      elist[off[d] + p] = e;
    }
  } else {
    int n = (b - 3125) * 256 + threadIdx.x;
    if (n < NN) {
      int d = deg[n], o = off[n], c = choff[n];
      int nch = (d + 15) >> 4;
      for (int j = 0; j < nch; ++j) {
        int cnt = d - 16 * j; if (cnt > 16) cnt = 16;
        chunks[c + j] = make_uint2((unsigned)(o + 16 * j),
                                   ((unsigned)n << 5) | (unsigned)cnt);
      }
    }
  }
}

// ---------------- k_edge: one straight-line wave per 16-edge chunk ----------
// DPP-based reductions (VALU) replace ds_bpermute shuffles: the per-CU LDS
// unit was the saturated pipe (R12: 2x wave capacity -> zero speedup).
__global__ __launch_bounds__(512) void k_edge(
    const _Float16* __restrict__ Q16, const _Float16* __restrict__ K16,
    const _Float16* __restrict__ V16,
    const float* __restrict__ Wt, const float* __restrict__ bt,
    const uint4* __restrict__ wefrag,
    const float* __restrict__ msg, const int* __restrict__ last_update,
    const int* __restrict__ ei, const int* __restrict__ tt,
    const int* __restrict__ elist, const uint2* __restrict__ chunks,
    const int* __restrict__ choff,
    unsigned* __restrict__ numbuf, float4* __restrict__ mdm,
    float4* __restrict__ mdd)
{
  __shared__ uint4 wef_s[2048];
  __shared__ float2 wtbt_s[104];
  __shared__ float accs_s[8][128];

  for (int i = threadIdx.x; i < 2048; i += 512) wef_s[i] = wefrag[i];
  if (threadIdx.x < 104) {
    int j = threadIdx.x;
    wtbt_s[j] = make_float2(j < TDIM ? Wt[j] : 0.f, j < TDIM ? bt[j] : 0.f);
  }
  __syncthreads();

  const int wid = threadIdx.x >> 6, lane = threadIdx.x & 63;
  const int chunk = blockIdx.x * 8 + wid;
  if (chunk >= choff[NN]) return;

  uint2 ce = chunks[chunk];
  const int estart = (int)ce.x;
  const int node = (int)(ce.y >> 5);
  const int cnt = (int)(ce.y & 31u);
  const int g = lane >> 4, ed = lane & 15;

  // per-lane direct gathers (16 distinct addrs, cache-deduped); clamp keeps
  // invalid lanes in-bounds, their w becomes 0 below.
  const int edc = (ed < cnt) ? ed : (cnt - 1);
  const int eid = elist[estart + edc];
  const int src_b = ei[eid];
  const float mg_b = msg[eid];
  const float rel_b = (float)(last_update[src_b] - tt[eid]);
  const bool valid = (ed < cnt);

  unsigned bfu[4][4];
  build_bfu(rel_b, mg_b, g, wtbt_s, bfu);

  // e via MFMA: ec[mt][r] = e[ed][mt*16+g*4+r]
  f32x4 ec[8];
#pragma unroll
  for (int mt = 0; mt < 8; ++mt) {
    f32x4 c4 = {0.f, 0.f, 0.f, 0.f};
#pragma unroll
    for (int ks = 0; ks < 4; ++ks) {
      U16 av2; av2.u = wef_s[(ks * 8 + mt) * 64 + lane];
      U16 bv2; bv2.u.x = bfu[ks][0]; bv2.u.y = bfu[ks][1];
      bv2.u.z = bfu[ks][2]; bv2.u.w = bfu[ks][3];
      c4 = __builtin_amdgcn_mfma_f32_16x16x32_f16(av2.h, bv2.h, c4, 0, 0, 0);
    }
    ec[mt] = c4;
  }

  // per-head partial alpha: uint4 block i covers mt=2i,2i+1 == head i
  float pal[4];
  {
    const uint4* qp = (const uint4*)&Q16[(size_t)node * 128 + g * 32];
    const uint4* kp = (const uint4*)&K16[(size_t)src_b * 128 + g * 32];
#pragma unroll
    for (int i = 0; i < 4; ++i) {
      uint4 qa = qp[i], ka = kp[i];
      U4h q0, q1, q2, q3, k0, k1, k2, k3;
      q0.u = qa.x; q1.u = qa.y; q2.u = qa.z; q3.u = qa.w;
      k0.u = ka.x; k1.u = ka.y; k2.u = ka.z; k3.u = ka.w;
      int mA = 2 * i, mB = 2 * i + 1;
      float p = 0.f;
      p = fmaf((float)q0.h.x, (float)k0.h.x + ec[mA][0], p);
      p = fmaf((float)q0.h.y, (float)k0.h.y + ec[mA][1], p);
      p = fmaf((float)q1.h.x, (float)k1.h.x + ec[mA][2], p);
      p = fmaf((float)q1.h.y, (float)k1.h.y + ec[mA][3], p);
      p = fmaf((float)q2.h.x, (float)k2.h.x + ec[mB][0], p);
      p = fmaf((float)q2.h.y, (float)k2.h.y + ec[mB][1], p);
      p = fmaf((float)q3.h.x, (float)k3.h.x + ec[mB][2], p);
      p = fmaf((float)q3.h.y, (float)k3.h.y + ec[mB][3], p);
      pal[i] = p;
    }
  }

  // per-head: complete dot across g-lanes (cross-row: shfl), then chunk
  // softmax over ed-lanes via DPP butterflies (VALU).
  float m_[4], w_[4], d_[4];
#pragma unroll
  for (int h = 0; h < 4; ++h) {
    float p = pal[h];
    p += __shfl_xor(p, 16); p += __shfl_xor(p, 32);
    float al = valid ? p * 0.17677669529663689f : -INFINITY;
    float mm = red16_max(al);
    m_[h] = mm;
    w_[h] = __expf(al - mm);       // invalid -> 0
    d_[h] = red16_add(w_[h]);
  }

  // partial num: overwrite ec in place; weight w_[head]
  {
    const uint4* vp = (const uint4*)&V16[(size_t)src_b * 128 + g * 32];
#pragma unroll
    for (int i = 0; i < 4; ++i) {
      uint4 va = vp[i];
      U4h v0, v1, v2, v3;
      v0.u = va.x; v1.u = va.y; v2.u = va.z; v3.u = va.w;
      int mA = 2 * i, mB = 2 * i + 1;
      float wi = w_[i];
      ec[mA][0] = wi * ((float)v0.h.x + ec[mA][0]);
      ec[mA][1] = wi * ((float)v0.h.y + ec[mA][1]);
      ec[mA][2] = wi * ((float)v1.h.x + ec[mA][2]);
      ec[mA][3] = wi * ((float)v1.h.y + ec[mA][3]);
      ec[mB][0] = wi * ((float)v2.h.x + ec[mB][0]);
      ec[mB][1] = wi * ((float)v2.h.y + ec[mB][1]);
      ec[mB][2] = wi * ((float)v3.h.x + ec[mB][2]);
      ec[mB][3] = wi * ((float)v3.h.y + ec[mB][3]);
    }
  }

  // reduce over the 16 edge-lanes (DPP butterflies, VALU pipe)
#pragma unroll
  for (int mt = 0; mt < 8; ++mt)
#pragma unroll
    for (int r = 0; r < 4; ++r)
      ec[mt][r] = red16_add(ec[mt][r]);

  if (ed == 0) {
#pragma unroll
    for (int mt = 0; mt < 8; ++mt)
#pragma unroll
      for (int r = 0; r < 4; ++r)
        accs_s[wid][mt * 16 + g * 4 + r] = ec[mt][r];
  }
  __asm__ volatile("s_waitcnt lgkmcnt(0)" ::: "memory");

  float2 nv = *(const float2*)&accs_s[wid][2 * lane];
  numbuf[(size_t)chunk * 64 + lane] = pk16(nv.x, nv.y);
  if (lane == 0) {
    mdm[chunk] = make_float4(m_[0], m_[1], m_[2], m_[3]);
    mdd[chunk] = make_float4(d_[0], d_[1], d_[2], d_[3]);
  }
}

// ---------------- k_comb: per-head flash combine + skip/relu/layernorm ------
__global__ __launch_bounds__(256) void k_comb(
    const unsigned* __restrict__ numbuf, const float* __restrict__ mdmf,
    const float* __restrict__ mddf, const _Float16* __restrict__ S16,
    const float* __restrict__ gamma, const float* __restrict__ beta,
    const int* __restrict__ choff, float* __restrict__ out)
{
  const int wid = threadIdx.x >> 6, lane = threadIdx.x & 63;
  const int node = blockIdx.x * 4 + wid;
  const int g = lane >> 4;          // head of channels 2*lane, 2*lane+1
  const int c0 = choff[node], c1 = choff[node + 1];

  float M = -INFINITY;
  for (int c = c0; c < c1; ++c) M = fmaxf(M, mdmf[c * 4 + g]);

  float den = 0.f, n0 = 0.f, n1 = 0.f;
  for (int c = c0; c < c1; ++c) {
    float sc = __expf(mdmf[c * 4 + g] - M);
    den = fmaf(mddf[c * 4 + g], sc, den);
    U4h u; u.u = numbuf[(size_t)c * 64 + lane];
    n0 = fmaf((float)u.h.x, sc, n0);
    n1 = fmaf((float)u.h.y, sc, n1);
  }

  float iv = 1.f / (den + 1e-16f);
  U4h s2; s2.u = *(const unsigned*)&S16[(size_t)node * 128 + 2 * lane];
  float r0 = fmaxf(fmaf(n0, iv, (float)s2.h.x), 0.f);
  float r1 = fmaxf(fmaf(n1, iv, (float)s2.h.y), 0.f);

  float sum = r0 + r1;
#pragma unroll
  for (int o = 1; o < 64; o <<= 1) sum += __shfl_xor(sum, o);
  float mu = sum * 0.0078125f;
  float d0 = r0 - mu, d1 = r1 - mu;
  float vs = d0 * d0 + d1 * d1;
#pragma unroll
  for (int o = 1; o < 64; o <<= 1) vs += __shfl_xor(vs, o);
  float rstd = rsqrtf(vs * 0.0078125f + 1e-5f);
  float2 gm = ((const float2*)gamma)[lane], bb = ((const float2*)beta)[lane];
  ((float2*)out)[node * 64 + lane] =
      make_float2(d0 * rstd * gm.x + bb.x, d1 * rstd * gm.y + bb.y);
}

// ---------------- launch ----------------
// ws (bytes): Q16 0 | S16 12.8M | K16 25.6M | V16 38.4M | numbuf 51.2M (25.6M)
//   deg 76.8M | cur 77.0M | off 77.2M | choff 77,400,064 | elist 77,600,128
//   wef 80,800,128 | chunks 80,832,896 | mdm 81,632,896 | mdd 83,232,896
//   wpf 84,832,896 (128KB) | bsum 84,963,968 | bsumc 84,964,968 | end 84,965,968
extern "C" void kernel_launch(void* const* d_in, const int* in_sizes, int n_in,
                              void* d_out, int out_size, void* d_ws, size_t ws_size,
                              hipStream_t stream)
{
  (void)in_sizes; (void)n_in; (void)out_size;
  if (ws_size < 84965968u) return;

  const float* x     = (const float*)d_in[0];
  const float* msg   = (const float*)d_in[1];
  const float* Wt    = (const float*)d_in[2];
  const float* bt    = (const float*)d_in[3];
  const float* Wq    = (const float*)d_in[4];
  const float* bq    = (const float*)d_in[5];
  const float* Wk    = (const float*)d_in[6];
  const float* bk    = (const float*)d_in[7];
  const float* Wv    = (const float*)d_in[8];
  const float* bv    = (const float*)d_in[9];
  const float* We    = (const float*)d_in[10];
  const float* Wskip = (const float*)d_in[11];
  const float* bskip = (const float*)d_in[12];
  const float* gamma = (const float*)d_in[13];
  const float* beta  = (const float*)d_in[14];
  const int* last_update = (const int*)d_in[15];
  const int* ei    = (const int*)d_in[16];
  const int* tt    = (const int*)d_in[17];

  char* ws = (char*)d_ws;
  _Float16* Q16 = (_Float16*)(ws);
  _Float16* S16 = (_Float16*)(ws + 12800000);
  _Float16* K16 = (_Float16*)(ws + 25600000);
  _Float16* V16 = (_Float16*)(ws + 38400000);
  unsigned* numbuf = (unsigned*)(ws + 51200000);
  int* deg   = (int*)(ws + 76800000);
  int* cur   = (int*)(ws + 77000000);
  int* off   = (int*)(ws + 77200000);
  int* choff = (int*)(ws + 77400064);
  int* elist = (int*)(ws + 77600128);
  uint4* wef = (uint4*)(ws + 80800128);
  uint2* chunks = (uint2*)(ws + 80832896);
  float4* mdm = (float4*)(ws + 81632896);
  float4* mdd = (float4*)(ws + 83232896);
  uint4* wpf = (uint4*)(ws + 84832896);
  int* bsum  = (int*)(ws + 84963968);
  int* bsumc = (int*)(ws + 84964968);

  (void)hipMemsetAsync(deg, 0, 400000, stream);        // deg + cur
  k_init<<<(NE + 255) / 256, 256, 0, stream>>>(We, Wq, Wk, Wv, Wskip, wef, wpf,
                                               ei, deg);
  k_scan1<<<NBLK, 256, 0, stream>>>(deg, off, choff, bsum, bsumc);
  k_scan2<<<1, 256, 0, stream>>>(bsum, bsumc, off, choff);
  k_scan3<<<NBLK, 256, 0, stream>>>(off, choff, bsum, bsumc);
  k_fillch<<<3125 + (NN + 255) / 256, 256, 0, stream>>>(ei, deg, off, choff,
                                                        cur, elist, chunks);
  dim3 pg(4, (NN + 31) / 32);
  k_proj2<<<pg, 256, 0, stream>>>(x, bq, bk, bv, bskip, wpf,
                                  Q16, K16, V16, S16);
  k_edge<<<MAXCH / 8, 512, 0, stream>>>(Q16, K16, V16, Wt, bt, wef,
                                        msg, last_update, ei, tt, elist,
                                        chunks, choff, numbuf, mdm, mdd);
  k_comb<<<NN / 4, 256, 0, stream>>>(numbuf, (const float*)mdm, (const float*)mdd,
                                     S16, gamma, beta, choff, (float*)d_out);
}

// Round 14
// 276.436 us; speedup vs baseline: 3.6628x; 1.0500x over previous
//
#include <hip/hip_runtime.h>
#include <math.h>

#define NN 50000
#define NE 800000
#define TDIM 100
#define MAXCH 100000   // sum ceil(deg/16) <= 50000 + 800000/16 = 100000
#define NBLK 196       // ceil(NN/256)

typedef _Float16 half2v __attribute__((ext_vector_type(2)));
typedef _Float16 half4v __attribute__((ext_vector_type(4)));
typedef _Float16 half8v __attribute__((ext_vector_type(8)));
typedef __fp16 fp16x2 __attribute__((ext_vector_type(2)));
typedef float f32x4 __attribute__((ext_vector_type(4)));

union U16 { uint4 u; half8v h; };
union U4h { unsigned u; half2v h; };

// cos(x) matching np.cos(float32) to ~1e-6.
__device__ __forceinline__ float ref_cosf(float x) {
  const float C1 = 0.15915494f;
  const float C2 = 6.42063831e-9f;
  float p = x * C1;
  float r = __fmaf_rn(x, C1, -p);
  r = __fmaf_rn(x, C2, r);
  float n = rintf(p);
  float f = (p - n) + r;
  return __builtin_amdgcn_cosf(f);
}

__device__ __forceinline__ unsigned pk16(float a, float b) {
  fp16x2 h = __builtin_amdgcn_cvt_pkrtz(a, b);
  unsigned u;
  __builtin_memcpy(&u, &h, 4);
  return u;
}

__device__ __forceinline__ float fdot2f(unsigned a, unsigned b, float c) {
  U4h ua, ub; ua.u = a; ub.u = b;
#if __has_builtin(__builtin_amdgcn_fdot2)
  return __builtin_amdgcn_fdot2(ua.h, ub.h, c, false);
#else
  return c + (float)ua.h.x * (float)ub.h.x + (float)ua.h.y * (float)ub.h.y;
#endif
}

// packed f16 helpers (v_pk_add_f16 / v_pk_mul_f16)
__device__ __forceinline__ unsigned pkadd(unsigned a, unsigned b) {
  half2v x, y; __builtin_memcpy(&x, &a, 4); __builtin_memcpy(&y, &b, 4);
  half2v z = x + y; unsigned r; __builtin_memcpy(&r, &z, 4); return r;
}
__device__ __forceinline__ unsigned pkmul(unsigned a, unsigned b) {
  half2v x, y; __builtin_memcpy(&x, &a, 4); __builtin_memcpy(&y, &b, 4);
  half2v z = x * y; unsigned r; __builtin_memcpy(&r, &z, 4); return r;
}

// ---- DPP 16-lane butterfly (VALU pipe): masks {1,2,7,15} -------------------
template<int CTRL>
__device__ __forceinline__ int dpp_i(int x) {
  return __builtin_amdgcn_update_dpp(0, x, CTRL, 0xf, 0xf, true);
}
template<int CTRL>
__device__ __forceinline__ float dpp_addf(float x) {
  return x + __int_as_float(dpp_i<CTRL>(__float_as_int(x)));
}
template<int CTRL>
__device__ __forceinline__ float dpp_maxf(float x) {
  return fmaxf(x, __int_as_float(dpp_i<CTRL>(__float_as_int(x))));
}
__device__ __forceinline__ float red16_add(float x) {
  x = dpp_addf<0xB1>(x); x = dpp_addf<0x4E>(x);
  x = dpp_addf<0x141>(x); x = dpp_addf<0x140>(x);
  return x;
}
__device__ __forceinline__ float red16_max(float x) {
  x = dpp_maxf<0xB1>(x); x = dpp_maxf<0x4E>(x);
  x = dpp_maxf<0x141>(x); x = dpp_maxf<0x140>(x);
  return x;
}
__device__ __forceinline__ unsigned red16_pkadd(unsigned x) {
  x = pkadd(x, (unsigned)dpp_i<0xB1>((int)x));
  x = pkadd(x, (unsigned)dpp_i<0x4E>((int)x));
  x = pkadd(x, (unsigned)dpp_i<0x141>((int)x));
  x = pkadd(x, (unsigned)dpp_i<0x140>((int)x));
  return x;
}

// attr fragments: lane slice g, j = ks*32 + g*8 + 2p (+1); j>100 -> 0
__device__ __forceinline__ void build_bfu(float rel_b, float mg_b, int g,
                                          const float2* wtbt_s, unsigned bfu[4][4]) {
#pragma unroll
  for (int ks = 0; ks < 4; ++ks) {
#pragma unroll
    for (int p = 0; p < 4; ++p) {
      int j0 = ks * 32 + g * 8 + 2 * p;
      float a0 = 0.f, a1 = 0.f;
      if (ks < 3) {
        float2 w0 = wtbt_s[j0], w1 = wtbt_s[j0 + 1];
        a0 = ref_cosf(__fmaf_rn(rel_b, w0.x, w0.y));
        a1 = ref_cosf(__fmaf_rn(rel_b, w1.x, w1.y));
      } else {
        if (j0 < 100) {
          float2 w0 = wtbt_s[j0];
          a0 = ref_cosf(__fmaf_rn(rel_b, w0.x, w0.y));
        } else if (j0 == 100) a0 = mg_b;
        if (j0 + 1 < 100) {
          float2 w1 = wtbt_s[j0 + 1];
          a1 = ref_cosf(__fmaf_rn(rel_b, w1.x, w1.y));
        } else if (j0 + 1 == 100) a1 = mg_b;
      }
      bfu[ks][p] = pk16(a0, a1);
    }
  }
}

// ---------------- k_init: W fragments + degree count (fused) ---------------
__global__ void k_init(const float* __restrict__ We,
                       const float* __restrict__ Wq, const float* __restrict__ Wk,
                       const float* __restrict__ Wv, const float* __restrict__ Wskip,
                       uint4* __restrict__ wef, uint4* __restrict__ wpf,
                       const int* __restrict__ ei, int* __restrict__ deg) {
  int idx = blockIdx.x * 256 + threadIdx.x;
  if (idx < 2048) {
    int lane = idx & 63, fi = idx >> 6;
    int ks = fi >> 3, mt = fi & 7;
    int ch = mt * 16 + (lane & 15);
    int k0 = ks * 32 + ((lane >> 4) << 3);
    U16 cv;
#pragma unroll
    for (int jj = 0; jj < 8; ++jj) {
      int j = k0 + jj;
      cv.h[jj] = (j <= 100) ? (_Float16)We[j * 128 + ch] : (_Float16)0.f;
    }
    wef[idx] = cv.u;
  } else if (idx < 2048 + 8192) {
    int i2 = idx - 2048;
    int lane = i2 & 63, fi = i2 >> 6;     // fi = (cy*4+ks)*8+nt
    int nt = fi & 7, ks = (fi >> 3) & 3, cy = fi >> 5;
    const float* W = (cy == 0) ? Wq : (cy == 1) ? Wk : (cy == 2) ? Wv : Wskip;
    int n = nt * 16 + (lane & 15);
    int k0 = ks * 32 + ((lane >> 4) << 3);
    U16 cv;
#pragma unroll
    for (int jj = 0; jj < 8; ++jj)
      cv.h[jj] = (_Float16)W[(k0 + jj) * 128 + n];
    wpf[i2] = cv.u;
  }
  if (idx < NE) atomicAdd(&deg[ei[NE + idx]], 1);
}

// ---------------- MFMA projection: 32 rows x 128 cols per block -------------
// Q,K,V stored PERMUTED: channel c -> ((c>>2)&3)*32 + (c>>4)*4 + (c&3).
// S natural. cy = blockIdx.x: 0=Q 1=K 2=V 3=S.
__global__ __launch_bounds__(256) void k_proj2(
    const float* __restrict__ x,
    const float* __restrict__ bq, const float* __restrict__ bk,
    const float* __restrict__ bv, const float* __restrict__ bskip,
    const uint4* __restrict__ wpf,
    _Float16* __restrict__ Q16, _Float16* __restrict__ K16,
    _Float16* __restrict__ V16, _Float16* __restrict__ S16)
{
  __shared__ unsigned xs[32][68];     // x rows as f16 pairs (272B pitch)
  __shared__ _Float16 os[32][136];    // output bounce (272B pitch)

  const int cy = blockIdx.x;
  const int n0 = blockIdx.y * 32;
  const int tid = threadIdx.x;
  const float* bias = (cy == 0) ? bq : (cy == 1) ? bk : (cy == 2) ? bv : bskip;
  _Float16* dst     = (cy == 0) ? Q16 : (cy == 1) ? K16 : (cy == 2) ? V16 : S16;

  {
    int r = tid >> 3, c16 = (tid & 7) * 16;
    int row = n0 + r;
    float4 v0 = {0,0,0,0}, v1 = {0,0,0,0}, v2 = {0,0,0,0}, v3 = {0,0,0,0};
    if (row < NN) {
      const float4* xp = (const float4*)&x[(size_t)row * 128 + c16];
      v0 = xp[0]; v1 = xp[1]; v2 = xp[2]; v3 = xp[3];
    }
    unsigned* xr = &xs[r][c16 >> 1];
    xr[0] = pk16(v0.x, v0.y); xr[1] = pk16(v0.z, v0.w);
    xr[2] = pk16(v1.x, v1.y); xr[3] = pk16(v1.z, v1.w);
    xr[4] = pk16(v2.x, v2.y); xr[5] = pk16(v2.z, v2.w);
    xr[6] = pk16(v3.x, v3.y); xr[7] = pk16(v3.z, v3.w);
  }
  __syncthreads();

  const int w = tid >> 6, lane = tid & 63;
  const int mrow = (w & 1) << 4;        // wave's 16-row tile
  const int nh = w >> 1;                // n-tiles nh*4 .. nh*4+3

  f32x4 acc[4] = {{0,0,0,0},{0,0,0,0},{0,0,0,0},{0,0,0,0}};
#pragma unroll
  for (int ks = 0; ks < 4; ++ks) {
    U16 a_; a_.u = *(const uint4*)&xs[mrow + (lane & 15)][ks * 16 + ((lane >> 4) << 2)];
#pragma unroll
    for (int nt = 0; nt < 4; ++nt) {
      U16 b_; b_.u = wpf[((cy * 4 + ks) * 8 + nh * 4 + nt) * 64 + lane];
      acc[nt] = __builtin_amdgcn_mfma_f32_16x16x32_f16(a_.h, b_.h, acc[nt], 0, 0, 0);
    }
  }

  // bias + stash to LDS (D: col=lane&15, row=(lane>>4)*4+reg)
#pragma unroll
  for (int nt = 0; nt < 4; ++nt) {
    int col = (nh * 4 + nt) * 16 + (lane & 15);
    float bb = bias[col];
    int rbase = mrow + ((lane >> 4) << 2);
#pragma unroll
    for (int reg = 0; reg < 4; ++reg)
      os[rbase + reg][col] = (_Float16)(acc[nt][reg] + bb);
  }
  __syncthreads();

  {
    int r = tid >> 3, c16 = (tid & 7) * 16;
    int row = n0 + r;
    if (row < NN) {
      const _Float16* op = &os[r][c16];
      if (cy < 3) {
#pragma unroll
        for (int q = 0; q < 4; ++q) {
          int j4 = (c16 >> 2) + q;
          int po = ((j4 & 3) << 5) | ((j4 >> 2) << 2);
          *(half4v*)&dst[(size_t)row * 128 + po] = *(const half4v*)&op[q * 4];
        }
      } else {
        *(uint4*)&dst[(size_t)row * 128 + c16]     = ((const uint4*)op)[0];
        *(uint4*)&dst[(size_t)row * 128 + c16 + 8] = ((const uint4*)op)[1];
      }
    }
  }
}

// ---------------- parallel CSR scan (3 small kernels) ----------------------
__global__ __launch_bounds__(256) void k_scan1(const int* __restrict__ deg,
                                               int* __restrict__ off,
                                               int* __restrict__ choff,
                                               int* __restrict__ bsum,
                                               int* __restrict__ bsumc) {
  __shared__ int s[256], sc[256];
  const int b = blockIdx.x, t = threadIdx.x;
  const int n = b * 256 + t;
  int d = (n < NN) ? deg[n] : 0;
  int c = (d + 15) >> 4;
  s[t] = d; sc[t] = c;
  __syncthreads();
  for (int o = 1; o < 256; o <<= 1) {
    int v1 = 0, v2 = 0;
    if (t >= o) { v1 = s[t - o]; v2 = sc[t - o]; }
    __syncthreads();
    if (t >= o) { s[t] += v1; sc[t] += v2; }
    __syncthreads();
  }
  if (n < NN) { off[n] = s[t] - d; choff[n] = sc[t] - c; }
  if (t == 255) { bsum[b] = s[255]; bsumc[b] = sc[255]; }
}

__global__ __launch_bounds__(256) void k_scan2(int* __restrict__ bsum,
                                               int* __restrict__ bsumc,
                                               int* __restrict__ off,
                                               int* __restrict__ choff) {
  __shared__ int s[256], sc[256];
  const int t = threadIdx.x;
  int v = (t < NBLK) ? bsum[t] : 0;
  int vc = (t < NBLK) ? bsumc[t] : 0;
  s[t] = v; sc[t] = vc;
  __syncthreads();
  for (int o = 1; o < 256; o <<= 1) {
    int v1 = 0, v2 = 0;
    if (t >= o) { v1 = s[t - o]; v2 = sc[t - o]; }
    __syncthreads();
    if (t >= o) { s[t] += v1; sc[t] += v2; }
    __syncthreads();
  }
  if (t < NBLK) { bsum[t] = s[t] - v; bsumc[t] = sc[t] - vc; }  // exclusive
  if (t == 255) { off[NN] = s[255]; choff[NN] = sc[255]; }
}

__global__ void k_scan3(int* __restrict__ off, int* __restrict__ choff,
                        const int* __restrict__ bsum, const int* __restrict__ bsumc) {
  int b = blockIdx.x, n = b * 256 + threadIdx.x;
  if (n < NN) { off[n] += bsum[b]; choff[n] += bsumc[b]; }
}

// fused: blocks [0,3125) fill elist; blocks [3125,3321) build chunk table
__global__ void k_fillch(const int* __restrict__ ei, const int* __restrict__ deg,
                         const int* __restrict__ off, const int* __restrict__ choff,
                         int* __restrict__ cur, int* __restrict__ elist,
                         uint2* __restrict__ chunks) {
  int b = blockIdx.x;
  if (b < 3125) {
    int e = b * 256 + threadIdx.x;
    if (e < NE) {
      int d = ei[NE + e];
      int p = atomicAdd(&cur[d], 1);
      elist[off[d] + p] = e;
    }
  } else {
    int n = (b - 3125) * 256 + threadIdx.x;
    if (n < NN) {
      int d = deg[n], o = off[n], c = choff[n];
      int nch = (d + 15) >> 4;
      for (int j = 0; j < nch; ++j) {
        int cnt = d - 16 * j; if (cnt > 16) cnt = 16;
        chunks[c + j] = make_uint2((unsigned)(o + 16 * j),
                                   ((unsigned)n << 5) | (unsigned)cnt);
      }
    }
  }
}

// ---------------- k_edge: one straight-line wave per 16-edge chunk ----------
// DPP reductions on VALU; alpha via fdot2 (packed f16 dot); num accumulated
// in packed f16 (pk_add/pk_mul + packed DPP butterflies).
__global__ __launch_bounds__(512) void k_edge(
    const _Float16* __restrict__ Q16, const _Float16* __restrict__ K16,
    const _Float16* __restrict__ V16,
    const float* __restrict__ Wt, const float* __restrict__ bt,
    const uint4* __restrict__ wefrag,
    const float* __restrict__ msg, const int* __restrict__ last_update,
    const int* __restrict__ ei, const int* __restrict__ tt,
    const int* __restrict__ elist, const uint2* __restrict__ chunks,
    const int* __restrict__ choff,
    unsigned* __restrict__ numbuf, float4* __restrict__ mdm,
    float4* __restrict__ mdd)
{
  __shared__ uint4 wef_s[2048];
  __shared__ float2 wtbt_s[104];
  __shared__ unsigned accs_u[8][64];

  for (int i = threadIdx.x; i < 2048; i += 512) wef_s[i] = wefrag[i];
  if (threadIdx.x < 104) {
    int j = threadIdx.x;
    wtbt_s[j] = make_float2(j < TDIM ? Wt[j] : 0.f, j < TDIM ? bt[j] : 0.f);
  }
  __syncthreads();

  const int wid = threadIdx.x >> 6, lane = threadIdx.x & 63;
  const int chunk = blockIdx.x * 8 + wid;
  if (chunk >= choff[NN]) return;

  uint2 ce = chunks[chunk];
  const int estart = (int)ce.x;
  const int node = (int)(ce.y >> 5);
  const int cnt = (int)(ce.y & 31u);
  const int g = lane >> 4, ed = lane & 15;

  // per-lane direct gathers (16 distinct addrs, cache-deduped); clamp keeps
  // invalid lanes in-bounds, their w becomes 0 below.
  const int edc = (ed < cnt) ? ed : (cnt - 1);
  const int eid = elist[estart + edc];
  const int src_b = ei[eid];
  const float mg_b = msg[eid];
  const float rel_b = (float)(last_update[src_b] - tt[eid]);
  const bool valid = (ed < cnt);

  unsigned bfu[4][4];
  build_bfu(rel_b, mg_b, g, wtbt_s, bfu);

  // e via MFMA: ec[mt][r] = e[ed][mt*16+g*4+r]
  f32x4 ec[8];
#pragma unroll
  for (int mt = 0; mt < 8; ++mt) {
    f32x4 c4 = {0.f, 0.f, 0.f, 0.f};
#pragma unroll
    for (int ks = 0; ks < 4; ++ks) {
      U16 av2; av2.u = wef_s[(ks * 8 + mt) * 64 + lane];
      U16 bv2; bv2.u.x = bfu[ks][0]; bv2.u.y = bfu[ks][1];
      bv2.u.z = bfu[ks][2]; bv2.u.w = bfu[ks][3];
      c4 = __builtin_amdgcn_mfma_f32_16x16x32_f16(av2.h, bv2.h, c4, 0, 0, 0);
    }
    ec[mt] = c4;
  }

  // pack e to f16 pairs; pair layout matches the permuted q/k/v uint4 blocks:
  // block i (head i) = pairs {4i..4i+3} = channels (2i..2i+1 tiles)
  unsigned ep2[16];
#pragma unroll
  for (int mt = 0; mt < 8; ++mt) {
    ep2[mt * 2 + 0] = pk16(ec[mt][0], ec[mt][1]);
    ep2[mt * 2 + 1] = pk16(ec[mt][2], ec[mt][3]);
  }

  // per-head alpha = q.k + q.e via fdot2
  float pal[4];
  {
    const uint4* qp = (const uint4*)&Q16[(size_t)node * 128 + g * 32];
    const uint4* kp = (const uint4*)&K16[(size_t)src_b * 128 + g * 32];
#pragma unroll
    for (int i = 0; i < 4; ++i) {
      uint4 qa = qp[i], ka = kp[i];
      float p = 0.f;
      p = fdot2f(qa.x, ka.x, p); p = fdot2f(qa.y, ka.y, p);
      p = fdot2f(qa.z, ka.z, p); p = fdot2f(qa.w, ka.w, p);
      p = fdot2f(qa.x, ep2[4 * i + 0], p); p = fdot2f(qa.y, ep2[4 * i + 1], p);
      p = fdot2f(qa.z, ep2[4 * i + 2], p); p = fdot2f(qa.w, ep2[4 * i + 3], p);
      pal[i] = p;
    }
  }

  // per-head: complete dot across g-lanes (shfl), chunk softmax via DPP
  float m_[4], w_[4], d_[4];
#pragma unroll
  for (int h = 0; h < 4; ++h) {
    float p = pal[h];
    p += __shfl_xor(p, 16); p += __shfl_xor(p, 32);
    float al = valid ? p * 0.17677669529663689f : -INFINITY;
    float mm = red16_max(al);
    m_[h] = mm;
    w_[h] = __expf(al - mm);       // invalid -> 0
    d_[h] = red16_add(w_[h]);
  }

  // partial num in packed f16: w*(v+e), reduced over ed with packed DPP
  unsigned np2[16];
  {
    const uint4* vp = (const uint4*)&V16[(size_t)src_b * 128 + g * 32];
#pragma unroll
    for (int i = 0; i < 4; ++i) {
      uint4 va = vp[i];
      unsigned w2 = pk16(w_[i], w_[i]);
      np2[4 * i + 0] = pkmul(pkadd(va.x, ep2[4 * i + 0]), w2);
      np2[4 * i + 1] = pkmul(pkadd(va.y, ep2[4 * i + 1]), w2);
      np2[4 * i + 2] = pkmul(pkadd(va.z, ep2[4 * i + 2]), w2);
      np2[4 * i + 3] = pkmul(pkadd(va.w, ep2[4 * i + 3]), w2);
    }
  }
#pragma unroll
  for (int j = 0; j < 16; ++j) np2[j] = red16_pkadd(np2[j]);

  // stash reduced pairs: natural pair index P = 16i + 8(j>>1) + 2g + (j&1)
  if (ed == 0) {
#pragma unroll
    for (int i = 0; i < 4; ++i)
#pragma unroll
      for (int j = 0; j < 4; ++j)
        accs_u[wid][16 * i + 8 * (j >> 1) + 2 * g + (j & 1)] = np2[4 * i + j];
  }
  __asm__ volatile("s_waitcnt lgkmcnt(0)" ::: "memory");

  numbuf[(size_t)chunk * 64 + lane] = accs_u[wid][lane];
  if (lane == 0) {
    mdm[chunk] = make_float4(m_[0], m_[1], m_[2], m_[3]);
    mdd[chunk] = make_float4(d_[0], d_[1], d_[2], d_[3]);
  }
}

// ---------------- k_comb: per-head flash combine + skip/relu/layernorm ------
__global__ __launch_bounds__(256) void k_comb(
    const unsigned* __restrict__ numbuf, const float* __restrict__ mdmf,
    const float* __restrict__ mddf, const _Float16* __restrict__ S16,
    const float* __restrict__ gamma, const float* __restrict__ beta,
    const int* __restrict__ choff, float* __restrict__ out)
{
  const int wid = threadIdx.x >> 6, lane = threadIdx.x & 63;
  const int node = blockIdx.x * 4 + wid;
  const int g = lane >> 4;          // head of channels 2*lane, 2*lane+1
  const int c0 = choff[node], c1 = choff[node + 1];

  float M = -INFINITY;
  for (int c = c0; c < c1; ++c) M = fmaxf(M, mdmf[c * 4 + g]);

  float den = 0.f, n0 = 0.f, n1 = 0.f;
  for (int c = c0; c < c1; ++c) {
    float sc = __expf(mdmf[c * 4 + g] - M);
    den = fmaf(mddf[c * 4 + g], sc, den);
    U4h u; u.u = numbuf[(size_t)c * 64 + lane];
    n0 = fmaf((float)u.h.x, sc, n0);
    n1 = fmaf((float)u.h.y, sc, n1);
  }

  float iv = 1.f / (den + 1e-16f);
  U4h s2; s2.u = *(const unsigned*)&S16[(size_t)node * 128 + 2 * lane];
  float r0 = fmaxf(fmaf(n0, iv, (float)s2.h.x), 0.f);
  float r1 = fmaxf(fmaf(n1, iv, (float)s2.h.y), 0.f);

  float sum = r0 + r1;
#pragma unroll
  for (int o = 1; o < 64; o <<= 1) sum += __shfl_xor(sum, o);
  float mu = sum * 0.0078125f;
  float d0 = r0 - mu, d1 = r1 - mu;
  float vs = d0 * d0 + d1 * d1;
#pragma unroll
  for (int o = 1; o < 64; o <<= 1) vs += __shfl_xor(vs, o);
  float rstd = rsqrtf(vs * 0.0078125f + 1e-5f);
  float2 gm = ((const float2*)gamma)[lane], bb = ((const float2*)beta)[lane];
  ((float2*)out)[node * 64 + lane] =
      make_float2(d0 * rstd * gm.x + bb.x, d1 * rstd * gm.y + bb.y);
}

// ---------------- launch ----------------
// ws (bytes): Q16 0 | S16 12.8M | K16 25.6M | V16 38.4M | numbuf 51.2M (25.6M)
//   deg 76.8M | cur 77.0M | off 77.2M | choff 77,400,064 | elist 77,600,128
//   wef 80,800,128 | chunks 80,832,896 | mdm 81,632,896 | mdd 83,232,896
//   wpf 84,832,896 (128KB) | bsum 84,963,968 | bsumc 84,964,968 | end 84,965,968
extern "C" void kernel_launch(void* const* d_in, const int* in_sizes, int n_in,
                              void* d_out, int out_size, void* d_ws, size_t ws_size,
                              hipStream_t stream)
{
  (void)in_sizes; (void)n_in; (void)out_size;
  if (ws_size < 84965968u) return;

  const float* x     = (const float*)d_in[0];
  const float* msg   = (const float*)d_in[1];
  const float* Wt    = (const float*)d_in[2];
  const float* bt    = (const float*)d_in[3];
  const float* Wq    = (const float*)d_in[4];
  const float* bq    = (const float*)d_in[5];
  const float* Wk    = (const float*)d_in[6];
  const float* bk    = (const float*)d_in[7];
  const float* Wv    = (const float*)d_in[8];
  const float* bv    = (const float*)d_in[9];
  const float* We    = (const float*)d_in[10];
  const float* Wskip = (const float*)d_in[11];
  const float* bskip = (const float*)d_in[12];
  const float* gamma = (const float*)d_in[13];
  const float* beta  = (const float*)d_in[14];
  const int* last_update = (const int*)d_in[15];
  const int* ei    = (const int*)d_in[16];
  const int* tt    = (const int*)d_in[17];

  char* ws = (char*)d_ws;
  _Float16* Q16 = (_Float16*)(ws);
  _Float16* S16 = (_Float16*)(ws + 12800000);
  _Float16* K16 = (_Float16*)(ws + 25600000);
  _Float16* V16 = (_Float16*)(ws + 38400000);
  unsigned* numbuf = (unsigned*)(ws + 51200000);
  int* deg   = (int*)(ws + 76800000);
  int* cur   = (int*)(ws + 77000000);
  int* off   = (int*)(ws + 77200000);
  int* choff = (int*)(ws + 77400064);
  int* elist = (int*)(ws + 77600128);
  uint4* wef = (uint4*)(ws + 80800128);
  uint2* chunks = (uint2*)(ws + 80832896);
  float4* mdm = (float4*)(ws + 81632896);
  float4* mdd = (float4*)(ws + 83232896);
  uint4* wpf = (uint4*)(ws + 84832896);
  int* bsum  = (int*)(ws + 84963968);
  int* bsumc = (int*)(ws + 84964968);

  (void)hipMemsetAsync(deg, 0, 400000, stream);        // deg + cur
  k_init<<<(NE + 255) / 256, 256, 0, stream>>>(We, Wq, Wk, Wv, Wskip, wef, wpf,
                                               ei, deg);
  k_scan1<<<NBLK, 256, 0, stream>>>(deg, off, choff, bsum, bsumc);
  k_scan2<<<1, 256, 0, stream>>>(bsum, bsumc, off, choff);
  k_scan3<<<NBLK, 256, 0, stream>>>(off, choff, bsum, bsumc);
  k_fillch<<<3125 + (NN + 255) / 256, 256, 0, stream>>>(ei, deg, off, choff,
                                                        cur, elist, chunks);
  dim3 pg(4, (NN + 31) / 32);
  k_proj2<<<pg, 256, 0, stream>>>(x, bq, bk, bv, bskip, wpf,
                                  Q16, K16, V16, S16);
  k_edge<<<MAXCH / 8, 512, 0, stream>>>(Q16, K16, V16, Wt, bt, wef,
                                        msg, last_update, ei, tt, elist,
                                        chunks, choff, numbuf, mdm, mdd);
  k_comb<<<NN / 4, 256, 0, stream>>>(numbuf, (const float*)mdm, (const float*)mdd,
                                     S16, gamma, beta, choff, (float*)d_out);
}

// Round 15
// 274.508 us; speedup vs baseline: 3.6886x; 1.0070x over previous
//
#include <hip/hip_runtime.h>
#include <math.h>

#define NN 50000
#define NE 800000
#define TDIM 100
#define MAXCH 100000   // sum ceil(deg/16) <= 50000 + 800000/16 = 100000
#define NBLK 196       // ceil(NN/256)

typedef _Float16 half2v __attribute__((ext_vector_type(2)));
typedef _Float16 half4v __attribute__((ext_vector_type(4)));
typedef _Float16 half8v __attribute__((ext_vector_type(8)));
typedef __fp16 fp16x2 __attribute__((ext_vector_type(2)));
typedef float f32x4 __attribute__((ext_vector_type(4)));

union U16 { uint4 u; half8v h; };
union U4h { unsigned u; half2v h; };

// cos(x) matching np.cos(float32) to ~1e-6.
__device__ __forceinline__ float ref_cosf(float x) {
  const float C1 = 0.15915494f;
  const float C2 = 6.42063831e-9f;
  float p = x * C1;
  float r = __fmaf_rn(x, C1, -p);
  r = __fmaf_rn(x, C2, r);
  float n = rintf(p);
  float f = (p - n) + r;
  return __builtin_amdgcn_cosf(f);
}

__device__ __forceinline__ unsigned pk16(float a, float b) {
  fp16x2 h = __builtin_amdgcn_cvt_pkrtz(a, b);
  unsigned u;
  __builtin_memcpy(&u, &h, 4);
  return u;
}

__device__ __forceinline__ float fdot2f(unsigned a, unsigned b, float c) {
  U4h ua, ub; ua.u = a; ub.u = b;
#if __has_builtin(__builtin_amdgcn_fdot2)
  return __builtin_amdgcn_fdot2(ua.h, ub.h, c, false);
#else
  return c + (float)ua.h.x * (float)ub.h.x + (float)ua.h.y * (float)ub.h.y;
#endif
}

// packed f16 helpers (v_pk_add_f16 / v_pk_mul_f16)
__device__ __forceinline__ unsigned pkadd(unsigned a, unsigned b) {
  half2v x, y; __builtin_memcpy(&x, &a, 4); __builtin_memcpy(&y, &b, 4);
  half2v z = x + y; unsigned r; __builtin_memcpy(&r, &z, 4); return r;
}
__device__ __forceinline__ unsigned pkmul(unsigned a, unsigned b) {
  half2v x, y; __builtin_memcpy(&x, &a, 4); __builtin_memcpy(&y, &b, 4);
  half2v z = x * y; unsigned r; __builtin_memcpy(&r, &z, 4); return r;
}

// ---- DPP 16-lane butterfly (VALU pipe): masks {1,2,7,15} -------------------
template<int CTRL>
__device__ __forceinline__ int dpp_i(int x) {
  return __builtin_amdgcn_update_dpp(0, x, CTRL, 0xf, 0xf, true);
}
template<int CTRL>
__device__ __forceinline__ float dpp_addf(float x) {
  return x + __int_as_float(dpp_i<CTRL>(__float_as_int(x)));
}
template<int CTRL>
__device__ __forceinline__ float dpp_maxf(float x) {
  return fmaxf(x, __int_as_float(dpp_i<CTRL>(__float_as_int(x))));
}
__device__ __forceinline__ float red16_add(float x) {
  x = dpp_addf<0xB1>(x); x = dpp_addf<0x4E>(x);
  x = dpp_addf<0x141>(x); x = dpp_addf<0x140>(x);
  return x;
}
__device__ __forceinline__ float red16_max(float x) {
  x = dpp_maxf<0xB1>(x); x = dpp_maxf<0x4E>(x);
  x = dpp_maxf<0x141>(x); x = dpp_maxf<0x140>(x);
  return x;
}
__device__ __forceinline__ unsigned red16_pkadd(unsigned x) {
  x = pkadd(x, (unsigned)dpp_i<0xB1>((int)x));
  x = pkadd(x, (unsigned)dpp_i<0x4E>((int)x));
  x = pkadd(x, (unsigned)dpp_i<0x141>((int)x));
  x = pkadd(x, (unsigned)dpp_i<0x140>((int)x));
  return x;
}

// attr fragments: lane slice g, j = ks*32 + g*8 + 2p (+1); j>100 -> 0
__device__ __forceinline__ void build_bfu(float rel_b, float mg_b, int g,
                                          const float2* wtbt_s, unsigned bfu[4][4]) {
#pragma unroll
  for (int ks = 0; ks < 4; ++ks) {
#pragma unroll
    for (int p = 0; p < 4; ++p) {
      int j0 = ks * 32 + g * 8 + 2 * p;
      float a0 = 0.f, a1 = 0.f;
      if (ks < 3) {
        float2 w0 = wtbt_s[j0], w1 = wtbt_s[j0 + 1];
        a0 = ref_cosf(__fmaf_rn(rel_b, w0.x, w0.y));
        a1 = ref_cosf(__fmaf_rn(rel_b, w1.x, w1.y));
      } else {
        if (j0 < 100) {
          float2 w0 = wtbt_s[j0];
          a0 = ref_cosf(__fmaf_rn(rel_b, w0.x, w0.y));
        } else if (j0 == 100) a0 = mg_b;
        if (j0 + 1 < 100) {
          float2 w1 = wtbt_s[j0 + 1];
          a1 = ref_cosf(__fmaf_rn(rel_b, w1.x, w1.y));
        } else if (j0 + 1 == 100) a1 = mg_b;
      }
      bfu[ks][p] = pk16(a0, a1);
    }
  }
}

// ---------------- k_init: W fragments + degree count (fused) ---------------
__global__ void k_init(const float* __restrict__ We,
                       const float* __restrict__ Wq, const float* __restrict__ Wk,
                       const float* __restrict__ Wv, const float* __restrict__ Wskip,
                       uint4* __restrict__ wef, uint4* __restrict__ wpf,
                       const int* __restrict__ ei, int* __restrict__ deg) {
  int idx = blockIdx.x * 256 + threadIdx.x;
  if (idx < 2048) {
    int lane = idx & 63, fi = idx >> 6;
    int ks = fi >> 3, mt = fi & 7;
    int ch = mt * 16 + (lane & 15);
    int k0 = ks * 32 + ((lane >> 4) << 3);
    U16 cv;
#pragma unroll
    for (int jj = 0; jj < 8; ++jj) {
      int j = k0 + jj;
      cv.h[jj] = (j <= 100) ? (_Float16)We[j * 128 + ch] : (_Float16)0.f;
    }
    wef[idx] = cv.u;
  } else if (idx < 2048 + 8192) {
    int i2 = idx - 2048;
    int lane = i2 & 63, fi = i2 >> 6;     // fi = (cy*4+ks)*8+nt
    int nt = fi & 7, ks = (fi >> 3) & 3, cy = fi >> 5;
    const float* W = (cy == 0) ? Wq : (cy == 1) ? Wk : (cy == 2) ? Wv : Wskip;
    int n = nt * 16 + (lane & 15);
    int k0 = ks * 32 + ((lane >> 4) << 3);
    U16 cv;
#pragma unroll
    for (int jj = 0; jj < 8; ++jj)
      cv.h[jj] = (_Float16)W[(k0 + jj) * 128 + n];
    wpf[i2] = cv.u;
  }
  if (idx < NE) atomicAdd(&deg[ei[NE + idx]], 1);
}

// ---------------- MFMA projection v2: all 4 outputs, x staged once ----------
// 512 threads; wave w: cy = w>>1, 64-col half = w&1; 32 rows per block.
// Q,K,V stored PERMUTED: channel c -> ((c>>2)&3)*32 + (c>>4)*4 + (c&3).
__global__ __launch_bounds__(512) void k_proj2(
    const float* __restrict__ x,
    const float* __restrict__ bq, const float* __restrict__ bk,
    const float* __restrict__ bv, const float* __restrict__ bskip,
    const uint4* __restrict__ wpf,
    _Float16* __restrict__ Q16, _Float16* __restrict__ K16,
    _Float16* __restrict__ V16, _Float16* __restrict__ S16)
{
  __shared__ unsigned xs[32][68];     // x rows as f16 pairs (272B pitch)
  __shared__ _Float16 os[32][136];    // output bounce (272B pitch)

  const int n0 = blockIdx.x * 32;
  const int tid = threadIdx.x;

  {
    int r = tid >> 4, c8 = (tid & 15) * 8;     // 32 rows x 16 col-groups of 8
    int row = n0 + r;
    float4 v0 = {0,0,0,0}, v1 = {0,0,0,0};
    if (row < NN) {
      const float4* xp = (const float4*)&x[(size_t)row * 128 + c8];
      v0 = xp[0]; v1 = xp[1];
    }
    unsigned* xr = &xs[r][c8 >> 1];
    xr[0] = pk16(v0.x, v0.y); xr[1] = pk16(v0.z, v0.w);
    xr[2] = pk16(v1.x, v1.y); xr[3] = pk16(v1.z, v1.w);
  }
  __syncthreads();

  const int w = tid >> 6, lane = tid & 63;
  const int cy = w >> 1, half = w & 1;

  f32x4 acc[2][4] = {};
#pragma unroll
  for (int ks = 0; ks < 4; ++ks) {
    U16 a0_, a1_;
    a0_.u = *(const uint4*)&xs[lane & 15][ks * 16 + ((lane >> 4) << 2)];
    a1_.u = *(const uint4*)&xs[16 + (lane & 15)][ks * 16 + ((lane >> 4) << 2)];
#pragma unroll
    for (int nt = 0; nt < 4; ++nt) {
      U16 b_; b_.u = wpf[((cy * 4 + ks) * 8 + half * 4 + nt) * 64 + lane];
      acc[0][nt] = __builtin_amdgcn_mfma_f32_16x16x32_f16(a0_.h, b_.h, acc[0][nt], 0, 0, 0);
      acc[1][nt] = __builtin_amdgcn_mfma_f32_16x16x32_f16(a1_.h, b_.h, acc[1][nt], 0, 0, 0);
    }
  }

  const float* biases[4] = {bq, bk, bv, bskip};
  _Float16* dsts[4] = {Q16, K16, V16, S16};
#pragma unroll
  for (int c = 0; c < 4; ++c) {
    __syncthreads();
    if (cy == c) {
#pragma unroll
      for (int nt = 0; nt < 4; ++nt) {
        int col = half * 64 + nt * 16 + (lane & 15);
        float bb = biases[c][col];
        int rb = (lane >> 4) << 2;
#pragma unroll
        for (int mt2 = 0; mt2 < 2; ++mt2)
#pragma unroll
          for (int reg = 0; reg < 4; ++reg)
            os[mt2 * 16 + rb + reg][col] = (_Float16)(acc[mt2][nt][reg] + bb);
      }
    }
    __syncthreads();
    {
      int r = tid >> 4, c8 = (tid & 15) * 8;
      int row = n0 + r;
      if (row < NN) {
        _Float16* dst = dsts[c];
        const _Float16* op = &os[r][c8];
        if (c < 3) {
#pragma unroll
          for (int q = 0; q < 2; ++q) {
            int j4 = (c8 >> 2) + q;
            int po = ((j4 & 3) << 5) | ((j4 >> 2) << 2);
            *(half4v*)&dst[(size_t)row * 128 + po] = *(const half4v*)&op[q * 4];
          }
        } else {
          *(uint4*)&dst[(size_t)row * 128 + c8] = *((const uint4*)op);
        }
      }
    }
  }
}

// ---------------- parallel CSR scan (2 kernels) ----------------------------
__global__ __launch_bounds__(256) void k_scan1(const int* __restrict__ deg,
                                               int* __restrict__ off,
                                               int* __restrict__ choff,
                                               int* __restrict__ bsum,
                                               int* __restrict__ bsumc) {
  __shared__ int s[256], sc[256];
  const int b = blockIdx.x, t = threadIdx.x;
  const int n = b * 256 + t;
  int d = (n < NN) ? deg[n] : 0;
  int c = (d + 15) >> 4;
  s[t] = d; sc[t] = c;
  __syncthreads();
  for (int o = 1; o < 256; o <<= 1) {
    int v1 = 0, v2 = 0;
    if (t >= o) { v1 = s[t - o]; v2 = sc[t - o]; }
    __syncthreads();
    if (t >= o) { s[t] += v1; sc[t] += v2; }
    __syncthreads();
  }
  if (n < NN) { off[n] = s[t] - d; choff[n] = sc[t] - c; }
  if (t == 255) { bsum[b] = s[255]; bsumc[b] = sc[255]; }
}

// merged scan2+scan3: every block redundantly scans the 196 block sums,
// then adds its exclusive base to its 256 nodes.
__global__ __launch_bounds__(256) void k_scanf(const int* __restrict__ bsum,
                                               const int* __restrict__ bsumc,
                                               int* __restrict__ off,
                                               int* __restrict__ choff) {
  __shared__ int s[256], sc[256];
  const int b = blockIdx.x, t = threadIdx.x;
  s[t] = (t < NBLK) ? bsum[t] : 0;
  sc[t] = (t < NBLK) ? bsumc[t] : 0;
  __syncthreads();
  for (int o = 1; o < 256; o <<= 1) {
    int v1 = 0, v2 = 0;
    if (t >= o) { v1 = s[t - o]; v2 = sc[t - o]; }
    __syncthreads();
    if (t >= o) { s[t] += v1; sc[t] += v2; }
    __syncthreads();
  }
  int base = (b > 0) ? s[b - 1] : 0;
  int basec = (b > 0) ? sc[b - 1] : 0;
  int n = b * 256 + t;
  if (n < NN) { off[n] += base; choff[n] += basec; }
  if (b == 0 && t == 0) { off[NN] = s[NBLK - 1]; choff[NN] = sc[NBLK - 1]; }
}

// fused: blocks [0,3125) fill elist; blocks [3125,3321) build chunk table
__global__ void k_fillch(const int* __restrict__ ei, const int* __restrict__ deg,
                         const int* __restrict__ off, const int* __restrict__ choff,
                         int* __restrict__ cur, int* __restrict__ elist,
                         uint2* __restrict__ chunks) {
  int b = blockIdx.x;
  if (b < 3125) {
    int e = b * 256 + threadIdx.x;
    if (e < NE) {
      int d = ei[NE + e];
      int p = atomicAdd(&cur[d], 1);
      elist[off[d] + p] = e;
    }
  } else {
    int n = (b - 3125) * 256 + threadIdx.x;
    if (n < NN) {
      int d = deg[n], o = off[n], c = choff[n];
      int nch = (d + 15) >> 4;
      for (int j = 0; j < nch; ++j) {
        int cnt = d - 16 * j; if (cnt > 16) cnt = 16;
        chunks[c + j] = make_uint2((unsigned)(o + 16 * j),
                                   ((unsigned)n << 5) | (unsigned)cnt);
      }
    }
  }
}

// ---------------- k_edge: one straight-line wave per 16-edge chunk ----------
// DPP reductions on VALU; alpha via fdot2; num in packed f16.
__global__ __launch_bounds__(512) void k_edge(
    const _Float16* __restrict__ Q16, const _Float16* __restrict__ K16,
    const _Float16* __restrict__ V16,
    const float* __restrict__ Wt, const float* __restrict__ bt,
    const uint4* __restrict__ wefrag,
    const float* __restrict__ msg, const int* __restrict__ last_update,
    const int* __restrict__ ei, const int* __restrict__ tt,
    const int* __restrict__ elist, const uint2* __restrict__ chunks,
    const int* __restrict__ choff,
    unsigned* __restrict__ numbuf, float4* __restrict__ mdm,
    float4* __restrict__ mdd)
{
  __shared__ uint4 wef_s[2048];
  __shared__ float2 wtbt_s[104];
  __shared__ unsigned accs_u[8][64];

  const int nchunks = choff[NN];
  if (blockIdx.x * 8 >= nchunks) return;   // block-uniform: skip dead staging

  for (int i = threadIdx.x; i < 2048; i += 512) wef_s[i] = wefrag[i];
  if (threadIdx.x < 104) {
    int j = threadIdx.x;
    wtbt_s[j] = make_float2(j < TDIM ? Wt[j] : 0.f, j < TDIM ? bt[j] : 0.f);
  }
  __syncthreads();

  const int wid = threadIdx.x >> 6, lane = threadIdx.x & 63;
  const int chunk = blockIdx.x * 8 + wid;
  if (chunk >= nchunks) return;

  uint2 ce = chunks[chunk];
  const int estart = (int)ce.x;
  const int node = (int)(ce.y >> 5);
  const int cnt = (int)(ce.y & 31u);
  const int g = lane >> 4, ed = lane & 15;

  const int edc = (ed < cnt) ? ed : (cnt - 1);
  const int eid = elist[estart + edc];
  const int src_b = ei[eid];
  const float mg_b = msg[eid];
  const float rel_b = (float)(last_update[src_b] - tt[eid]);
  const bool valid = (ed < cnt);

  unsigned bfu[4][4];
  build_bfu(rel_b, mg_b, g, wtbt_s, bfu);

  // e via MFMA: ec[mt][r] = e[ed][mt*16+g*4+r]
  f32x4 ec[8];
#pragma unroll
  for (int mt = 0; mt < 8; ++mt) {
    f32x4 c4 = {0.f, 0.f, 0.f, 0.f};
#pragma unroll
    for (int ks = 0; ks < 4; ++ks) {
      U16 av2; av2.u = wef_s[(ks * 8 + mt) * 64 + lane];
      U16 bv2; bv2.u.x = bfu[ks][0]; bv2.u.y = bfu[ks][1];
      bv2.u.z = bfu[ks][2]; bv2.u.w = bfu[ks][3];
      c4 = __builtin_amdgcn_mfma_f32_16x16x32_f16(av2.h, bv2.h, c4, 0, 0, 0);
    }
    ec[mt] = c4;
  }

  // pack e to f16 pairs; pair layout matches permuted q/k/v uint4 blocks
  unsigned ep2[16];
#pragma unroll
  for (int mt = 0; mt < 8; ++mt) {
    ep2[mt * 2 + 0] = pk16(ec[mt][0], ec[mt][1]);
    ep2[mt * 2 + 1] = pk16(ec[mt][2], ec[mt][3]);
  }

  // per-head alpha = q.k + q.e via fdot2
  float pal[4];
  {
    const uint4* qp = (const uint4*)&Q16[(size_t)node * 128 + g * 32];
    const uint4* kp = (const uint4*)&K16[(size_t)src_b * 128 + g * 32];
#pragma unroll
    for (int i = 0; i < 4; ++i) {
      uint4 qa = qp[i], ka = kp[i];
      float p = 0.f;
      p = fdot2f(qa.x, ka.x, p); p = fdot2f(qa.y, ka.y, p);
      p = fdot2f(qa.z, ka.z, p); p = fdot2f(qa.w, ka.w, p);
      p = fdot2f(qa.x, ep2[4 * i + 0], p); p = fdot2f(qa.y, ep2[4 * i + 1], p);
      p = fdot2f(qa.z, ep2[4 * i + 2], p); p = fdot2f(qa.w, ep2[4 * i + 3], p);
      pal[i] = p;
    }
  }

  // per-head: complete dot across g-lanes (shfl), chunk softmax via DPP
  float m_[4], w_[4], d_[4];
#pragma unroll
  for (int h = 0; h < 4; ++h) {
    float p = pal[h];
    p += __shfl_xor(p, 16); p += __shfl_xor(p, 32);
    float al = valid ? p * 0.17677669529663689f : -INFINITY;
    float mm = red16_max(al);
    m_[h] = mm;
    w_[h] = __expf(al - mm);       // invalid -> 0
    d_[h] = red16_add(w_[h]);
  }

  // partial num in packed f16: w*(v+e), reduced over ed with packed DPP
  unsigned np2[16];
  {
    const uint4* vp = (const uint4*)&V16[(size_t)src_b * 128 + g * 32];
#pragma unroll
    for (int i = 0; i < 4; ++i) {
      uint4 va = vp[i];
      unsigned w2 = pk16(w_[i], w_[i]);
      np2[4 * i + 0] = pkmul(pkadd(va.x, ep2[4 * i + 0]), w2);
      np2[4 * i + 1] = pkmul(pkadd(va.y, ep2[4 * i + 1]), w2);
      np2[4 * i + 2] = pkmul(pkadd(va.z, ep2[4 * i + 2]), w2);
      np2[4 * i + 3] = pkmul(pkadd(va.w, ep2[4 * i + 3]), w2);
    }
  }
#pragma unroll
  for (int j = 0; j < 16; ++j) np2[j] = red16_pkadd(np2[j]);

  // stash reduced pairs: natural pair index P = 16i + 8(j>>1) + 2g + (j&1)
  if (ed == 0) {
#pragma unroll
    for (int i = 0; i < 4; ++i)
#pragma unroll
      for (int j = 0; j < 4; ++j)
        accs_u[wid][16 * i + 8 * (j >> 1) + 2 * g + (j & 1)] = np2[4 * i + j];
  }
  __asm__ volatile("s_waitcnt lgkmcnt(0)" ::: "memory");

  numbuf[(size_t)chunk * 64 + lane] = accs_u[wid][lane];
  if (lane == 0) {
    mdm[chunk] = make_float4(m_[0], m_[1], m_[2], m_[3]);
    mdd[chunk] = make_float4(d_[0], d_[1], d_[2], d_[3]);
  }
}

// ---------------- k_comb: per-head flash combine + skip/relu/layernorm ------
__global__ __launch_bounds__(256) void k_comb(
    const unsigned* __restrict__ numbuf, const float* __restrict__ mdmf,
    const float* __restrict__ mddf, const _Float16* __restrict__ S16,
    const float* __restrict__ gamma, const float* __restrict__ beta,
    const int* __restrict__ choff, float* __restrict__ out)
{
  const int wid = threadIdx.x >> 6, lane = threadIdx.x & 63;
  const int node = blockIdx.x * 4 + wid;
  const int g = lane >> 4;          // head of channels 2*lane, 2*lane+1
  const int c0 = choff[node], c1 = choff[node + 1];

  float M = -INFINITY;
  for (int c = c0; c < c1; ++c) M = fmaxf(M, mdmf[c * 4 + g]);

  float den = 0.f, n0 = 0.f, n1 = 0.f;
  for (int c = c0; c < c1; ++c) {
    float sc = __expf(mdmf[c * 4 + g] - M);
    den = fmaf(mddf[c * 4 + g], sc, den);
    U4h u; u.u = numbuf[(size_t)c * 64 + lane];
    n0 = fmaf((float)u.h.x, sc, n0);
    n1 = fmaf((float)u.h.y, sc, n1);
  }

  float iv = 1.f / (den + 1e-16f);
  U4h s2; s2.u = *(const unsigned*)&S16[(size_t)node * 128 + 2 * lane];
  float r0 = fmaxf(fmaf(n0, iv, (float)s2.h.x), 0.f);
  float r1 = fmaxf(fmaf(n1, iv, (float)s2.h.y), 0.f);

  float sum = r0 + r1;
#pragma unroll
  for (int o = 1; o < 64; o <<= 1) sum += __shfl_xor(sum, o);
  float mu = sum * 0.0078125f;
  float d0 = r0 - mu, d1 = r1 - mu;
  float vs = d0 * d0 + d1 * d1;
#pragma unroll
  for (int o = 1; o < 64; o <<= 1) vs += __shfl_xor(vs, o);
  float rstd = rsqrtf(vs * 0.0078125f + 1e-5f);
  float2 gm = ((const float2*)gamma)[lane], bb = ((const float2*)beta)[lane];
  ((float2*)out)[node * 64 + lane] =
      make_float2(d0 * rstd * gm.x + bb.x, d1 * rstd * gm.y + bb.y);
}

// ---------------- launch ----------------
// ws (bytes): Q16 0 | S16 12.8M | K16 25.6M | V16 38.4M | numbuf 51.2M (25.6M)
//   deg 76.8M | cur 77.0M | off 77.2M | choff 77,400,064 | elist 77,600,128
//   wef 80,800,128 | chunks 80,832,896 | mdm 81,632,896 | mdd 83,232,896
//   wpf 84,832,896 (128KB) | bsum 84,963,968 | bsumc 84,964,968 | end 84,965,968
extern "C" void kernel_launch(void* const* d_in, const int* in_sizes, int n_in,
                              void* d_out, int out_size, void* d_ws, size_t ws_size,
                              hipStream_t stream)
{
  (void)in_sizes; (void)n_in; (void)out_size;
  if (ws_size < 84965968u) return;

  const float* x     = (const float*)d_in[0];
  const float* msg   = (const float*)d_in[1];
  const float* Wt    = (const float*)d_in[2];
  const float* bt    = (const float*)d_in[3];
  const float* Wq    = (const float*)d_in[4];
  const float* bq    = (const float*)d_in[5];
  const float* Wk    = (const float*)d_in[6];
  const float* bk    = (const float*)d_in[7];
  const float* Wv    = (const float*)d_in[8];
  const float* bv    = (const float*)d_in[9];
  const float* We    = (const float*)d_in[10];
  const float* Wskip = (const float*)d_in[11];
  const float* bskip = (const float*)d_in[12];
  const float* gamma = (const float*)d_in[13];
  const float* beta  = (const float*)d_in[14];
  const int* last_update = (const int*)d_in[15];
  const int* ei    = (const int*)d_in[16];
  const int* tt    = (const int*)d_in[17];

  char* ws = (char*)d_ws;
  _Float16* Q16 = (_Float16*)(ws);
  _Float16* S16 = (_Float16*)(ws + 12800000);
  _Float16* K16 = (_Float16*)(ws + 25600000);
  _Float16* V16 = (_Float16*)(ws + 38400000);
  unsigned* numbuf = (unsigned*)(ws + 51200000);
  int* deg   = (int*)(ws + 76800000);
  int* cur   = (int*)(ws + 77000000);
  int* off   = (int*)(ws + 77200000);
  int* choff = (int*)(ws + 77400064);
  int* elist = (int*)(ws + 77600128);
  uint4* wef = (uint4*)(ws + 80800128);
  uint2* chunks = (uint2*)(ws + 80832896);
  float4* mdm = (float4*)(ws + 81632896);
  float4* mdd = (float4*)(ws + 83232896);
  uint4* wpf = (uint4*)(ws + 84832896);
  int* bsum  = (int*)(ws + 84963968);
  int* bsumc = (int*)(ws + 84964968);

  (void)hipMemsetAsync(deg, 0, 400000, stream);        // deg + cur
  k_init<<<(NE + 255) / 256, 256, 0, stream>>>(We, Wq, Wk, Wv, Wskip, wef, wpf,
                                               ei, deg);
  k_scan1<<<NBLK, 256, 0, stream>>>(deg, off, choff, bsum, bsumc);
  k_scanf<<<NBLK, 256, 0, stream>>>(bsum, bsumc, off, choff);
  k_fillch<<<3125 + (NN + 255) / 256, 256, 0, stream>>>(ei, deg, off, choff,
                                                        cur, elist, chunks);
  k_proj2<<<(NN + 31) / 32, 512, 0, stream>>>(x, bq, bk, bv, bskip, wpf,
                                              Q16, K16, V16, S16);
  k_edge<<<MAXCH / 8, 512, 0, stream>>>(Q16, K16, V16, Wt, bt, wef,
                                        msg, last_update, ei, tt, elist,
                                        chunks, choff, numbuf, mdm, mdd);
  k_comb<<<NN / 4, 256, 0, stream>>>(numbuf, (const float*)mdm, (const float*)mdd,
                                     S16, gamma, beta, choff, (float*)d_out);
}

// Round 16
// 263.885 us; speedup vs baseline: 3.8371x; 1.0403x over previous
//
#include <hip/hip_runtime.h>
#include <math.h>

#define NN 50000
#define NE 800000
#define TDIM 100
#define MAXCH 100000   // sum ceil(deg/16) <= 50000 + 800000/16 = 100000
#define NBLK 196       // ceil(NN/256)
#define EGRID 1024     // persistent k_edge blocks (4/CU)

typedef _Float16 half2v __attribute__((ext_vector_type(2)));
typedef _Float16 half4v __attribute__((ext_vector_type(4)));
typedef _Float16 half8v __attribute__((ext_vector_type(8)));
typedef __fp16 fp16x2 __attribute__((ext_vector_type(2)));
typedef float f32x4 __attribute__((ext_vector_type(4)));

union U16 { uint4 u; half8v h; };
union U4h { unsigned u; half2v h; };

// cos(x) matching np.cos(float32) to ~1e-6.
__device__ __forceinline__ float ref_cosf(float x) {
  const float C1 = 0.15915494f;
  const float C2 = 6.42063831e-9f;
  float p = x * C1;
  float r = __fmaf_rn(x, C1, -p);
  r = __fmaf_rn(x, C2, r);
  float n = rintf(p);
  float f = (p - n) + r;
  return __builtin_amdgcn_cosf(f);
}

__device__ __forceinline__ unsigned pk16(float a, float b) {
  fp16x2 h = __builtin_amdgcn_cvt_pkrtz(a, b);
  unsigned u;
  __builtin_memcpy(&u, &h, 4);
  return u;
}

__device__ __forceinline__ float fdot2f(unsigned a, unsigned b, float c) {
  U4h ua, ub; ua.u = a; ub.u = b;
#if __has_builtin(__builtin_amdgcn_fdot2)
  return __builtin_amdgcn_fdot2(ua.h, ub.h, c, false);
#else
  return c + (float)ua.h.x * (float)ub.h.x + (float)ua.h.y * (float)ub.h.y;
#endif
}

// packed f16 helpers (v_pk_add_f16 / v_pk_mul_f16)
__device__ __forceinline__ unsigned pkadd(unsigned a, unsigned b) {
  half2v x, y; __builtin_memcpy(&x, &a, 4); __builtin_memcpy(&y, &b, 4);
  half2v z = x + y; unsigned r; __builtin_memcpy(&r, &z, 4); return r;
}
__device__ __forceinline__ unsigned pkmul(unsigned a, unsigned b) {
  half2v x, y; __builtin_memcpy(&x, &a, 4); __builtin_memcpy(&y, &b, 4);
  half2v z = x * y; unsigned r; __builtin_memcpy(&r, &z, 4); return r;
}

// ---- DPP 16-lane butterfly (VALU pipe): masks {1,2,7,15} -------------------
template<int CTRL>
__device__ __forceinline__ int dpp_i(int x) {
  return __builtin_amdgcn_update_dpp(0, x, CTRL, 0xf, 0xf, true);
}
template<int CTRL>
__device__ __forceinline__ float dpp_addf(float x) {
  return x + __int_as_float(dpp_i<CTRL>(__float_as_int(x)));
}
template<int CTRL>
__device__ __forceinline__ float dpp_maxf(float x) {
  return fmaxf(x, __int_as_float(dpp_i<CTRL>(__float_as_int(x))));
}
__device__ __forceinline__ float red16_add(float x) {
  x = dpp_addf<0xB1>(x); x = dpp_addf<0x4E>(x);
  x = dpp_addf<0x141>(x); x = dpp_addf<0x140>(x);
  return x;
}
__device__ __forceinline__ float red16_max(float x) {
  x = dpp_maxf<0xB1>(x); x = dpp_maxf<0x4E>(x);
  x = dpp_maxf<0x141>(x); x = dpp_maxf<0x140>(x);
  return x;
}
__device__ __forceinline__ unsigned red16_pkadd(unsigned x) {
  x = pkadd(x, (unsigned)dpp_i<0xB1>((int)x));
  x = pkadd(x, (unsigned)dpp_i<0x4E>((int)x));
  x = pkadd(x, (unsigned)dpp_i<0x141>((int)x));
  x = pkadd(x, (unsigned)dpp_i<0x140>((int)x));
  return x;
}

// attr fragments: lane slice g, j = ks*32 + g*8 + 2p (+1); j>100 -> 0
__device__ __forceinline__ void build_bfu(float rel_b, float mg_b, int g,
                                          const float2* wtbt_s, unsigned bfu[4][4]) {
#pragma unroll
  for (int ks = 0; ks < 4; ++ks) {
#pragma unroll
    for (int p = 0; p < 4; ++p) {
      int j0 = ks * 32 + g * 8 + 2 * p;
      float a0 = 0.f, a1 = 0.f;
      if (ks < 3) {
        float2 w0 = wtbt_s[j0], w1 = wtbt_s[j0 + 1];
        a0 = ref_cosf(__fmaf_rn(rel_b, w0.x, w0.y));
        a1 = ref_cosf(__fmaf_rn(rel_b, w1.x, w1.y));
      } else {
        if (j0 < 100) {
          float2 w0 = wtbt_s[j0];
          a0 = ref_cosf(__fmaf_rn(rel_b, w0.x, w0.y));
        } else if (j0 == 100) a0 = mg_b;
        if (j0 + 1 < 100) {
          float2 w1 = wtbt_s[j0 + 1];
          a1 = ref_cosf(__fmaf_rn(rel_b, w1.x, w1.y));
        } else if (j0 + 1 == 100) a1 = mg_b;
      }
      bfu[ks][p] = pk16(a0, a1);
    }
  }
}

// ---------------- k_init: W fragments + degree count (fused) ---------------
__global__ void k_init(const float* __restrict__ We,
                       const float* __restrict__ Wq, const float* __restrict__ Wk,
                       const float* __restrict__ Wv, const float* __restrict__ Wskip,
                       uint4* __restrict__ wef, uint4* __restrict__ wpf,
                       const int* __restrict__ ei, int* __restrict__ deg) {
  int idx = blockIdx.x * 256 + threadIdx.x;
  if (idx < 2048) {
    int lane = idx & 63, fi = idx >> 6;
    int ks = fi >> 3, mt = fi & 7;
    int ch = mt * 16 + (lane & 15);
    int k0 = ks * 32 + ((lane >> 4) << 3);
    U16 cv;
#pragma unroll
    for (int jj = 0; jj < 8; ++jj) {
      int j = k0 + jj;
      cv.h[jj] = (j <= 100) ? (_Float16)We[j * 128 + ch] : (_Float16)0.f;
    }
    wef[idx] = cv.u;
  } else if (idx < 2048 + 8192) {
    int i2 = idx - 2048;
    int lane = i2 & 63, fi = i2 >> 6;     // fi = (cy*4+ks)*8+nt
    int nt = fi & 7, ks = (fi >> 3) & 3, cy = fi >> 5;
    const float* W = (cy == 0) ? Wq : (cy == 1) ? Wk : (cy == 2) ? Wv : Wskip;
    int n = nt * 16 + (lane & 15);
    int k0 = ks * 32 + ((lane >> 4) << 3);
    U16 cv;
#pragma unroll
    for (int jj = 0; jj < 8; ++jj)
      cv.h[jj] = (_Float16)W[(k0 + jj) * 128 + n];
    wpf[i2] = cv.u;
  }
  if (idx < NE) atomicAdd(&deg[ei[NE + idx]], 1);
}

// ---------------- MFMA projection v2: all 4 outputs, x staged once ----------
// 512 threads; wave w: cy = w>>1, 64-col half = w&1; 32 rows per block.
// Q,K,V stored PERMUTED: channel c -> ((c>>2)&3)*32 + (c>>4)*4 + (c&3).
__global__ __launch_bounds__(512) void k_proj2(
    const float* __restrict__ x,
    const float* __restrict__ bq, const float* __restrict__ bk,
    const float* __restrict__ bv, const float* __restrict__ bskip,
    const uint4* __restrict__ wpf,
    _Float16* __restrict__ Q16, _Float16* __restrict__ K16,
    _Float16* __restrict__ V16, _Float16* __restrict__ S16)
{
  __shared__ unsigned xs[32][68];     // x rows as f16 pairs (272B pitch)
  __shared__ _Float16 os[32][136];    // output bounce (272B pitch)

  const int n0 = blockIdx.x * 32;
  const int tid = threadIdx.x;

  {
    int r = tid >> 4, c8 = (tid & 15) * 8;     // 32 rows x 16 col-groups of 8
    int row = n0 + r;
    float4 v0 = {0,0,0,0}, v1 = {0,0,0,0};
    if (row < NN) {
      const float4* xp = (const float4*)&x[(size_t)row * 128 + c8];
      v0 = xp[0]; v1 = xp[1];
    }
    unsigned* xr = &xs[r][c8 >> 1];
    xr[0] = pk16(v0.x, v0.y); xr[1] = pk16(v0.z, v0.w);
    xr[2] = pk16(v1.x, v1.y); xr[3] = pk16(v1.z, v1.w);
  }
  __syncthreads();

  const int w = tid >> 6, lane = tid & 63;
  const int cy = w >> 1, half = w & 1;

  f32x4 acc[2][4] = {};
#pragma unroll
  for (int ks = 0; ks < 4; ++ks) {
    U16 a0_, a1_;
    a0_.u = *(const uint4*)&xs[lane & 15][ks * 16 + ((lane >> 4) << 2)];
    a1_.u = *(const uint4*)&xs[16 + (lane & 15)][ks * 16 + ((lane >> 4) << 2)];
#pragma unroll
    for (int nt = 0; nt < 4; ++nt) {
      U16 b_; b_.u = wpf[((cy * 4 + ks) * 8 + half * 4 + nt) * 64 + lane];
      acc[0][nt] = __builtin_amdgcn_mfma_f32_16x16x32_f16(a0_.h, b_.h, acc[0][nt], 0, 0, 0);
      acc[1][nt] = __builtin_amdgcn_mfma_f32_16x16x32_f16(a1_.h, b_.h, acc[1][nt], 0, 0, 0);
    }
  }

  const float* biases[4] = {bq, bk, bv, bskip};
  _Float16* dsts[4] = {Q16, K16, V16, S16};
#pragma unroll
  for (int c = 0; c < 4; ++c) {
    __syncthreads();
    if (cy == c) {
#pragma unroll
      for (int nt = 0; nt < 4; ++nt) {
        int col = half * 64 + nt * 16 + (lane & 15);
        float bb = biases[c][col];
        int rb = (lane >> 4) << 2;
#pragma unroll
        for (int mt2 = 0; mt2 < 2; ++mt2)
#pragma unroll
          for (int reg = 0; reg < 4; ++reg)
            os[mt2 * 16 + rb + reg][col] = (_Float16)(acc[mt2][nt][reg] + bb);
      }
    }
    __syncthreads();
    {
      int r = tid >> 4, c8 = (tid & 15) * 8;
      int row = n0 + r;
      if (row < NN) {
        _Float16* dst = dsts[c];
        const _Float16* op = &os[r][c8];
        if (c < 3) {
#pragma unroll
          for (int q = 0; q < 2; ++q) {
            int j4 = (c8 >> 2) + q;
            int po = ((j4 & 3) << 5) | ((j4 >> 2) << 2);
            *(half4v*)&dst[(size_t)row * 128 + po] = *(const half4v*)&op[q * 4];
          }
        } else {
          *(uint4*)&dst[(size_t)row * 128 + c8] = *((const uint4*)op);
        }
      }
    }
  }
}

// ---------------- parallel CSR scan (2 kernels) ----------------------------
__global__ __launch_bounds__(256) void k_scan1(const int* __restrict__ deg,
                                               int* __restrict__ off,
                                               int* __restrict__ choff,
                                               int* __restrict__ bsum,
                                               int* __restrict__ bsumc) {
  __shared__ int s[256], sc[256];
  const int b = blockIdx.x, t = threadIdx.x;
  const int n = b * 256 + t;
  int d = (n < NN) ? deg[n] : 0;
  int c = (d + 15) >> 4;
  s[t] = d; sc[t] = c;
  __syncthreads();
  for (int o = 1; o < 256; o <<= 1) {
    int v1 = 0, v2 = 0;
    if (t >= o) { v1 = s[t - o]; v2 = sc[t - o]; }
    __syncthreads();
    if (t >= o) { s[t] += v1; sc[t] += v2; }
    __syncthreads();
  }
  if (n < NN) { off[n] = s[t] - d; choff[n] = sc[t] - c; }
  if (t == 255) { bsum[b] = s[255]; bsumc[b] = sc[255]; }
}

// merged scan2+scan3: every block redundantly scans the 196 block sums,
// then adds its exclusive base to its 256 nodes.
__global__ __launch_bounds__(256) void k_scanf(const int* __restrict__ bsum,
                                               const int* __restrict__ bsumc,
                                               int* __restrict__ off,
                                               int* __restrict__ choff) {
  __shared__ int s[256], sc[256];
  const int b = blockIdx.x, t = threadIdx.x;
  s[t] = (t < NBLK) ? bsum[t] : 0;
  sc[t] = (t < NBLK) ? bsumc[t] : 0;
  __syncthreads();
  for (int o = 1; o < 256; o <<= 1) {
    int v1 = 0, v2 = 0;
    if (t >= o) { v1 = s[t - o]; v2 = sc[t - o]; }
    __syncthreads();
    if (t >= o) { s[t] += v1; sc[t] += v2; }
    __syncthreads();
  }
  int base = (b > 0) ? s[b - 1] : 0;
  int basec = (b > 0) ? sc[b - 1] : 0;
  int n = b * 256 + t;
  if (n < NN) { off[n] += base; choff[n] += basec; }
  if (b == 0 && t == 0) { off[NN] = s[NBLK - 1]; choff[NN] = sc[NBLK - 1]; }
}

// fused: blocks [0,3125) fill elist; blocks [3125,3321) build chunk table
__global__ void k_fillch(const int* __restrict__ ei, const int* __restrict__ deg,
                         const int* __restrict__ off, const int* __restrict__ choff,
                         int* __restrict__ cur, int* __restrict__ elist,
                         uint2* __restrict__ chunks) {
  int b = blockIdx.x;
  if (b < 3125) {
    int e = b * 256 + threadIdx.x;
    if (e < NE) {
      int d = ei[NE + e];
      int p = atomicAdd(&cur[d], 1);
      elist[off[d] + p] = e;
    }
  } else {
    int n = (b - 3125) * 256 + threadIdx.x;
    if (n < NN) {
      int d = deg[n], o = off[n], c = choff[n];
      int nch = (d + 15) >> 4;
      for (int j = 0; j < nch; ++j) {
        int cnt = d - 16 * j; if (cnt > 16) cnt = 16;
        chunks[c + j] = make_uint2((unsigned)(o + 16 * j),
                                   ((unsigned)n << 5) | (unsigned)cnt);
      }
    }
  }
}

// ---------------- k_edge: persistent blocks, one wave per 16-edge chunk -----
// wef staged ONCE per block (was 12.5k re-stagings); grid-stride over chunks.
// DPP reductions on VALU; alpha via fdot2; num in packed f16.
__global__ __launch_bounds__(512) void k_edge(
    const _Float16* __restrict__ Q16, const _Float16* __restrict__ K16,
    const _Float16* __restrict__ V16,
    const float* __restrict__ Wt, const float* __restrict__ bt,
    const uint4* __restrict__ wefrag,
    const float* __restrict__ msg, const int* __restrict__ last_update,
    const int* __restrict__ ei, const int* __restrict__ tt,
    const int* __restrict__ elist, const uint2* __restrict__ chunks,
    const int* __restrict__ choff,
    unsigned* __restrict__ numbuf, float4* __restrict__ mdm,
    float4* __restrict__ mdd)
{
  __shared__ uint4 wef_s[2048];
  __shared__ float2 wtbt_s[104];
  __shared__ unsigned accs_u[8][64];

  for (int i = threadIdx.x; i < 2048; i += 512) wef_s[i] = wefrag[i];
  if (threadIdx.x < 104) {
    int j = threadIdx.x;
    wtbt_s[j] = make_float2(j < TDIM ? Wt[j] : 0.f, j < TDIM ? bt[j] : 0.f);
  }
  __syncthreads();

  const int nchunks = choff[NN];
  const int wid = threadIdx.x >> 6, lane = threadIdx.x & 63;
  const int g = lane >> 4, ed = lane & 15;

  for (int c0 = blockIdx.x * 8; c0 < nchunks; c0 += EGRID * 8) {
    const int chunk = c0 + wid;
    if (chunk >= nchunks) continue;   // no block-wide sync in body: safe

    uint2 ce = chunks[chunk];
    const int estart = (int)ce.x;
    const int node = (int)(ce.y >> 5);
    const int cnt = (int)(ce.y & 31u);

    const int edc = (ed < cnt) ? ed : (cnt - 1);
    const int eid = elist[estart + edc];
    const int src_b = ei[eid];
    const float mg_b = msg[eid];
    const float rel_b = (float)(last_update[src_b] - tt[eid]);
    const bool valid = (ed < cnt);

    unsigned bfu[4][4];
    build_bfu(rel_b, mg_b, g, wtbt_s, bfu);

    // e via MFMA: ec[mt][r] = e[ed][mt*16+g*4+r]
    f32x4 ec[8];
#pragma unroll
    for (int mt = 0; mt < 8; ++mt) {
      f32x4 c4 = {0.f, 0.f, 0.f, 0.f};
#pragma unroll
      for (int ks = 0; ks < 4; ++ks) {
        U16 av2; av2.u = wef_s[(ks * 8 + mt) * 64 + lane];
        U16 bv2; bv2.u.x = bfu[ks][0]; bv2.u.y = bfu[ks][1];
        bv2.u.z = bfu[ks][2]; bv2.u.w = bfu[ks][3];
        c4 = __builtin_amdgcn_mfma_f32_16x16x32_f16(av2.h, bv2.h, c4, 0, 0, 0);
      }
      ec[mt] = c4;
    }

    // pack e to f16 pairs; pair layout matches permuted q/k/v uint4 blocks
    unsigned ep2[16];
#pragma unroll
    for (int mt = 0; mt < 8; ++mt) {
      ep2[mt * 2 + 0] = pk16(ec[mt][0], ec[mt][1]);
      ep2[mt * 2 + 1] = pk16(ec[mt][2], ec[mt][3]);
    }

    // per-head alpha = q.k + q.e via fdot2
    float pal[4];
    {
      const uint4* qp = (const uint4*)&Q16[(size_t)node * 128 + g * 32];
      const uint4* kp = (const uint4*)&K16[(size_t)src_b * 128 + g * 32];
#pragma unroll
      for (int i = 0; i < 4; ++i) {
        uint4 qa = qp[i], ka = kp[i];
        float p = 0.f;
        p = fdot2f(qa.x, ka.x, p); p = fdot2f(qa.y, ka.y, p);
        p = fdot2f(qa.z, ka.z, p); p = fdot2f(qa.w, ka.w, p);
        p = fdot2f(qa.x, ep2[4 * i + 0], p); p = fdot2f(qa.y, ep2[4 * i + 1], p);
        p = fdot2f(qa.z, ep2[4 * i + 2], p); p = fdot2f(qa.w, ep2[4 * i + 3], p);
        pal[i] = p;
      }
    }

    // per-head: complete dot across g-lanes (shfl), chunk softmax via DPP
    float m_[4], w_[4], d_[4];
#pragma unroll
    for (int h = 0; h < 4; ++h) {
      float p = pal[h];
      p += __shfl_xor(p, 16); p += __shfl_xor(p, 32);
      float al = valid ? p * 0.17677669529663689f : -INFINITY;
      float mm = red16_max(al);
      m_[h] = mm;
      w_[h] = __expf(al - mm);       // invalid -> 0
      d_[h] = red16_add(w_[h]);
    }

    // partial num in packed f16: w*(v+e), reduced over ed with packed DPP
    unsigned np2[16];
    {
      const uint4* vp = (const uint4*)&V16[(size_t)src_b * 128 + g * 32];
#pragma unroll
      for (int i = 0; i < 4; ++i) {
        uint4 va = vp[i];
        unsigned w2 = pk16(w_[i], w_[i]);
        np2[4 * i + 0] = pkmul(pkadd(va.x, ep2[4 * i + 0]), w2);
        np2[4 * i + 1] = pkmul(pkadd(va.y, ep2[4 * i + 1]), w2);
        np2[4 * i + 2] = pkmul(pkadd(va.z, ep2[4 * i + 2]), w2);
        np2[4 * i + 3] = pkmul(pkadd(va.w, ep2[4 * i + 3]), w2);
      }
    }
#pragma unroll
    for (int j = 0; j < 16; ++j) np2[j] = red16_pkadd(np2[j]);

    // stash reduced pairs: natural pair index P = 16i + 8(j>>1) + 2g + (j&1)
    if (ed == 0) {
#pragma unroll
      for (int i = 0; i < 4; ++i)
#pragma unroll
        for (int j = 0; j < 4; ++j)
          accs_u[wid][16 * i + 8 * (j >> 1) + 2 * g + (j & 1)] = np2[4 * i + j];
    }
    __asm__ volatile("s_waitcnt lgkmcnt(0)" ::: "memory");

    numbuf[(size_t)chunk * 64 + lane] = accs_u[wid][lane];
    if (lane == 0) {
      mdm[chunk] = make_float4(m_[0], m_[1], m_[2], m_[3]);
      mdd[chunk] = make_float4(d_[0], d_[1], d_[2], d_[3]);
    }
  }
}

// ---------------- k_comb: per-head flash combine + skip/relu/layernorm ------
__global__ __launch_bounds__(256) void k_comb(
    const unsigned* __restrict__ numbuf, const float* __restrict__ mdmf,
    const float* __restrict__ mddf, const _Float16* __restrict__ S16,
    const float* __restrict__ gamma, const float* __restrict__ beta,
    const int* __restrict__ choff, float* __restrict__ out)
{
  const int wid = threadIdx.x >> 6, lane = threadIdx.x & 63;
  const int node = blockIdx.x * 4 + wid;
  const int g = lane >> 4;          // head of channels 2*lane, 2*lane+1
  const int c0 = choff[node], c1 = choff[node + 1];

  float M = -INFINITY;
  for (int c = c0; c < c1; ++c) M = fmaxf(M, mdmf[c * 4 + g]);

  float den = 0.f, n0 = 0.f, n1 = 0.f;
  for (int c = c0; c < c1; ++c) {
    float sc = __expf(mdmf[c * 4 + g] - M);
    den = fmaf(mddf[c * 4 + g], sc, den);
    U4h u; u.u = numbuf[(size_t)c * 64 + lane];
    n0 = fmaf((float)u.h.x, sc, n0);
    n1 = fmaf((float)u.h.y, sc, n1);
  }

  float iv = 1.f / (den + 1e-16f);
  U4h s2; s2.u = *(const unsigned*)&S16[(size_t)node * 128 + 2 * lane];
  float r0 = fmaxf(fmaf(n0, iv, (float)s2.h.x), 0.f);
  float r1 = fmaxf(fmaf(n1, iv, (float)s2.h.y), 0.f);

  float sum = r0 + r1;
#pragma unroll
  for (int o = 1; o < 64; o <<= 1) sum += __shfl_xor(sum, o);
  float mu = sum * 0.0078125f;
  float d0 = r0 - mu, d1 = r1 - mu;
  float vs = d0 * d0 + d1 * d1;
#pragma unroll
  for (int o = 1; o < 64; o <<= 1) vs += __shfl_xor(vs, o);
  float rstd = rsqrtf(vs * 0.0078125f + 1e-5f);
  float2 gm = ((const float2*)gamma)[lane], bb = ((const float2*)beta)[lane];
  ((float2*)out)[node * 64 + lane] =
      make_float2(d0 * rstd * gm.x + bb.x, d1 * rstd * gm.y + bb.y);
}

// ---------------- launch ----------------
// ws (bytes): Q16 0 | S16 12.8M | K16 25.6M | V16 38.4M | numbuf 51.2M (25.6M)
//   deg 76.8M | cur 77.0M | off 77.2M | choff 77,400,064 | elist 77,600,128
//   wef 80,800,128 | chunks 80,832,896 | mdm 81,632,896 | mdd 83,232,896
//   wpf 84,832,896 (128KB) | bsum 84,963,968 | bsumc 84,964,968 | end 84,965,968
extern "C" void kernel_launch(void* const* d_in, const int* in_sizes, int n_in,
                              void* d_out, int out_size, void* d_ws, size_t ws_size,
                              hipStream_t stream)
{
  (void)in_sizes; (void)n_in; (void)out_size;
  if (ws_size < 84965968u) return;

  const float* x     = (const float*)d_in[0];
  const float* msg   = (const float*)d_in[1];
  const float* Wt    = (const float*)d_in[2];
  const float* bt    = (const float*)d_in[3];
  const float* Wq    = (const float*)d_in[4];
  const float* bq    = (const float*)d_in[5];
  const float* Wk    = (const float*)d_in[6];
  const float* bk    = (const float*)d_in[7];
  const float* Wv    = (const float*)d_in[8];
  const float* bv    = (const float*)d_in[9];
  const float* We    = (const float*)d_in[10];
  const float* Wskip = (const float*)d_in[11];
  const float* bskip = (const float*)d_in[12];
  const float* gamma = (const float*)d_in[13];
  const float* beta  = (const float*)d_in[14];
  const int* last_update = (const int*)d_in[15];
  const int* ei    = (const int*)d_in[16];
  const int* tt    = (const int*)d_in[17];

  char* ws = (char*)d_ws;
  _Float16* Q16 = (_Float16*)(ws);
  _Float16* S16 = (_Float16*)(ws + 12800000);
  _Float16* K16 = (_Float16*)(ws + 25600000);
  _Float16* V16 = (_Float16*)(ws + 38400000);
  unsigned* numbuf = (unsigned*)(ws + 51200000);
  int* deg   = (int*)(ws + 76800000);
  int* cur   = (int*)(ws + 77000000);
  int* off   = (int*)(ws + 77200000);
  int* choff = (int*)(ws + 77400064);
  int* elist = (int*)(ws + 77600128);
  uint4* wef = (uint4*)(ws + 80800128);
  uint2* chunks = (uint2*)(ws + 80832896);
  float4* mdm = (float4*)(ws + 81632896);
  float4* mdd = (float4*)(ws + 83232896);
  uint4* wpf = (uint4*)(ws + 84832896);
  int* bsum  = (int*)(ws + 84963968);
  int* bsumc = (int*)(ws + 84964968);

  (void)hipMemsetAsync(deg, 0, 400000, stream);        // deg + cur
  k_init<<<(NE + 255) / 256, 256, 0, stream>>>(We, Wq, Wk, Wv, Wskip, wef, wpf,
                                               ei, deg);
  k_scan1<<<NBLK, 256, 0, stream>>>(deg, off, choff, bsum, bsumc);
  k_scanf<<<NBLK, 256, 0, stream>>>(bsum, bsumc, off, choff);
  k_fillch<<<3125 + (NN + 255) / 256, 256, 0, stream>>>(ei, deg, off, choff,
                                                        cur, elist, chunks);
  k_proj2<<<(NN + 31) / 32, 512, 0, stream>>>(x, bq, bk, bv, bskip, wpf,
                                              Q16, K16, V16, S16);
  k_edge<<<EGRID, 512, 0, stream>>>(Q16, K16, V16, Wt, bt, wef,
                                    msg, last_update, ei, tt, elist,
                                    chunks, choff, numbuf, mdm, mdd);
  k_comb<<<NN / 4, 256, 0, stream>>>(numbuf, (const float*)mdm, (const float*)mdd,
                                     S16, gamma, beta, choff, (float*)d_out);
}

// Round 17
// 263.660 us; speedup vs baseline: 3.8403x; 1.0009x over previous
//
#include <hip/hip_runtime.h>
#include <math.h>

#define NN 50000
#define NE 800000
#define TDIM 100
#define MAXCH 100000   // sum ceil(deg/16) <= 50000 + 800000/16 = 100000
#define NBLK 196       // ceil(NN/256)
#define EGRID 2048     // persistent k_edge blocks (2-deep per CU for balance)

typedef _Float16 half2v __attribute__((ext_vector_type(2)));
typedef _Float16 half4v __attribute__((ext_vector_type(4)));
typedef _Float16 half8v __attribute__((ext_vector_type(8)));
typedef __fp16 fp16x2 __attribute__((ext_vector_type(2)));
typedef float f32x4 __attribute__((ext_vector_type(4)));

union U16 { uint4 u; half8v h; };
union U4h { unsigned u; half2v h; };

// cos(x) matching np.cos(float32) to ~1e-6.
__device__ __forceinline__ float ref_cosf(float x) {
  const float C1 = 0.15915494f;
  const float C2 = 6.42063831e-9f;
  float p = x * C1;
  float r = __fmaf_rn(x, C1, -p);
  r = __fmaf_rn(x, C2, r);
  float n = rintf(p);
  float f = (p - n) + r;
  return __builtin_amdgcn_cosf(f);
}

__device__ __forceinline__ unsigned pk16(float a, float b) {
  fp16x2 h = __builtin_amdgcn_cvt_pkrtz(a, b);
  unsigned u;
  __builtin_memcpy(&u, &h, 4);
  return u;
}

__device__ __forceinline__ float fdot2f(unsigned a, unsigned b, float c) {
  U4h ua, ub; ua.u = a; ub.u = b;
#if __has_builtin(__builtin_amdgcn_fdot2)
  return __builtin_amdgcn_fdot2(ua.h, ub.h, c, false);
#else
  return c + (float)ua.h.x * (float)ub.h.x + (float)ua.h.y * (float)ub.h.y;
#endif
}

// packed f16 helpers (v_pk_add_f16 / v_pk_mul_f16)
__device__ __forceinline__ unsigned pkadd(unsigned a, unsigned b) {
  half2v x, y; __builtin_memcpy(&x, &a, 4); __builtin_memcpy(&y, &b, 4);
  half2v z = x + y; unsigned r; __builtin_memcpy(&r, &z, 4); return r;
}
__device__ __forceinline__ unsigned pkmul(unsigned a, unsigned b) {
  half2v x, y; __builtin_memcpy(&x, &a, 4); __builtin_memcpy(&y, &b, 4);
  half2v z = x * y; unsigned r; __builtin_memcpy(&r, &z, 4); return r;
}

// ---- DPP 16-lane butterfly (VALU pipe): masks {1,2,7,15} -------------------
template<int CTRL>
__device__ __forceinline__ int dpp_i(int x) {
  return __builtin_amdgcn_update_dpp(0, x, CTRL, 0xf, 0xf, true);
}
template<int CTRL>
__device__ __forceinline__ float dpp_addf(float x) {
  return x + __int_as_float(dpp_i<CTRL>(__float_as_int(x)));
}
template<int CTRL>
__device__ __forceinline__ float dpp_maxf(float x) {
  return fmaxf(x, __int_as_float(dpp_i<CTRL>(__float_as_int(x))));
}
__device__ __forceinline__ float red16_add(float x) {
  x = dpp_addf<0xB1>(x); x = dpp_addf<0x4E>(x);
  x = dpp_addf<0x141>(x); x = dpp_addf<0x140>(x);
  return x;
}
__device__ __forceinline__ float red16_max(float x) {
  x = dpp_maxf<0xB1>(x); x = dpp_maxf<0x4E>(x);
  x = dpp_maxf<0x141>(x); x = dpp_maxf<0x140>(x);
  return x;
}
__device__ __forceinline__ unsigned red16_pkadd(unsigned x) {
  x = pkadd(x, (unsigned)dpp_i<0xB1>((int)x));
  x = pkadd(x, (unsigned)dpp_i<0x4E>((int)x));
  x = pkadd(x, (unsigned)dpp_i<0x141>((int)x));
  x = pkadd(x, (unsigned)dpp_i<0x140>((int)x));
  return x;
}

// attr fragments: lane slice g, j = ks*32 + g*8 + 2p (+1); j>100 -> 0
__device__ __forceinline__ void build_bfu(float rel_b, float mg_b, int g,
                                          const float2* wtbt_s, unsigned bfu[4][4]) {
#pragma unroll
  for (int ks = 0; ks < 4; ++ks) {
#pragma unroll
    for (int p = 0; p < 4; ++p) {
      int j0 = ks * 32 + g * 8 + 2 * p;
      float a0 = 0.f, a1 = 0.f;
      if (ks < 3) {
        float2 w0 = wtbt_s[j0], w1 = wtbt_s[j0 + 1];
        a0 = ref_cosf(__fmaf_rn(rel_b, w0.x, w0.y));
        a1 = ref_cosf(__fmaf_rn(rel_b, w1.x, w1.y));
      } else {
        if (j0 < 100) {
          float2 w0 = wtbt_s[j0];
          a0 = ref_cosf(__fmaf_rn(rel_b, w0.x, w0.y));
        } else if (j0 == 100) a0 = mg_b;
        if (j0 + 1 < 100) {
          float2 w1 = wtbt_s[j0 + 1];
          a1 = ref_cosf(__fmaf_rn(rel_b, w1.x, w1.y));
        } else if (j0 + 1 == 100) a1 = mg_b;
      }
      bfu[ks][p] = pk16(a0, a1);
    }
  }
}

// ---------------- k_init: W fragments + degree count (fused) ---------------
__global__ void k_init(const float* __restrict__ We,
                       const float* __restrict__ Wq, const float* __restrict__ Wk,
                       const float* __restrict__ Wv, const float* __restrict__ Wskip,
                       uint4* __restrict__ wef, uint4* __restrict__ wpf,
                       const int* __restrict__ ei, int* __restrict__ deg) {
  int idx = blockIdx.x * 256 + threadIdx.x;
  if (idx < 2048) {
    int lane = idx & 63, fi = idx >> 6;
    int ks = fi >> 3, mt = fi & 7;
    int ch = mt * 16 + (lane & 15);
    int k0 = ks * 32 + ((lane >> 4) << 3);
    U16 cv;
#pragma unroll
    for (int jj = 0; jj < 8; ++jj) {
      int j = k0 + jj;
      cv.h[jj] = (j <= 100) ? (_Float16)We[j * 128 + ch] : (_Float16)0.f;
    }
    wef[idx] = cv.u;
  } else if (idx < 2048 + 8192) {
    int i2 = idx - 2048;
    int lane = i2 & 63, fi = i2 >> 6;     // fi = (cy*4+ks)*8+nt
    int nt = fi & 7, ks = (fi >> 3) & 3, cy = fi >> 5;
    const float* W = (cy == 0) ? Wq : (cy == 1) ? Wk : (cy == 2) ? Wv : Wskip;
    int n = nt * 16 + (lane & 15);
    int k0 = ks * 32 + ((lane >> 4) << 3);
    U16 cv;
#pragma unroll
    for (int jj = 0; jj < 8; ++jj)
      cv.h[jj] = (_Float16)W[(k0 + jj) * 128 + n];
    wpf[i2] = cv.u;
  }
  if (idx < NE) atomicAdd(&deg[ei[NE + idx]], 1);
}

// ---------------- MFMA projection v2: all 4 outputs, x staged once ----------
// 512 threads; wave w: cy = w>>1, 64-col half = w&1; 32 rows per block.
// Q,K,V stored PERMUTED: channel c -> ((c>>2)&3)*32 + (c>>4)*4 + (c&3).
__global__ __launch_bounds__(512) void k_proj2(
    const float* __restrict__ x,
    const float* __restrict__ bq, const float* __restrict__ bk,
    const float* __restrict__ bv, const float* __restrict__ bskip,
    const uint4* __restrict__ wpf,
    _Float16* __restrict__ Q16, _Float16* __restrict__ K16,
    _Float16* __restrict__ V16, _Float16* __restrict__ S16)
{
  __shared__ unsigned xs[32][68];     // x rows as f16 pairs (272B pitch)
  __shared__ _Float16 os[32][136];    // output bounce (272B pitch)

  const int n0 = blockIdx.x * 32;
  const int tid = threadIdx.x;

  {
    int r = tid >> 4, c8 = (tid & 15) * 8;     // 32 rows x 16 col-groups of 8
    int row = n0 + r;
    float4 v0 = {0,0,0,0}, v1 = {0,0,0,0};
    if (row < NN) {
      const float4* xp = (const float4*)&x[(size_t)row * 128 + c8];
      v0 = xp[0]; v1 = xp[1];
    }
    unsigned* xr = &xs[r][c8 >> 1];
    xr[0] = pk16(v0.x, v0.y); xr[1] = pk16(v0.z, v0.w);
    xr[2] = pk16(v1.x, v1.y); xr[3] = pk16(v1.z, v1.w);
  }
  __syncthreads();

  const int w = tid >> 6, lane = tid & 63;
  const int cy = w >> 1, half = w & 1;

  f32x4 acc[2][4] = {};
#pragma unroll
  for (int ks = 0; ks < 4; ++ks) {
    U16 a0_, a1_;
    a0_.u = *(const uint4*)&xs[lane & 15][ks * 16 + ((lane >> 4) << 2)];
    a1_.u = *(const uint4*)&xs[16 + (lane & 15)][ks * 16 + ((lane >> 4) << 2)];
#pragma unroll
    for (int nt = 0; nt < 4; ++nt) {
      U16 b_; b_.u = wpf[((cy * 4 + ks) * 8 + half * 4 + nt) * 64 + lane];
      acc[0][nt] = __builtin_amdgcn_mfma_f32_16x16x32_f16(a0_.h, b_.h, acc[0][nt], 0, 0, 0);
      acc[1][nt] = __builtin_amdgcn_mfma_f32_16x16x32_f16(a1_.h, b_.h, acc[1][nt], 0, 0, 0);
    }
  }

  const float* biases[4] = {bq, bk, bv, bskip};
  _Float16* dsts[4] = {Q16, K16, V16, S16};
#pragma unroll
  for (int c = 0; c < 4; ++c) {
    __syncthreads();
    if (cy == c) {
#pragma unroll
      for (int nt = 0; nt < 4; ++nt) {
        int col = half * 64 + nt * 16 + (lane & 15);
        float bb = biases[c][col];
        int rb = (lane >> 4) << 2;
#pragma unroll
        for (int mt2 = 0; mt2 < 2; ++mt2)
#pragma unroll
          for (int reg = 0; reg < 4; ++reg)
            os[mt2 * 16 + rb + reg][col] = (_Float16)(acc[mt2][nt][reg] + bb);
      }
    }
    __syncthreads();
    {
      int r = tid >> 4, c8 = (tid & 15) * 8;
      int row = n0 + r;
      if (row < NN) {
        _Float16* dst = dsts[c];
        const _Float16* op = &os[r][c8];
        if (c < 3) {
#pragma unroll
          for (int q = 0; q < 2; ++q) {
            int j4 = (c8 >> 2) + q;
            int po = ((j4 & 3) << 5) | ((j4 >> 2) << 2);
            *(half4v*)&dst[(size_t)row * 128 + po] = *(const half4v*)&op[q * 4];
          }
        } else {
          *(uint4*)&dst[(size_t)row * 128 + c8] = *((const uint4*)op);
        }
      }
    }
  }
}

// ---------------- parallel CSR scan (2 kernels) ----------------------------
__global__ __launch_bounds__(256) void k_scan1(const int* __restrict__ deg,
                                               int* __restrict__ off,
                                               int* __restrict__ choff,
                                               int* __restrict__ bsum,
                                               int* __restrict__ bsumc) {
  __shared__ int s[256], sc[256];
  const int b = blockIdx.x, t = threadIdx.x;
  const int n = b * 256 + t;
  int d = (n < NN) ? deg[n] : 0;
  int c = (d + 15) >> 4;
  s[t] = d; sc[t] = c;
  __syncthreads();
  for (int o = 1; o < 256; o <<= 1) {
    int v1 = 0, v2 = 0;
    if (t >= o) { v1 = s[t - o]; v2 = sc[t - o]; }
    __syncthreads();
    if (t >= o) { s[t] += v1; sc[t] += v2; }
    __syncthreads();
  }
  if (n < NN) { off[n] = s[t] - d; choff[n] = sc[t] - c; }
  if (t == 255) { bsum[b] = s[255]; bsumc[b] = sc[255]; }
}

// merged scan2+scan3: every block redundantly scans the 196 block sums,
// then adds its exclusive base to its 256 nodes.
__global__ __launch_bounds__(256) void k_scanf(const int* __restrict__ bsum,
                                               const int* __restrict__ bsumc,
                                               int* __restrict__ off,
                                               int* __restrict__ choff) {
  __shared__ int s[256], sc[256];
  const int b = blockIdx.x, t = threadIdx.x;
  s[t] = (t < NBLK) ? bsum[t] : 0;
  sc[t] = (t < NBLK) ? bsumc[t] : 0;
  __syncthreads();
  for (int o = 1; o < 256; o <<= 1) {
    int v1 = 0, v2 = 0;
    if (t >= o) { v1 = s[t - o]; v2 = sc[t - o]; }
    __syncthreads();
    if (t >= o) { s[t] += v1; sc[t] += v2; }
    __syncthreads();
  }
  int base = (b > 0) ? s[b - 1] : 0;
  int basec = (b > 0) ? sc[b - 1] : 0;
  int n = b * 256 + t;
  if (n < NN) { off[n] += base; choff[n] += basec; }
  if (b == 0 && t == 0) { off[NN] = s[NBLK - 1]; choff[NN] = sc[NBLK - 1]; }
}

// fused: blocks [0,3125) fill elist; blocks [3125,3321) build chunk table.
// bit31 of chunk.y flags a SINGLE-chunk node (k_edge finishes it inline).
__global__ void k_fillch(const int* __restrict__ ei, const int* __restrict__ deg,
                         const int* __restrict__ off, const int* __restrict__ choff,
                         int* __restrict__ cur, int* __restrict__ elist,
                         uint2* __restrict__ chunks) {
  int b = blockIdx.x;
  if (b < 3125) {
    int e = b * 256 + threadIdx.x;
    if (e < NE) {
      int d = ei[NE + e];
      int p = atomicAdd(&cur[d], 1);
      elist[off[d] + p] = e;
    }
  } else {
    int n = (b - 3125) * 256 + threadIdx.x;
    if (n < NN) {
      int d = deg[n], o = off[n], c = choff[n];
      int nch = (d + 15) >> 4;
      unsigned flag = (nch == 1) ? 0x80000000u : 0u;
      for (int j = 0; j < nch; ++j) {
        int cnt = d - 16 * j; if (cnt > 16) cnt = 16;
        chunks[c + j] = make_uint2((unsigned)(o + 16 * j),
                                   flag | ((unsigned)n << 5) | (unsigned)cnt);
      }
    }
  }
}

// ---------------- k_edge: persistent blocks, one wave per 16-edge chunk -----
// wef staged once per block; grid-stride over chunks. Single-chunk nodes are
// finished INLINE (skip+relu+layernorm; identical math to k_comb with sc=1).
__global__ __launch_bounds__(512) void k_edge(
    const _Float16* __restrict__ Q16, const _Float16* __restrict__ K16,
    const _Float16* __restrict__ V16, const _Float16* __restrict__ S16,
    const float* __restrict__ Wt, const float* __restrict__ bt,
    const uint4* __restrict__ wefrag,
    const float* __restrict__ gamma, const float* __restrict__ beta,
    const float* __restrict__ msg, const int* __restrict__ last_update,
    const int* __restrict__ ei, const int* __restrict__ tt,
    const int* __restrict__ elist, const uint2* __restrict__ chunks,
    const int* __restrict__ choff,
    unsigned* __restrict__ numbuf, float4* __restrict__ mdm,
    float4* __restrict__ mdd, float* __restrict__ out)
{
  __shared__ uint4 wef_s[2048];
  __shared__ float2 wtbt_s[104];
  __shared__ unsigned accs_u[8][64];

  for (int i = threadIdx.x; i < 2048; i += 512) wef_s[i] = wefrag[i];
  if (threadIdx.x < 104) {
    int j = threadIdx.x;
    wtbt_s[j] = make_float2(j < TDIM ? Wt[j] : 0.f, j < TDIM ? bt[j] : 0.f);
  }
  __syncthreads();

  const int nchunks = choff[NN];
  const int wid = threadIdx.x >> 6, lane = threadIdx.x & 63;
  const int g = lane >> 4, ed = lane & 15;

  for (int c0 = blockIdx.x * 8; c0 < nchunks; c0 += EGRID * 8) {
    const int chunk = c0 + wid;
    if (chunk >= nchunks) continue;   // no block-wide sync in body: safe

    uint2 ce = chunks[chunk];
    const int estart = (int)ce.x;
    const int node = (int)((ce.y >> 5) & 0xFFFFu);
    const int cnt = (int)(ce.y & 31u);

    const int edc = (ed < cnt) ? ed : (cnt - 1);
    const int eid = elist[estart + edc];
    const int src_b = ei[eid];
    const float mg_b = msg[eid];
    const float rel_b = (float)(last_update[src_b] - tt[eid]);
    const bool valid = (ed < cnt);

    unsigned bfu[4][4];
    build_bfu(rel_b, mg_b, g, wtbt_s, bfu);

    // e via MFMA: ec[mt][r] = e[ed][mt*16+g*4+r]
    f32x4 ec[8];
#pragma unroll
    for (int mt = 0; mt < 8; ++mt) {
      f32x4 c4 = {0.f, 0.f, 0.f, 0.f};
#pragma unroll
      for (int ks = 0; ks < 4; ++ks) {
        U16 av2; av2.u = wef_s[(ks * 8 + mt) * 64 + lane];
        U16 bv2; bv2.u.x = bfu[ks][0]; bv2.u.y = bfu[ks][1];
        bv2.u.z = bfu[ks][2]; bv2.u.w = bfu[ks][3];
        c4 = __builtin_amdgcn_mfma_f32_16x16x32_f16(av2.h, bv2.h, c4, 0, 0, 0);
      }
      ec[mt] = c4;
    }

    // pack e to f16 pairs; pair layout matches permuted q/k/v uint4 blocks
    unsigned ep2[16];
#pragma unroll
    for (int mt = 0; mt < 8; ++mt) {
      ep2[mt * 2 + 0] = pk16(ec[mt][0], ec[mt][1]);
      ep2[mt * 2 + 1] = pk16(ec[mt][2], ec[mt][3]);
    }

    // per-head alpha = q.k + q.e via fdot2
    float pal[4];
    {
      const uint4* qp = (const uint4*)&Q16[(size_t)node * 128 + g * 32];
      const uint4* kp = (const uint4*)&K16[(size_t)src_b * 128 + g * 32];
#pragma unroll
      for (int i = 0; i < 4; ++i) {
        uint4 qa = qp[i], ka = kp[i];
        float p = 0.f;
        p = fdot2f(qa.x, ka.x, p); p = fdot2f(qa.y, ka.y, p);
        p = fdot2f(qa.z, ka.z, p); p = fdot2f(qa.w, ka.w, p);
        p = fdot2f(qa.x, ep2[4 * i + 0], p); p = fdot2f(qa.y, ep2[4 * i + 1], p);
        p = fdot2f(qa.z, ep2[4 * i + 2], p); p = fdot2f(qa.w, ep2[4 * i + 3], p);
        pal[i] = p;
      }
    }

    // per-head: complete dot across g-lanes (shfl), chunk softmax via DPP
    float m_[4], w_[4], d_[4];
#pragma unroll
    for (int h = 0; h < 4; ++h) {
      float p = pal[h];
      p += __shfl_xor(p, 16); p += __shfl_xor(p, 32);
      float al = valid ? p * 0.17677669529663689f : -INFINITY;
      float mm = red16_max(al);
      m_[h] = mm;
      w_[h] = __expf(al - mm);       // invalid -> 0
      d_[h] = red16_add(w_[h]);
    }

    // partial num in packed f16: w*(v+e), reduced over ed with packed DPP
    unsigned np2[16];
    {
      const uint4* vp = (const uint4*)&V16[(size_t)src_b * 128 + g * 32];
#pragma unroll
      for (int i = 0; i < 4; ++i) {
        uint4 va = vp[i];
        unsigned w2 = pk16(w_[i], w_[i]);
        np2[4 * i + 0] = pkmul(pkadd(va.x, ep2[4 * i + 0]), w2);
        np2[4 * i + 1] = pkmul(pkadd(va.y, ep2[4 * i + 1]), w2);
        np2[4 * i + 2] = pkmul(pkadd(va.z, ep2[4 * i + 2]), w2);
        np2[4 * i + 3] = pkmul(pkadd(va.w, ep2[4 * i + 3]), w2);
      }
    }
#pragma unroll
    for (int j = 0; j < 16; ++j) np2[j] = red16_pkadd(np2[j]);

    // stash reduced pairs: natural pair index P = 16i + 8(j>>1) + 2g + (j&1)
    if (ed == 0) {
#pragma unroll
      for (int i = 0; i < 4; ++i)
#pragma unroll
        for (int j = 0; j < 4; ++j)
          accs_u[wid][16 * i + 8 * (j >> 1) + 2 * g + (j & 1)] = np2[4 * i + j];
    }
    __asm__ volatile("s_waitcnt lgkmcnt(0)" ::: "memory");

    unsigned pr = accs_u[wid][lane];
    if (!(ce.y & 0x80000000u)) {
      numbuf[(size_t)chunk * 64 + lane] = pr;
      if (lane == 0) {
        mdm[chunk] = make_float4(m_[0], m_[1], m_[2], m_[3]);
        mdd[chunk] = make_float4(d_[0], d_[1], d_[2], d_[3]);
      }
    } else {
      // single-chunk node: finish inline (sc = exp(m-M) = 1)
      float dg = (g & 2) ? ((g & 1) ? d_[3] : d_[2])
                         : ((g & 1) ? d_[1] : d_[0]);
      float iv = 1.f / (dg + 1e-16f);
      U4h u; u.u = pr;
      U4h s2; s2.u = *(const unsigned*)&S16[(size_t)node * 128 + 2 * lane];
      float r0 = fmaxf(fmaf((float)u.h.x, iv, (float)s2.h.x), 0.f);
      float r1 = fmaxf(fmaf((float)u.h.y, iv, (float)s2.h.y), 0.f);
      float sum = r0 + r1;
#pragma unroll
      for (int o = 1; o < 64; o <<= 1) sum += __shfl_xor(sum, o);
      float mu = sum * 0.0078125f;
      float dd0 = r0 - mu, dd1 = r1 - mu;
      float vs = dd0 * dd0 + dd1 * dd1;
#pragma unroll
      for (int o = 1; o < 64; o <<= 1) vs += __shfl_xor(vs, o);
      float rstd = rsqrtf(vs * 0.0078125f + 1e-5f);
      float2 gm = ((const float2*)gamma)[lane], bb = ((const float2*)beta)[lane];
      ((float2*)out)[node * 64 + lane] =
          make_float2(dd0 * rstd * gm.x + bb.x, dd1 * rstd * gm.y + bb.y);
    }
  }
}

// ---------------- k_comb: per-head flash combine (multi-chunk nodes only) ---
__global__ __launch_bounds__(256) void k_comb(
    const unsigned* __restrict__ numbuf, const float* __restrict__ mdmf,
    const float* __restrict__ mddf, const _Float16* __restrict__ S16,
    const float* __restrict__ gamma, const float* __restrict__ beta,
    const int* __restrict__ choff, float* __restrict__ out)
{
  const int wid = threadIdx.x >> 6, lane = threadIdx.x & 63;
  const int node = blockIdx.x * 4 + wid;
  const int g = lane >> 4;          // head of channels 2*lane, 2*lane+1
  const int c0 = choff[node], c1 = choff[node + 1];
  if (c1 - c0 == 1) return;         // finished inline by k_edge

  float M = -INFINITY;
  for (int c = c0; c < c1; ++c) M = fmaxf(M, mdmf[c * 4 + g]);

  float den = 0.f, n0 = 0.f, n1 = 0.f;
  for (int c = c0; c < c1; ++c) {
    float sc = __expf(mdmf[c * 4 + g] - M);
    den = fmaf(mddf[c * 4 + g], sc, den);
    U4h u; u.u = numbuf[(size_t)c * 64 + lane];
    n0 = fmaf((float)u.h.x, sc, n0);
    n1 = fmaf((float)u.h.y, sc, n1);
  }

  float iv = 1.f / (den + 1e-16f);
  U4h s2; s2.u = *(const unsigned*)&S16[(size_t)node * 128 + 2 * lane];
  float r0 = fmaxf(fmaf(n0, iv, (float)s2.h.x), 0.f);
  float r1 = fmaxf(fmaf(n1, iv, (float)s2.h.y), 0.f);

  float sum = r0 + r1;
#pragma unroll
  for (int o = 1; o < 64; o <<= 1) sum += __shfl_xor(sum, o);
  float mu = sum * 0.0078125f;
  float d0 = r0 - mu, d1 = r1 - mu;
  float vs = d0 * d0 + d1 * d1;
#pragma unroll
  for (int o = 1; o < 64; o <<= 1) vs += __shfl_xor(vs, o);
  float rstd = rsqrtf(vs * 0.0078125f + 1e-5f);
  float2 gm = ((const float2*)gamma)[lane], bb = ((const float2*)beta)[lane];
  ((float2*)out)[node * 64 + lane] =
      make_float2(d0 * rstd * gm.x + bb.x, d1 * rstd * gm.y + bb.y);
}

// ---------------- launch ----------------
// ws (bytes): Q16 0 | S16 12.8M | K16 25.6M | V16 38.4M | numbuf 51.2M (25.6M)
//   deg 76.8M | cur 77.0M | off 77.2M | choff 77,400,064 | elist 77,600,128
//   wef 80,800,128 | chunks 80,832,896 | mdm 81,632,896 | mdd 83,232,896
//   wpf 84,832,896 (128KB) | bsum 84,963,968 | bsumc 84,964,968 | end 84,965,968
extern "C" void kernel_launch(void* const* d_in, const int* in_sizes, int n_in,
                              void* d_out, int out_size, void* d_ws, size_t ws_size,
                              hipStream_t stream)
{
  (void)in_sizes; (void)n_in; (void)out_size;
  if (ws_size < 84965968u) return;

  const float* x     = (const float*)d_in[0];
  const float* msg   = (const float*)d_in[1];
  const float* Wt    = (const float*)d_in[2];
  const float* bt    = (const float*)d_in[3];
  const float* Wq    = (const float*)d_in[4];
  const float* bq    = (const float*)d_in[5];
  const float* Wk    = (const float*)d_in[6];
  const float* bk    = (const float*)d_in[7];
  const float* Wv    = (const float*)d_in[8];
  const float* bv    = (const float*)d_in[9];
  const float* We    = (const float*)d_in[10];
  const float* Wskip = (const float*)d_in[11];
  const float* bskip = (const float*)d_in[12];
  const float* gamma = (const float*)d_in[13];
  const float* beta  = (const float*)d_in[14];
  const int* last_update = (const int*)d_in[15];
  const int* ei    = (const int*)d_in[16];
  const int* tt    = (const int*)d_in[17];

  char* ws = (char*)d_ws;
  _Float16* Q16 = (_Float16*)(ws);
  _Float16* S16 = (_Float16*)(ws + 12800000);
  _Float16* K16 = (_Float16*)(ws + 25600000);
  _Float16* V16 = (_Float16*)(ws + 38400000);
  unsigned* numbuf = (unsigned*)(ws + 51200000);
  int* deg   = (int*)(ws + 76800000);
  int* cur   = (int*)(ws + 77000000);
  int* off   = (int*)(ws + 77200000);
  int* choff = (int*)(ws + 77400064);
  int* elist = (int*)(ws + 77600128);
  uint4* wef = (uint4*)(ws + 80800128);
  uint2* chunks = (uint2*)(ws + 80832896);
  float4* mdm = (float4*)(ws + 81632896);
  float4* mdd = (float4*)(ws + 83232896);
  uint4* wpf = (uint4*)(ws + 84832896);
  int* bsum  = (int*)(ws + 84963968);
  int* bsumc = (int*)(ws + 84964968);

  (void)hipMemsetAsync(deg, 0, 400000, stream);        // deg + cur
  k_init<<<(NE + 255) / 256, 256, 0, stream>>>(We, Wq, Wk, Wv, Wskip, wef, wpf,
                                               ei, deg);
  k_scan1<<<NBLK, 256, 0, stream>>>(deg, off, choff, bsum, bsumc);
  k_scanf<<<NBLK, 256, 0, stream>>>(bsum, bsumc, off, choff);
  k_fillch<<<3125 + (NN + 255) / 256, 256, 0, stream>>>(ei, deg, off, choff,
                                                        cur, elist, chunks);
  k_proj2<<<(NN + 31) / 32, 512, 0, stream>>>(x, bq, bk, bv, bskip, wpf,
                                              Q16, K16, V16, S16);
  k_edge<<<EGRID, 512, 0, stream>>>(Q16, K16, V16, S16, Wt, bt, wef,
                                    gamma, beta, msg, last_update, ei, tt,
                                    elist, chunks, choff, numbuf, mdm, mdd,
                                    (float*)d_out);
  k_comb<<<NN / 4, 256, 0, stream>>>(numbuf, (const float*)mdm, (const float*)mdd,
                                     S16, gamma, beta, choff, (float*)d_out);
}